// Round 4
// baseline (370.657 us; speedup 1.0000x reference)
//
#include <hip/hip_runtime.h>

#define T_TOK 4096   // B*S
#define D_DIM 1024
#define N3    3072
#define S_LEN 2048
#define NH    16
#define HD    64
#define KAUG  1056   // 1024 + 16 (q-lora) + 16 (v-lora)

#define OUT_A_ELEMS   4194304   // B*S*D   (f32 elements)
#define OUT_KV_ELEMS  4194304   // B*H*S*hd

typedef __attribute__((ext_vector_type(8))) short bf16x8;
typedef __attribute__((ext_vector_type(4))) float f32x4;
typedef __attribute__((ext_vector_type(16))) float f32x16;

union U4 { unsigned u[4]; bf16x8 v; };

// granule-position hash for LDS bank-conflict-free B tiles (row stride 64 B)
#define GHASH(r) ((((r) >> 1) ^ ((r) >> 3)) & 3)

__device__ __forceinline__ unsigned short f2bf(float f) {
    unsigned u = __float_as_uint(f);
    u += 0x7FFFu + ((u >> 16) & 1u);
    return (unsigned short)(u >> 16);
}
__device__ __forceinline__ float bf2f(unsigned short h) {
    return __uint_as_float(((unsigned)h) << 16);
}
__device__ __forceinline__ unsigned cvtpk(float a, float b) {
    unsigned r;
    asm("v_cvt_pk_bf16_f32 %0, %1, %2" : "=v"(r) : "v"(a), "v"(b));
    return r;
}

#define GLL16(gp, lp) __builtin_amdgcn_global_load_lds( \
    (const __attribute__((address_space(1))) unsigned int*)(gp), \
    (__attribute__((address_space(3))) unsigned int*)(lp), 16, 0, 0)

#define MFMA32(A, B, C) __builtin_amdgcn_mfma_f32_32x32x16_bf16(A, B, C, 0, 0, 0)

// ---------------- K1 (v2): lora down-proj  tq = x@q_a1, tv = x@v_a1 ----------------
__global__ __launch_bounds__(256) void lora1_v2(const float* __restrict__ x,
    const float* __restrict__ qa1, const float* __restrict__ va1,
    float* __restrict__ tq, float* __restrict__ tv) {
    int tid = threadIdx.x;
    int w = tid >> 6;
    int lane = tid & 63;
    int t = blockIdx.x * 4 + w;
    int cg = lane & 7;
    int ks = lane >> 3;
    const float* a1 = (cg < 4) ? qa1 : va1;
    int c4 = (cg & 3) * 4;
    const float* xr = x + (size_t)t * D_DIM + ks * 128;
    const float* ar = a1 + (size_t)(ks * 128) * 16 + c4;
    float4 acc = make_float4(0.f, 0.f, 0.f, 0.f);
#pragma unroll 8
    for (int j = 0; j < 128; ++j) {
        float xv = xr[j];
        float4 av = *(const float4*)&ar[j * 16];
        acc.x = fmaf(xv, av.x, acc.x);
        acc.y = fmaf(xv, av.y, acc.y);
        acc.z = fmaf(xv, av.z, acc.z);
        acc.w = fmaf(xv, av.w, acc.w);
    }
#pragma unroll
    for (int m = 8; m < 64; m <<= 1) {
        acc.x += __shfl_xor(acc.x, m);
        acc.y += __shfl_xor(acc.y, m);
        acc.z += __shfl_xor(acc.z, m);
        acc.w += __shfl_xor(acc.w, m);
    }
    if (lane < 8) {
        float* dst = (cg < 4) ? &tq[t * 16 + c4] : &tv[t * 16 + (cg - 4) * 4];
        *(float4*)dst = acc;
    }
}

// ---------------- prep: split A_aug = [x | tq | tv] into bf16 hi/lo planes [T_TOK][KAUG]
// natural (unswizzled) layout — A is consumed by direct per-lane global loads
__global__ __launch_bounds__(256) void splitA_kernel(const float* __restrict__ x,
    const float* __restrict__ tq, const float* __restrict__ tv,
    unsigned short* __restrict__ ah, unsigned short* __restrict__ al) {
    int idx = blockIdx.x * 256 + threadIdx.x;
    const int total = T_TOK * (KAUG / 4);
    if (idx >= total) return;
    int t = idx / (KAUG / 4);
    int c4 = (idx - t * (KAUG / 4)) * 4;
    float4 v;
    if (c4 < D_DIM)           v = *(const float4*)&x[(size_t)t * D_DIM + c4];
    else if (c4 < D_DIM + 16) v = *(const float4*)&tq[t * 16 + (c4 - D_DIM)];
    else                      v = *(const float4*)&tv[t * 16 + (c4 - D_DIM - 16)];
    ushort4 h, l;
    h.x = f2bf(v.x); l.x = f2bf(v.x - bf2f(h.x));
    h.y = f2bf(v.y); l.y = f2bf(v.y - bf2f(h.y));
    h.z = f2bf(v.z); l.z = f2bf(v.z - bf2f(h.z));
    h.w = f2bf(v.w); l.w = f2bf(v.w - bf2f(h.w));
    *(ushort4*)&ah[(size_t)t * KAUG + c4] = h;
    *(ushort4*)&al[(size_t)t * KAUG + c4] = l;
}

// ---------------- prep: W_aug^T split planes [N3][KAUG], granule-swizzled per 32-k chunk
__global__ __launch_bounds__(256) void splitW_kernel(const float* __restrict__ w,
    const float* __restrict__ qa2, const float* __restrict__ va2,
    unsigned short* __restrict__ bh, unsigned short* __restrict__ bl) {
    __shared__ float T[32][65];
    int bn = blockIdx.x;
    int bk = blockIdx.y;
    int tid = threadIdx.x;
#pragma unroll
    for (int u = 0; u < 2; ++u) {
        int id = tid + 256 * u;
        int kr = id >> 4;
        int n4 = (id & 15) * 4;
        int k = bk * 32 + kr;
        int n = bn * 64 + n4;
        float4 v = make_float4(0.f, 0.f, 0.f, 0.f);
        if (k < D_DIM) {
            v = *(const float4*)&w[(size_t)k * N3 + n];
        } else if (k < D_DIM + 16) {
            if (n < D_DIM) {
                float4 q4 = *(const float4*)&qa2[(k - D_DIM) * D_DIM + n];
                v = make_float4(q4.x * 0.5f, q4.y * 0.5f, q4.z * 0.5f, q4.w * 0.5f);
            }
        } else {
            if (n >= 2 * D_DIM) {
                float4 q4 = *(const float4*)&va2[(k - D_DIM - 16) * D_DIM + (n - 2 * D_DIM)];
                v = make_float4(q4.x * 0.5f, q4.y * 0.5f, q4.z * 0.5f, q4.w * 0.5f);
            }
        }
        T[kr][n4 + 0] = v.x; T[kr][n4 + 1] = v.y;
        T[kr][n4 + 2] = v.z; T[kr][n4 + 3] = v.w;
    }
    __syncthreads();
    int n = tid >> 2;
    int k8 = (tid & 3) * 8;
    unsigned short hh[8], ll[8];
#pragma unroll
    for (int j = 0; j < 8; ++j) {
        float v = T[k8 + j][n];
        hh[j] = f2bf(v);
        ll[j] = f2bf(v - bf2f(hh[j]));
    }
    int nr = bn * 64 + n;
    int gsw = (tid & 3) ^ GHASH(nr);
    size_t ro = (size_t)nr * KAUG + bk * 32 + gsw * 8;
    ushort4 h0, h1, l0, l1;
    h0.x = hh[0]; h0.y = hh[1]; h0.z = hh[2]; h0.w = hh[3];
    h1.x = hh[4]; h1.y = hh[5]; h1.z = hh[6]; h1.w = hh[7];
    l0.x = ll[0]; l0.y = ll[1]; l0.z = ll[2]; l0.w = ll[3];
    l1.x = ll[4]; l1.y = ll[5]; l1.z = ll[6]; l1.w = ll[7];
    *(ushort4*)&bh[ro]     = h0;
    *(ushort4*)&bh[ro + 4] = h1;
    *(ushort4*)&bl[ro]     = l0;
    *(ushort4*)&bl[ro + 4] = l1;
}

// ---------------- prep: c_proj_w -> transposed split planes [1024][1024], swizzled
__global__ __launch_bounds__(256) void wprep_kernel(const float* __restrict__ w,
    unsigned short* __restrict__ bh, unsigned short* __restrict__ bl) {
    __shared__ float T[32][65];
    int bn = blockIdx.x;
    int bk = blockIdx.y;
    int tid = threadIdx.x;
#pragma unroll
    for (int u = 0; u < 2; ++u) {
        int id = tid + 256 * u;
        int kr = id >> 4;
        int n4 = (id & 15) * 4;
        float4 v = *(const float4*)&w[(size_t)(bk * 32 + kr) * D_DIM + bn * 64 + n4];
        T[kr][n4 + 0] = v.x; T[kr][n4 + 1] = v.y;
        T[kr][n4 + 2] = v.z; T[kr][n4 + 3] = v.w;
    }
    __syncthreads();
    int n = tid >> 2;
    int k8 = (tid & 3) * 8;
    unsigned short hh[8], ll[8];
#pragma unroll
    for (int j = 0; j < 8; ++j) {
        float v = T[k8 + j][n];
        hh[j] = f2bf(v);
        ll[j] = f2bf(v - bf2f(hh[j]));
    }
    int nr = bn * 64 + n;
    int gsw = (tid & 3) ^ GHASH(nr);
    size_t ro = (size_t)nr * D_DIM + bk * 32 + gsw * 8;
    ushort4 h0, h1, l0, l1;
    h0.x = hh[0]; h0.y = hh[1]; h0.z = hh[2]; h0.w = hh[3];
    h1.x = hh[4]; h1.y = hh[5]; h1.z = hh[6]; h1.w = hh[7];
    l0.x = ll[0]; l0.y = ll[1]; l0.z = ll[2]; l0.w = ll[3];
    l1.x = ll[4]; l1.y = ll[5]; l1.z = ll[6]; l1.w = ll[7];
    *(ushort4*)&bh[ro]     = h0;
    *(ushort4*)&bh[ro + 4] = h1;
    *(ushort4*)&bl[ro]     = l0;
    *(ushort4*)&bl[ro + 4] = l1;
}

// ---------------- K2 (v2): split-bf16 MFMA GEMM; A direct-from-global, B via LDS (swizzled)
__global__ __launch_bounds__(256, 3) void qkv_mfma(
    const unsigned short* __restrict__ ah_g, const unsigned short* __restrict__ al_g,
    const unsigned short* __restrict__ bh_g, const unsigned short* __restrict__ bl_g,
    const float* __restrict__ bias,
    float* __restrict__ qstage, float* __restrict__ pres) {
    __shared__ unsigned short Bh[128 * 32], Bl[128 * 32];
    // XCD-contiguous remap: 768 blocks = 8 XCDs x 96 (exact, bijective)
    int id = blockIdx.y * 24 + blockIdx.x;
    int nid = (id & 7) * 96 + (id >> 3);
    int bn = nid % 24;
    int bm = nid / 24;
    int tid = threadIdx.x;
    int w = tid >> 6, l = tid & 63;
    int wr = w >> 1, wc = w & 1;

    f32x4 acc[4][4];
#pragma unroll
    for (int i = 0; i < 4; ++i)
#pragma unroll
        for (int j = 0; j < 4; ++j)
            acc[i][j] = (f32x4){0.f, 0.f, 0.f, 0.f};

    int srow = l >> 2;
    int sk = (l & 3) * 8;
    const size_t b_base0 = (size_t)(bn * 128 + w * 32 + srow) * KAUG + sk;
    const size_t b_base1 = b_base0 + (size_t)16 * KAUG;
    unsigned short* pBh0 = &Bh[(w * 32) * 32];
    unsigned short* pBh1 = &Bh[(w * 32 + 16) * 32];
    unsigned short* pBl0 = &Bl[(w * 32) * 32];
    unsigned short* pBl1 = &Bl[(w * 32 + 16) * 32];

    int lrow = l & 15;
    int lg = l >> 4;

    const unsigned short* aH[4];
    const unsigned short* aL[4];
#pragma unroll
    for (int i = 0; i < 4; ++i) {
        int row = bm * 128 + wr * 64 + i * 16 + lrow;
        aH[i] = ah_g + (size_t)row * KAUG + lg * 8;
        aL[i] = al_g + (size_t)row * KAUG + lg * 8;
    }
    int roB[4];
#pragma unroll
    for (int j = 0; j < 4; ++j) {
        int Rb = wc * 64 + j * 16 + lrow;
        roB[j] = Rb * 32 + ((lg ^ GHASH(Rb)) * 8);
    }

    for (int k0 = 0; k0 < KAUG; k0 += 32) {
        __syncthreads();
        GLL16(bh_g + b_base0 + k0, pBh0);
        GLL16(bh_g + b_base1 + k0, pBh1);
        GLL16(bl_g + b_base0 + k0, pBl0);
        GLL16(bl_g + b_base1 + k0, pBl1);
        bf16x8 fa_h[4], fa_l[4];
#pragma unroll
        for (int i = 0; i < 4; ++i) {
            fa_h[i] = *(const bf16x8*)(aH[i] + k0);
            fa_l[i] = *(const bf16x8*)(aL[i] + k0);
        }
        __syncthreads();   // drains vmcnt(0): B in LDS, A in VGPRs

        bf16x8 fb_h[4], fb_l[4];
#pragma unroll
        for (int j = 0; j < 4; ++j) {
            fb_h[j] = *(const bf16x8*)&Bh[roB[j]];
            fb_l[j] = *(const bf16x8*)&Bl[roB[j]];
        }
#pragma unroll
        for (int i = 0; i < 4; ++i)
#pragma unroll
            for (int j = 0; j < 4; ++j) {
                acc[i][j] = __builtin_amdgcn_mfma_f32_16x16x32_bf16(
                    fa_h[i], fb_h[j], acc[i][j], 0, 0, 0);
                acc[i][j] = __builtin_amdgcn_mfma_f32_16x16x32_bf16(
                    fa_h[i], fb_l[j], acc[i][j], 0, 0, 0);
                acc[i][j] = __builtin_amdgcn_mfma_f32_16x16x32_bf16(
                    fa_l[i], fb_h[j], acc[i][j], 0, 0, 0);
            }
    }

    int seg = bn >> 3;
#pragma unroll
    for (int j = 0; j < 4; ++j) {
        int n = bn * 128 + wc * 64 + j * 16 + lrow;
        float bz = bias[n];
        int h = (n >> 6) & 15;
        int d = n & 63;
#pragma unroll
        for (int i = 0; i < 4; ++i) {
            int tbase = bm * 128 + wr * 64 + i * 16 + (l >> 4) * 4;
#pragma unroll
            for (int r = 0; r < 4; ++r) {
                int t = tbase + r;
                float v = acc[i][j][r] + bz;
                int bb = t >> 11, s = t & 2047;
                size_t idx = (((size_t)(bb * NH + h) * S_LEN + s) * HD) + d;
                if (seg == 0)      qstage[idx] = v * 0.125f;
                else if (seg == 1) pres[idx] = v;
                else               pres[OUT_KV_ELEMS + idx] = v;
            }
        }
    }
}

// ---------------- K5 (v2): proj via split-bf16 MFMA; A direct, B via LDS (swizzled)
__global__ __launch_bounds__(256, 3) void proj_mfma(
    const unsigned short* __restrict__ ah_g, const unsigned short* __restrict__ al_g,
    const unsigned short* __restrict__ bh_g, const unsigned short* __restrict__ bl_g,
    const float* __restrict__ bias, float* __restrict__ outp) {
    __shared__ unsigned short Bh[128 * 32], Bl[128 * 32];
    // 256 blocks = 8 x 32 (exact, bijective)
    int id = blockIdx.y * 8 + blockIdx.x;
    int nid = (id & 7) * 32 + (id >> 3);
    int bn = nid % 8;
    int bm = nid / 8;
    int tid = threadIdx.x;
    int w = tid >> 6, l = tid & 63;
    int wr = w >> 1, wc = w & 1;

    f32x4 acc[4][4];
#pragma unroll
    for (int i = 0; i < 4; ++i)
#pragma unroll
        for (int j = 0; j < 4; ++j)
            acc[i][j] = (f32x4){0.f, 0.f, 0.f, 0.f};

    int srow = l >> 2;
    int sk = (l & 3) * 8;
    const size_t b_base0 = (size_t)(bn * 128 + w * 32 + srow) * D_DIM + sk;
    const size_t b_base1 = b_base0 + (size_t)16 * D_DIM;
    unsigned short* pBh0 = &Bh[(w * 32) * 32];
    unsigned short* pBh1 = &Bh[(w * 32 + 16) * 32];
    unsigned short* pBl0 = &Bl[(w * 32) * 32];
    unsigned short* pBl1 = &Bl[(w * 32 + 16) * 32];

    int lrow = l & 15;
    int lg = l >> 4;

    const unsigned short* aH[4];
    const unsigned short* aL[4];
#pragma unroll
    for (int i = 0; i < 4; ++i) {
        int row = bm * 128 + wr * 64 + i * 16 + lrow;
        aH[i] = ah_g + (size_t)row * D_DIM + lg * 8;
        aL[i] = al_g + (size_t)row * D_DIM + lg * 8;
    }
    int roB[4];
#pragma unroll
    for (int j = 0; j < 4; ++j) {
        int Rb = wc * 64 + j * 16 + lrow;
        roB[j] = Rb * 32 + ((lg ^ GHASH(Rb)) * 8);
    }

    for (int k0 = 0; k0 < D_DIM; k0 += 32) {
        __syncthreads();
        GLL16(bh_g + b_base0 + k0, pBh0);
        GLL16(bh_g + b_base1 + k0, pBh1);
        GLL16(bl_g + b_base0 + k0, pBl0);
        GLL16(bl_g + b_base1 + k0, pBl1);
        bf16x8 fa_h[4], fa_l[4];
#pragma unroll
        for (int i = 0; i < 4; ++i) {
            fa_h[i] = *(const bf16x8*)(aH[i] + k0);
            fa_l[i] = *(const bf16x8*)(aL[i] + k0);
        }
        __syncthreads();

        bf16x8 fb_h[4], fb_l[4];
#pragma unroll
        for (int j = 0; j < 4; ++j) {
            fb_h[j] = *(const bf16x8*)&Bh[roB[j]];
            fb_l[j] = *(const bf16x8*)&Bl[roB[j]];
        }
#pragma unroll
        for (int i = 0; i < 4; ++i)
#pragma unroll
            for (int j = 0; j < 4; ++j) {
                acc[i][j] = __builtin_amdgcn_mfma_f32_16x16x32_bf16(
                    fa_h[i], fb_h[j], acc[i][j], 0, 0, 0);
                acc[i][j] = __builtin_amdgcn_mfma_f32_16x16x32_bf16(
                    fa_h[i], fb_l[j], acc[i][j], 0, 0, 0);
                acc[i][j] = __builtin_amdgcn_mfma_f32_16x16x32_bf16(
                    fa_l[i], fb_h[j], acc[i][j], 0, 0, 0);
            }
    }

#pragma unroll
    for (int j = 0; j < 4; ++j) {
        int n = bn * 128 + wc * 64 + j * 16 + lrow;
        float bz = bias[n];
#pragma unroll
        for (int i = 0; i < 4; ++i) {
            int tbase = bm * 128 + wr * 64 + i * 16 + (l >> 4) * 4;
#pragma unroll
            for (int r = 0; r < 4; ++r)
                outp[(size_t)(tbase + r) * D_DIM + n] = acc[i][j][r] + bz;
        }
    }
}

// ---------------- prep: K rows -> swizzled bf16 hi/lo planes [bh][key][64]
__global__ __launch_bounds__(256) void kprep_kernel(const float* __restrict__ kin,
    unsigned short* __restrict__ khp, unsigned short* __restrict__ klp) {
    int id = blockIdx.x * 256 + threadIdx.x;
    int rowi = id >> 3;
    int gsrc = id & 7;
    const float* src = kin + (size_t)rowi * 64 + gsrc * 8;
    float4 v0 = *(const float4*)src;
    float4 v1 = *(const float4*)(src + 4);
    int key = rowi & 2047;
    int gp = gsrc ^ (key & 7);
    size_t dst = (size_t)rowi * 64 + gp * 8;
    float vv[8] = {v0.x, v0.y, v0.z, v0.w, v1.x, v1.y, v1.z, v1.w};
    bf16x8 h, lo;
#pragma unroll
    for (int j = 0; j < 8; ++j) {
        unsigned short hh = f2bf(vv[j]);
        h[j] = (short)hh;
        lo[j] = (short)f2bf(vv[j] - bf2f(hh));
    }
    *(bf16x8*)&khp[dst] = h;
    *(bf16x8*)&klp[dst] = lo;
}

// ---------------- prep: V -> transposed swizzled bf16 hi/lo planes [bh][d][key]
__global__ __launch_bounds__(256) void vtprep_kernel(const float* __restrict__ vin,
    unsigned short* __restrict__ vth, unsigned short* __restrict__ vtl) {
    __shared__ __align__(16) unsigned short Th[64][72];
    __shared__ __align__(16) unsigned short Tl[64][72];
    int bh = blockIdx.x;
    int kv0 = blockIdx.y * 64;
    int tid = threadIdx.x;
#pragma unroll
    for (int p = 0; p < 4; ++p) {
        int key = (tid >> 4) + 16 * p;
        int d0 = (tid & 15) * 4;
        float4 v = *(const float4*)&vin[((size_t)bh * 2048 + kv0 + key) * 64 + d0];
        float vv[4] = {v.x, v.y, v.z, v.w};
#pragma unroll
        for (int j = 0; j < 4; ++j) {
            unsigned short hh = f2bf(vv[j]);
            Th[d0 + j][key] = hh;
            Tl[d0 + j][key] = f2bf(vv[j] - bf2f(hh));
        }
    }
    __syncthreads();
    int d = tid >> 2;
#pragma unroll
    for (int q = 0; q < 2; ++q) {
        int gg = (tid & 3) + 4 * q;
        int gs = gg ^ (d & 7);
        bf16x8 hv = *(const bf16x8*)&Th[d][gs * 8];
        bf16x8 lv = *(const bf16x8*)&Tl[d][gs * 8];
        size_t dst = ((size_t)bh * 64 + d) * 2048 + kv0 + gg * 8;
        *(bf16x8*)&vth[dst] = hv;
        *(bf16x8*)&vtl[dst] = lv;
    }
}

// ---------------- K3: MFMA flash attention, 32x32x16, swapped QK^T ----------------
__device__ __forceinline__ void stage_tile(
    const unsigned short* __restrict__ kh, const unsigned short* __restrict__ kl,
    const unsigned short* __restrict__ vh, const unsigned short* __restrict__ vl,
    unsigned short (*ldsb)[4096], int w, int l, int bh, int kv0) {
    if (w < 2) {
        const unsigned short* gp = (w == 0 ? kh : kl)
            + ((size_t)bh * 2048 + kv0 + (l >> 3)) * 64 + (l & 7) * 8;
        unsigned short* lp = ldsb[w];
#pragma unroll
        for (int i = 0; i < 8; ++i)
            GLL16(gp + i * 512, lp + i * 512);
    } else {
        const unsigned short* gp = (w == 2 ? vh : vl)
            + ((size_t)bh * 64 + (l >> 3)) * 2048 + kv0 + (l & 7) * 8;
        unsigned short* lp = ldsb[w];
#pragma unroll
        for (int i = 0; i < 8; ++i)
            GLL16(gp + (size_t)i * 16384, lp + i * 512);
    }
}

#define QROW(r) ((((r) & 3) + 8 * ((r) >> 2)) + 4 * g)

__global__ __launch_bounds__(256, 2) void attn_mfma(
    const float* __restrict__ q_s,
    const unsigned short* __restrict__ kh, const unsigned short* __restrict__ kl,
    const unsigned short* __restrict__ vh, const unsigned short* __restrict__ vl,
    unsigned short* __restrict__ aout_h, unsigned short* __restrict__ aout_l) {
    __shared__ __align__(16) unsigned short lds[2][4][4096];   // 64 KB
    int bh = blockIdx.x;
    int qi = (int)gridDim.y - 1 - blockIdx.y;
    int tid = threadIdx.x;
    int w = tid >> 6, l = tid & 63;
    int qloc = l & 31, g = l >> 5;
    int q0 = qi * 128;
    int qg = q0 + w * 32 + qloc;

    bf16x8 qf[4];
    {
        const float* qrow = q_s + ((size_t)bh * S_LEN + qg) * HD;
#pragma unroll
        for (int t = 0; t < 4; ++t) {
            float4 u0 = *(const float4*)&qrow[t * 16 + g * 8];
            float4 u1 = *(const float4*)&qrow[t * 16 + g * 8 + 4];
            float vv[8] = {u0.x, u0.y, u0.z, u0.w, u1.x, u1.y, u1.z, u1.w};
            bf16x8 r;
#pragma unroll
            for (int j = 0; j < 8; ++j) r[j] = (short)f2bf(vv[j]);
            qf[t] = r;
        }
    }

    f32x16 o0, o1;
#pragma unroll
    for (int r = 0; r < 16; ++r) { o0[r] = 0.f; o1[r] = 0.f; }
    float m_run = -1e30f, l_run = 0.f;

    int nt = 2 * qi + 2;
    int qwmax = q0 + w * 32 + 31;

    stage_tile(kh, kl, vh, vl, lds[0], w, l, bh, 0);
    __syncthreads();

    for (int t = 0; t < nt; ++t) {
        int kv0 = t * 64;
        int bi = t & 1;
        if (t + 1 < nt)
            stage_tile(kh, kl, vh, vl, lds[bi ^ 1], w, l, bh, (t + 1) * 64);

        if (kv0 <= qwmax) {
            const unsigned short* Khp = lds[bi][0];
            const unsigned short* Klp = lds[bi][1];
            const unsigned short* Vhp = lds[bi][2];
            const unsigned short* Vlp = lds[bi][3];

            f32x16 s0, s1;
#pragma unroll
            for (int r = 0; r < 16; ++r) { s0[r] = 0.f; s1[r] = 0.f; }

            __builtin_amdgcn_s_setprio(1);
#pragma unroll
            for (int tt = 0; tt < 4; ++tt) {
                int gr = ((2 * tt + g) ^ (qloc & 7)) * 8;
                bf16x8 a0h = *(const bf16x8*)&Khp[qloc * 64 + gr];
                bf16x8 a1h = *(const bf16x8*)&Khp[(32 + qloc) * 64 + gr];
                bf16x8 a0l = *(const bf16x8*)&Klp[qloc * 64 + gr];
                bf16x8 a1l = *(const bf16x8*)&Klp[(32 + qloc) * 64 + gr];
                s0 = MFMA32(a0h, qf[tt], s0);
                s0 = MFMA32(a0l, qf[tt], s0);
                s1 = MFMA32(a1h, qf[tt], s1);
                s1 = MFMA32(a1l, qf[tt], s1);
            }
            __builtin_amdgcn_s_setprio(0);

            if (kv0 + 63 > q0 + w * 32) {
#pragma unroll
                for (int r = 0; r < 16; ++r) {
                    int kk = kv0 + QROW(r);
                    if (kk > qg)      s0[r] = -1e30f;
                    if (kk + 32 > qg) s1[r] = -1e30f;
                }
            }

            float mx = s0[0];
#pragma unroll
            for (int r = 1; r < 16; ++r) mx = fmaxf(mx, s0[r]);
#pragma unroll
            for (int r = 0; r < 16; ++r) mx = fmaxf(mx, s1[r]);
            mx = fmaxf(mx, __shfl_xor(mx, 32));
            float mnew = fmaxf(m_run, mx);
            float al = __expf(m_run - mnew);
            m_run = mnew;
            float rs = 0.f;
#pragma unroll
            for (int r = 0; r < 16; ++r) { s0[r] = __expf(s0[r] - mnew); rs += s0[r]; }
#pragma unroll
            for (int r = 0; r < 16; ++r) { s1[r] = __expf(s1[r] - mnew); rs += s1[r]; }
            rs += __shfl_xor(rs, 32);
            l_run = l_run * al + rs;
#pragma unroll
            for (int r = 0; r < 16; ++r) {
                float ar = __shfl(al, QROW(r));
                o0[r] *= ar; o1[r] *= ar;
            }

            __builtin_amdgcn_s_setprio(1);
#pragma unroll
            for (int ks = 0; ks < 4; ++ks) {
                const int b = (ks & 1) * 8;
                unsigned w0, w1, w2, w3;
                if (ks < 2) {
                    w0 = cvtpk(s0[b + 0], s0[b + 1]);
                    w1 = cvtpk(s0[b + 2], s0[b + 3]);
                    w2 = cvtpk(s0[b + 4], s0[b + 5]);
                    w3 = cvtpk(s0[b + 6], s0[b + 7]);
                } else {
                    w0 = cvtpk(s1[b + 0], s1[b + 1]);
                    w1 = cvtpk(s1[b + 2], s1[b + 3]);
                    w2 = cvtpk(s1[b + 4], s1[b + 5]);
                    w3 = cvtpk(s1[b + 6], s1[b + 7]);
                }
                asm("v_permlane32_swap_b32 %0, %1" : "+v"(w0), "+v"(w2));
                asm("v_permlane32_swap_b32 %0, %1" : "+v"(w1), "+v"(w3));
                U4 u; u.u[0] = w0; u.u[1] = w1; u.u[2] = w2; u.u[3] = w3;
                bf16x8 pa = u.v;
                int gr = ((2 * ks + g) ^ (qloc & 7)) * 8;
                bf16x8 v0h = *(const bf16x8*)&Vhp[qloc * 64 + gr];
                bf16x8 v1h = *(const bf16x8*)&Vhp[(32 + qloc) * 64 + gr];
                bf16x8 v0l = *(const bf16x8*)&Vlp[qloc * 64 + gr];
                bf16x8 v1l = *(const bf16x8*)&Vlp[(32 + qloc) * 64 + gr];
                o0 = MFMA32(pa, v0h, o0);
                o0 = MFMA32(pa, v0l, o0);
                o1 = MFMA32(pa, v1h, o1);
                o1 = MFMA32(pa, v1l, o1);
            }
            __builtin_amdgcn_s_setprio(0);
        }
        __syncthreads();
    }

    int bb = bh >> 4, h = bh & 15;
#pragma unroll
    for (int r = 0; r < 16; ++r) {
        float li = __shfl(l_run, QROW(r));
        float inv = 1.f / li;
        int qq = q0 + w * 32 + QROW(r);
        size_t base = ((size_t)(bb * S_LEN + qq)) * D_DIM + h * HD + qloc;
        float v0 = o0[r] * inv;
        float v1 = o1[r] * inv;
        unsigned short h0 = f2bf(v0);
        unsigned short h1 = f2bf(v1);
        aout_h[base]      = h0;
        aout_l[base]      = f2bf(v0 - bf2f(h0));
        aout_h[base + 32] = h1;
        aout_l[base + 32] = f2bf(v1 - bf2f(h1));
    }
}

// ---------------- K3 fallback: f32 flash attention ----------------
#define LSTR 68
__global__ __launch_bounds__(256) void attn_kernel(const float* __restrict__ q_s,
    const float* __restrict__ k_s, const float* __restrict__ v_s,
    float* __restrict__ a_s) {
    __shared__ float Qt[64][LSTR];
    __shared__ float KP[64][LSTR];
    __shared__ float Vs[64][LSTR];
    int bh = blockIdx.x;
    int qi = 31 - blockIdx.y;
    int tid = threadIdx.x;
    int tx = tid & 15, ty = tid >> 4;

#pragma unroll
    for (int qq = 0; qq < 4; ++qq) {
        int q  = qq * 16 + (tid >> 4);
        int d4 = (tid & 15) * 4;
        float4 v = *(const float4*)&q_s[((size_t)bh * S_LEN + qi * 64 + q) * HD + d4];
        Qt[d4 + 0][q] = v.x; Qt[d4 + 1][q] = v.y;
        Qt[d4 + 2][q] = v.z; Qt[d4 + 3][q] = v.w;
    }

    float o[4][4];
#pragma unroll
    for (int r = 0; r < 4; ++r)
#pragma unroll
        for (int c = 0; c < 4; ++c) o[r][c] = 0.f;
    float mrow[4] = {-1e30f, -1e30f, -1e30f, -1e30f};
    float lrow[4] = {0.f, 0.f, 0.f, 0.f};

    for (int kt = 0; kt <= qi; ++kt) {
        __syncthreads();
#pragma unroll
        for (int kk2 = 0; kk2 < 4; ++kk2) {
            int k  = kk2 * 16 + (tid >> 4);
            int d4 = (tid & 15) * 4;
            size_t rowoff = ((size_t)bh * S_LEN + kt * 64 + k) * HD + d4;
            float4 kv4 = *(const float4*)&k_s[rowoff];
            KP[d4 + 0][k] = kv4.x; KP[d4 + 1][k] = kv4.y;
            KP[d4 + 2][k] = kv4.z; KP[d4 + 3][k] = kv4.w;
            float4 vv4 = *(const float4*)&v_s[rowoff];
            *(float4*)&Vs[k][d4] = vv4;
        }
        __syncthreads();

        float s[4][4];
#pragma unroll
        for (int r = 0; r < 4; ++r)
#pragma unroll
            for (int c = 0; c < 4; ++c) s[r][c] = 0.f;
#pragma unroll 8
        for (int d = 0; d < 64; ++d) {
            float4 qv = *(const float4*)&Qt[d][ty * 4];
            float4 kv = *(const float4*)&KP[d][tx * 4];
            float qa[4] = {qv.x, qv.y, qv.z, qv.w};
            float ka[4] = {kv.x, kv.y, kv.z, kv.w};
#pragma unroll
            for (int r = 0; r < 4; ++r)
#pragma unroll
                for (int c = 0; c < 4; ++c)
                    s[r][c] = fmaf(qa[r], ka[c], s[r][c]);
        }
        if (kt == qi) {
#pragma unroll
            for (int r = 0; r < 4; ++r)
#pragma unroll
                for (int c = 0; c < 4; ++c)
                    if (tx * 4 + c > ty * 4 + r) s[r][c] = -1e30f;
        }
        __syncthreads();

        float p[4][4];
#pragma unroll
        for (int r = 0; r < 4; ++r) {
            float mx = fmaxf(fmaxf(s[r][0], s[r][1]), fmaxf(s[r][2], s[r][3]));
            mx = fmaxf(mx, __shfl_xor(mx, 1));
            mx = fmaxf(mx, __shfl_xor(mx, 2));
            mx = fmaxf(mx, __shfl_xor(mx, 4));
            mx = fmaxf(mx, __shfl_xor(mx, 8));
            float mn = fmaxf(mrow[r], mx);
            float alpha = __expf(mrow[r] - mn);
            mrow[r] = mn;
            float rsum = 0.f;
#pragma unroll
            for (int c = 0; c < 4; ++c) {
                p[r][c] = __expf(s[r][c] - mn);
                rsum += p[r][c];
            }
            rsum += __shfl_xor(rsum, 1);
            rsum += __shfl_xor(rsum, 2);
            rsum += __shfl_xor(rsum, 4);
            rsum += __shfl_xor(rsum, 8);
            lrow[r] = lrow[r] * alpha + rsum;
#pragma unroll
            for (int c = 0; c < 4; ++c) o[r][c] *= alpha;
            *(float4*)&KP[ty * 4 + r][tx * 4] =
                make_float4(p[r][0], p[r][1], p[r][2], p[r][3]);
        }
        __syncthreads();

#pragma unroll 8
        for (int k = 0; k < 64; ++k) {
            float4 vv = *(const float4*)&Vs[k][tx * 4];
            float va[4] = {vv.x, vv.y, vv.z, vv.w};
#pragma unroll
            for (int r = 0; r < 4; ++r) {
                float pr = KP[ty * 4 + r][k];
#pragma unroll
                for (int c = 0; c < 4; ++c)
                    o[r][c] = fmaf(pr, va[c], o[r][c]);
            }
        }
    }

    int b = bh >> 4, h = bh & 15;
#pragma unroll
    for (int r = 0; r < 4; ++r) {
        int i = qi * 64 + ty * 4 + r;
        float inv = 1.f / lrow[r];
        *(float4*)&a_s[((size_t)(b * S_LEN + i)) * D_DIM + h * HD + tx * 4] =
            make_float4(o[r][0] * inv, o[r][1] * inv, o[r][2] * inv, o[r][3] * inv);
    }
}

// ------ K2 fallback (old fp32 path) ------
__global__ __launch_bounds__(256) void qkv_kernel(const float* __restrict__ x,
    const float* __restrict__ w, const float* __restrict__ bias,
    const float* __restrict__ qa2, const float* __restrict__ va2,
    const float* __restrict__ tq, const float* __restrict__ tv,
    float* __restrict__ qstage, float* __restrict__ pres) {
    __shared__ float As[128][17];
    __shared__ float Bs[16][64];
    int bx = blockIdx.x;
    int by = blockIdx.y;
    int tid = threadIdx.x;
    int tx = tid & 15, ty = tid >> 4;

    float c[8][4];
#pragma unroll
    for (int i = 0; i < 8; ++i)
#pragma unroll
        for (int j = 0; j < 4; ++j) c[i][j] = 0.f;

    for (int k0 = 0; k0 < D_DIM; k0 += 16) {
#pragma unroll
        for (int u = 0; u < 2; ++u) {
            int f4 = tid + 256 * u;
            int row = f4 >> 2;
            int kk4 = (f4 & 3) * 4;
            float4 av = *(const float4*)&x[(size_t)(by * 128 + row) * D_DIM + k0 + kk4];
            As[row][kk4 + 0] = av.x; As[row][kk4 + 1] = av.y;
            As[row][kk4 + 2] = av.z; As[row][kk4 + 3] = av.w;
        }
        {
            int kkb = tid >> 4;
            int col4 = (tid & 15) * 4;
            *(float4*)&Bs[kkb][col4] =
                *(const float4*)&w[(size_t)(k0 + kkb) * N3 + bx * 64 + col4];
        }
        __syncthreads();
#pragma unroll
        for (int kk = 0; kk < 16; ++kk) {
            float4 bv = *(const float4*)&Bs[kk][tx * 4];
#pragma unroll
            for (int i = 0; i < 8; ++i) {
                float a = As[ty * 8 + i][kk];
                c[i][0] = fmaf(a, bv.x, c[i][0]);
                c[i][1] = fmaf(a, bv.y, c[i][1]);
                c[i][2] = fmaf(a, bv.z, c[i][2]);
                c[i][3] = fmaf(a, bv.w, c[i][3]);
            }
        }
        __syncthreads();
    }

    int seg = bx >> 4;
    int h = bx & 15;
    int ncol = bx * 64 + tx * 4;
    float4 bias4 = *(const float4*)&bias[ncol];
    int nloc = h * 64 + tx * 4;

    float4 arr[16];
    if (seg != 1) {
        const float* a2 = (seg == 0 ? qa2 : va2);
#pragma unroll
        for (int jj = 0; jj < 16; ++jj)
            arr[jj] = *(const float4*)&a2[jj * D_DIM + nloc];
    }

#pragma unroll
    for (int i = 0; i < 8; ++i) {
        int t = by * 128 + ty * 8 + i;
        float v0 = c[i][0] + bias4.x;
        float v1 = c[i][1] + bias4.y;
        float v2 = c[i][2] + bias4.z;
        float v3 = c[i][3] + bias4.w;
        if (seg != 1) {
            const float* trow = (seg == 0 ? tq : tv) + t * 16;
            float l0 = 0.f, l1 = 0.f, l2 = 0.f, l3 = 0.f;
#pragma unroll
            for (int jj = 0; jj < 16; ++jj) {
                float tvv = trow[jj];
                l0 = fmaf(tvv, arr[jj].x, l0);
                l1 = fmaf(tvv, arr[jj].y, l1);
                l2 = fmaf(tvv, arr[jj].z, l2);
                l3 = fmaf(tvv, arr[jj].w, l3);
            }
            v0 += 0.5f * l0; v1 += 0.5f * l1; v2 += 0.5f * l2; v3 += 0.5f * l3;
        }
        int b = t >> 11, sidx = t & 2047;
        size_t idx = (((size_t)(b * NH + h) * S_LEN + sidx) * HD) + tx * 4;
        if (seg == 0) {
            *(float4*)&qstage[idx] = make_float4(v0 * 0.125f, v1 * 0.125f,
                                                 v2 * 0.125f, v3 * 0.125f);
        } else if (seg == 1) {
            *(float4*)&pres[idx] = make_float4(v0, v1, v2, v3);
        } else {
            *(float4*)&pres[OUT_KV_ELEMS + idx] = make_float4(v0, v1, v2, v3);
        }
    }
}

// ---------------- K4 fallback: f32 proj ----------------
__global__ __launch_bounds__(256) void proj_kernel(const float* __restrict__ A,
    const float* __restrict__ w, const float* __restrict__ bias,
    float* __restrict__ outp) {
    __shared__ float As[128][17];
    __shared__ float Bs[16][64];
    int bx = blockIdx.x;
    int by = blockIdx.y;
    int tid = threadIdx.x;
    int tx = tid & 15, ty = tid >> 4;

    float c[8][4];
#pragma unroll
    for (int i = 0; i < 8; ++i)
#pragma unroll
        for (int j = 0; j < 4; ++j) c[i][j] = 0.f;

    for (int k0 = 0; k0 < D_DIM; k0 += 16) {
#pragma unroll
        for (int u = 0; u < 2; ++u) {
            int f4 = tid + 256 * u;
            int row = f4 >> 2;
            int kk4 = (f4 & 3) * 4;
            float4 av = *(const float4*)&A[(size_t)(by * 128 + row) * D_DIM + k0 + kk4];
            As[row][kk4 + 0] = av.x; As[row][kk4 + 1] = av.y;
            As[row][kk4 + 2] = av.z; As[row][kk4 + 3] = av.w;
        }
        {
            int kkb = tid >> 4;
            int col4 = (tid & 15) * 4;
            *(float4*)&Bs[kkb][col4] =
                *(const float4*)&w[(size_t)(k0 + kkb) * D_DIM + bx * 64 + col4];
        }
        __syncthreads();
#pragma unroll
        for (int kk = 0; kk < 16; ++kk) {
            float4 bv = *(const float4*)&Bs[kk][tx * 4];
#pragma unroll
            for (int i = 0; i < 8; ++i) {
                float a = As[ty * 8 + i][kk];
                c[i][0] = fmaf(a, bv.x, c[i][0]);
                c[i][1] = fmaf(a, bv.y, c[i][1]);
                c[i][2] = fmaf(a, bv.z, c[i][2]);
                c[i][3] = fmaf(a, bv.w, c[i][3]);
            }
        }
        __syncthreads();
    }

    int ncol = bx * 64 + tx * 4;
    float4 bias4 = *(const float4*)&bias[ncol];
#pragma unroll
    for (int i = 0; i < 8; ++i) {
        int t = by * 128 + ty * 8 + i;
        *(float4*)&outp[(size_t)t * D_DIM + ncol] =
            make_float4(c[i][0] + bias4.x, c[i][1] + bias4.y,
                        c[i][2] + bias4.z, c[i][3] + bias4.w);
    }
}

extern "C" void kernel_launch(void* const* d_in, const int* in_sizes, int n_in,
                              void* d_out, int out_size, void* d_ws, size_t ws_size,
                              hipStream_t stream) {
    const float* x        = (const float*)d_in[0];
    const float* c_attn_w = (const float*)d_in[1];
    const float* c_attn_b = (const float*)d_in[2];
    const float* c_proj_w = (const float*)d_in[3];
    const float* c_proj_b = (const float*)d_in[4];
    const float* q_a1     = (const float*)d_in[5];
    const float* q_a2     = (const float*)d_in[6];
    const float* v_a1     = (const float*)d_in[7];
    const float* v_a2     = (const float*)d_in[8];

    float* outf   = (float*)d_out;
    float* qstage = outf;                  // a-region reused as f32 q staging [B,H,S,hd]
    float* pres   = outf + OUT_A_ELEMS;    // present [2,B,H,S,hd] f32

    char* wsb = (char*)d_ws;
    float* tq = (float*)wsb;
    float* tv = (float*)(wsb + 262144);
    unsigned short* wt_hi = (unsigned short*)(wsb + 524288);
    unsigned short* wt_lo = (unsigned short*)(wsb + 524288 + 6488064);
    unsigned short* a_hi  = (unsigned short*)(wsb + 13500416);
    unsigned short* a_lo  = (unsigned short*)(wsb + 13500416 + 8650752);
    unsigned short* kp_h  = (unsigned short*)wsb;
    unsigned short* kp_l  = (unsigned short*)(wsb + 8388608);
    unsigned short* vt_h  = (unsigned short*)(wsb + 16777216);
    unsigned short* vt_l  = (unsigned short*)(wsb + 25165824);
    unsigned short* aout_h = (unsigned short*)(wsb + 33554432);
    unsigned short* aout_l = (unsigned short*)(wsb + 41943040);
    unsigned short* wp_h  = (unsigned short*)wsb;
    unsigned short* wp_l  = (unsigned short*)(wsb + 2097152);
    const size_t WS_FULL = 50331648;
    const size_t WS_MID  = 30801920;

    lora1_v2<<<dim3(1024), dim3(256), 0, stream>>>(x, q_a1, v_a1, tq, tv);

    if (ws_size >= WS_FULL) {
        splitA_kernel<<<dim3((T_TOK * (KAUG / 4) + 255) / 256), dim3(256), 0, stream>>>(
            x, tq, tv, a_hi, a_lo);
        splitW_kernel<<<dim3(48, KAUG / 32), dim3(256), 0, stream>>>(
            c_attn_w, q_a2, v_a2, wt_hi, wt_lo);
        qkv_mfma<<<dim3(24, 32), dim3(256), 0, stream>>>(
            a_hi, a_lo, wt_hi, wt_lo, c_attn_b, qstage, pres);
        kprep_kernel<<<dim3(2048), dim3(256), 0, stream>>>(pres, kp_h, kp_l);
        vtprep_kernel<<<dim3(32, 32), dim3(256), 0, stream>>>(
            pres + OUT_KV_ELEMS, vt_h, vt_l);
        attn_mfma<<<dim3(32, 16), dim3(256), 0, stream>>>(
            qstage, kp_h, kp_l, vt_h, vt_l, aout_h, aout_l);
        wprep_kernel<<<dim3(16, 32), dim3(256), 0, stream>>>(c_proj_w, wp_h, wp_l);
        proj_mfma<<<dim3(8, 32), dim3(256), 0, stream>>>(
            aout_h, aout_l, wp_h, wp_l, c_proj_b, outf);
    } else if (ws_size >= WS_MID) {
        float* a_s = (float*)(wsb + 13500416);
        splitA_kernel<<<dim3((T_TOK * (KAUG / 4) + 255) / 256), dim3(256), 0, stream>>>(
            x, tq, tv, a_hi, a_lo);
        splitW_kernel<<<dim3(48, KAUG / 32), dim3(256), 0, stream>>>(
            c_attn_w, q_a2, v_a2, wt_hi, wt_lo);
        qkv_mfma<<<dim3(24, 32), dim3(256), 0, stream>>>(
            a_hi, a_lo, wt_hi, wt_lo, c_attn_b, qstage, pres);
        attn_kernel<<<dim3(32, 32), dim3(256), 0, stream>>>(
            qstage, pres, pres + OUT_KV_ELEMS, a_s);
        proj_kernel<<<dim3(16, 32), dim3(256), 0, stream>>>(
            a_s, c_proj_w, c_proj_b, outf);
    } else {
        float* a_s2 = tv + 65536;
        qkv_kernel<<<dim3(48, 32), dim3(256), 0, stream>>>(x, c_attn_w, c_attn_b,
            q_a2, v_a2, tq, tv, qstage, pres);
        attn_kernel<<<dim3(32, 32), dim3(256), 0, stream>>>(
            qstage, pres, pres + OUT_KV_ELEMS, a_s2);
        proj_kernel<<<dim3(16, 32), dim3(256), 0, stream>>>(
            a_s2, c_proj_w, c_proj_b, outf);
    }
}

// Round 5
// 364.097 us; speedup vs baseline: 1.0180x; 1.0180x over previous
//
#include <hip/hip_runtime.h>

#define T_TOK 4096   // B*S
#define D_DIM 1024
#define N3    3072
#define S_LEN 2048
#define NH    16
#define HD    64
#define KAUG  1056   // 1024 + 16 (q-lora) + 16 (v-lora)

#define OUT_A_ELEMS   4194304   // B*S*D   (f32 elements)
#define OUT_KV_ELEMS  4194304   // B*H*S*hd

typedef __attribute__((ext_vector_type(8))) short bf16x8;
typedef __attribute__((ext_vector_type(4))) float f32x4;
typedef __attribute__((ext_vector_type(16))) float f32x16;

union U4 { unsigned u[4]; bf16x8 v; };

// granule-position hash for LDS bank-conflict-free B tiles (row stride 64 B)
#define GHASH(r) ((((r) >> 1) ^ ((r) >> 3)) & 3)

__device__ __forceinline__ unsigned short f2bf(float f) {
    unsigned u = __float_as_uint(f);
    u += 0x7FFFu + ((u >> 16) & 1u);
    return (unsigned short)(u >> 16);
}
__device__ __forceinline__ float bf2f(unsigned short h) {
    return __uint_as_float(((unsigned)h) << 16);
}
__device__ __forceinline__ unsigned cvtpk(float a, float b) {
    unsigned r;
    asm("v_cvt_pk_bf16_f32 %0, %1, %2" : "=v"(r) : "v"(a), "v"(b));
    return r;
}

#define GLL16(gp, lp) __builtin_amdgcn_global_load_lds( \
    (const __attribute__((address_space(1))) unsigned int*)(gp), \
    (__attribute__((address_space(3))) unsigned int*)(lp), 16, 0, 0)

#define MFMA32(A, B, C) __builtin_amdgcn_mfma_f32_32x32x16_bf16(A, B, C, 0, 0, 0)

// ---------------- K1 (v2): lora down-proj  tq = x@q_a1, tv = x@v_a1 ----------------
__global__ __launch_bounds__(256) void lora1_v2(const float* __restrict__ x,
    const float* __restrict__ qa1, const float* __restrict__ va1,
    float* __restrict__ tq, float* __restrict__ tv) {
    int tid = threadIdx.x;
    int w = tid >> 6;
    int lane = tid & 63;
    int t = blockIdx.x * 4 + w;
    int cg = lane & 7;
    int ks = lane >> 3;
    const float* a1 = (cg < 4) ? qa1 : va1;
    int c4 = (cg & 3) * 4;
    const float* xr = x + (size_t)t * D_DIM + ks * 128;
    const float* ar = a1 + (size_t)(ks * 128) * 16 + c4;
    float4 acc = make_float4(0.f, 0.f, 0.f, 0.f);
#pragma unroll 8
    for (int j = 0; j < 128; ++j) {
        float xv = xr[j];
        float4 av = *(const float4*)&ar[j * 16];
        acc.x = fmaf(xv, av.x, acc.x);
        acc.y = fmaf(xv, av.y, acc.y);
        acc.z = fmaf(xv, av.z, acc.z);
        acc.w = fmaf(xv, av.w, acc.w);
    }
#pragma unroll
    for (int m = 8; m < 64; m <<= 1) {
        acc.x += __shfl_xor(acc.x, m);
        acc.y += __shfl_xor(acc.y, m);
        acc.z += __shfl_xor(acc.z, m);
        acc.w += __shfl_xor(acc.w, m);
    }
    if (lane < 8) {
        float* dst = (cg < 4) ? &tq[t * 16 + c4] : &tv[t * 16 + (cg - 4) * 4];
        *(float4*)dst = acc;
    }
}

// ---------------- prep: split A_aug = [x | tq | tv] into bf16 hi/lo planes [T_TOK][KAUG]
__global__ __launch_bounds__(256) void splitA_kernel(const float* __restrict__ x,
    const float* __restrict__ tq, const float* __restrict__ tv,
    unsigned short* __restrict__ ah, unsigned short* __restrict__ al) {
    int idx = blockIdx.x * 256 + threadIdx.x;
    const int total = T_TOK * (KAUG / 4);
    if (idx >= total) return;
    int t = idx / (KAUG / 4);
    int c4 = (idx - t * (KAUG / 4)) * 4;
    float4 v;
    if (c4 < D_DIM)           v = *(const float4*)&x[(size_t)t * D_DIM + c4];
    else if (c4 < D_DIM + 16) v = *(const float4*)&tq[t * 16 + (c4 - D_DIM)];
    else                      v = *(const float4*)&tv[t * 16 + (c4 - D_DIM - 16)];
    ushort4 h, l;
    h.x = f2bf(v.x); l.x = f2bf(v.x - bf2f(h.x));
    h.y = f2bf(v.y); l.y = f2bf(v.y - bf2f(h.y));
    h.z = f2bf(v.z); l.z = f2bf(v.z - bf2f(h.z));
    h.w = f2bf(v.w); l.w = f2bf(v.w - bf2f(h.w));
    *(ushort4*)&ah[(size_t)t * KAUG + c4] = h;
    *(ushort4*)&al[(size_t)t * KAUG + c4] = l;
}

// ---------------- prep: W_aug^T split planes [N3][KAUG], granule-swizzled per 32-k chunk
__global__ __launch_bounds__(256) void splitW_kernel(const float* __restrict__ w,
    const float* __restrict__ qa2, const float* __restrict__ va2,
    unsigned short* __restrict__ bh, unsigned short* __restrict__ bl) {
    __shared__ float T[32][65];
    int bn = blockIdx.x;
    int bk = blockIdx.y;
    int tid = threadIdx.x;
#pragma unroll
    for (int u = 0; u < 2; ++u) {
        int id = tid + 256 * u;
        int kr = id >> 4;
        int n4 = (id & 15) * 4;
        int k = bk * 32 + kr;
        int n = bn * 64 + n4;
        float4 v = make_float4(0.f, 0.f, 0.f, 0.f);
        if (k < D_DIM) {
            v = *(const float4*)&w[(size_t)k * N3 + n];
        } else if (k < D_DIM + 16) {
            if (n < D_DIM) {
                float4 q4 = *(const float4*)&qa2[(k - D_DIM) * D_DIM + n];
                v = make_float4(q4.x * 0.5f, q4.y * 0.5f, q4.z * 0.5f, q4.w * 0.5f);
            }
        } else {
            if (n >= 2 * D_DIM) {
                float4 q4 = *(const float4*)&va2[(k - D_DIM - 16) * D_DIM + (n - 2 * D_DIM)];
                v = make_float4(q4.x * 0.5f, q4.y * 0.5f, q4.z * 0.5f, q4.w * 0.5f);
            }
        }
        T[kr][n4 + 0] = v.x; T[kr][n4 + 1] = v.y;
        T[kr][n4 + 2] = v.z; T[kr][n4 + 3] = v.w;
    }
    __syncthreads();
    int n = tid >> 2;
    int k8 = (tid & 3) * 8;
    unsigned short hh[8], ll[8];
#pragma unroll
    for (int j = 0; j < 8; ++j) {
        float v = T[k8 + j][n];
        hh[j] = f2bf(v);
        ll[j] = f2bf(v - bf2f(hh[j]));
    }
    int nr = bn * 64 + n;
    int gsw = (tid & 3) ^ GHASH(nr);
    size_t ro = (size_t)nr * KAUG + bk * 32 + gsw * 8;
    ushort4 h0, h1, l0, l1;
    h0.x = hh[0]; h0.y = hh[1]; h0.z = hh[2]; h0.w = hh[3];
    h1.x = hh[4]; h1.y = hh[5]; h1.z = hh[6]; h1.w = hh[7];
    l0.x = ll[0]; l0.y = ll[1]; l0.z = ll[2]; l0.w = ll[3];
    l1.x = ll[4]; l1.y = ll[5]; l1.z = ll[6]; l1.w = ll[7];
    *(ushort4*)&bh[ro]     = h0;
    *(ushort4*)&bh[ro + 4] = h1;
    *(ushort4*)&bl[ro]     = l0;
    *(ushort4*)&bl[ro + 4] = l1;
}

// ---------------- prep: c_proj_w -> transposed split planes [1024][1024], swizzled
__global__ __launch_bounds__(256) void wprep_kernel(const float* __restrict__ w,
    unsigned short* __restrict__ bh, unsigned short* __restrict__ bl) {
    __shared__ float T[32][65];
    int bn = blockIdx.x;
    int bk = blockIdx.y;
    int tid = threadIdx.x;
#pragma unroll
    for (int u = 0; u < 2; ++u) {
        int id = tid + 256 * u;
        int kr = id >> 4;
        int n4 = (id & 15) * 4;
        float4 v = *(const float4*)&w[(size_t)(bk * 32 + kr) * D_DIM + bn * 64 + n4];
        T[kr][n4 + 0] = v.x; T[kr][n4 + 1] = v.y;
        T[kr][n4 + 2] = v.z; T[kr][n4 + 3] = v.w;
    }
    __syncthreads();
    int n = tid >> 2;
    int k8 = (tid & 3) * 8;
    unsigned short hh[8], ll[8];
#pragma unroll
    for (int j = 0; j < 8; ++j) {
        float v = T[k8 + j][n];
        hh[j] = f2bf(v);
        ll[j] = f2bf(v - bf2f(hh[j]));
    }
    int nr = bn * 64 + n;
    int gsw = (tid & 3) ^ GHASH(nr);
    size_t ro = (size_t)nr * D_DIM + bk * 32 + gsw * 8;
    ushort4 h0, h1, l0, l1;
    h0.x = hh[0]; h0.y = hh[1]; h0.z = hh[2]; h0.w = hh[3];
    h1.x = hh[4]; h1.y = hh[5]; h1.z = hh[6]; h1.w = hh[7];
    l0.x = ll[0]; l0.y = ll[1]; l0.z = ll[2]; l0.w = ll[3];
    l1.x = ll[4]; l1.y = ll[5]; l1.z = ll[6]; l1.w = ll[7];
    *(ushort4*)&bh[ro]     = h0;
    *(ushort4*)&bh[ro + 4] = h1;
    *(ushort4*)&bl[ro]     = l0;
    *(ushort4*)&bl[ro + 4] = l1;
}

// ---------------- K2 (v3): split-bf16 MFMA GEMM; A direct-from-global, B via LDS,
// double-buffered with next-chunk prefetch issued BEFORE compute (T3 2-phase)
__global__ __launch_bounds__(256, 3) void qkv_mfma(
    const unsigned short* __restrict__ ah_g, const unsigned short* __restrict__ al_g,
    const unsigned short* __restrict__ bh_g, const unsigned short* __restrict__ bl_g,
    const float* __restrict__ bias,
    float* __restrict__ qstage, float* __restrict__ pres) {
    __shared__ unsigned short Bh[2][128 * 32], Bl[2][128 * 32];   // 32 KB
    // XCD-contiguous remap: 768 blocks = 8 XCDs x 96 (exact, bijective)
    int id = blockIdx.y * 24 + blockIdx.x;
    int nid = (id & 7) * 96 + (id >> 3);
    int bn = nid % 24;
    int bm = nid / 24;
    int tid = threadIdx.x;
    int w = tid >> 6, l = tid & 63;
    int wr = w >> 1, wc = w & 1;

    f32x4 acc[4][4];
#pragma unroll
    for (int i = 0; i < 4; ++i)
#pragma unroll
        for (int j = 0; j < 4; ++j)
            acc[i][j] = (f32x4){0.f, 0.f, 0.f, 0.f};

    int srow = l >> 2;
    int sk = (l & 3) * 8;
    const size_t b_base0 = (size_t)(bn * 128 + w * 32 + srow) * KAUG + sk;
    const size_t b_base1 = b_base0 + (size_t)16 * KAUG;
    const int ldso0 = (w * 32) * 32;
    const int ldso1 = (w * 32 + 16) * 32;

    int lrow = l & 15;
    int lg = l >> 4;

    const unsigned short* aH[4];
    const unsigned short* aL[4];
#pragma unroll
    for (int i = 0; i < 4; ++i) {
        int row = bm * 128 + wr * 64 + i * 16 + lrow;
        aH[i] = ah_g + (size_t)row * KAUG + lg * 8;
        aL[i] = al_g + (size_t)row * KAUG + lg * 8;
    }
    int roB[4];
#pragma unroll
    for (int j = 0; j < 4; ++j) {
        int Rb = wc * 64 + j * 16 + lrow;
        roB[j] = Rb * 32 + ((lg ^ GHASH(Rb)) * 8);
    }

    bf16x8 cAh[4], cAl[4], nAh[4], nAl[4];

    // prologue: stage chunk 0 into buf0, A chunk 0 into regs
    GLL16(bh_g + b_base0, &Bh[0][ldso0]);
    GLL16(bh_g + b_base1, &Bh[0][ldso1]);
    GLL16(bl_g + b_base0, &Bl[0][ldso0]);
    GLL16(bl_g + b_base1, &Bl[0][ldso1]);
#pragma unroll
    for (int i = 0; i < 4; ++i) {
        cAh[i] = *(const bf16x8*)(aH[i]);
        cAl[i] = *(const bf16x8*)(aL[i]);
    }
    __syncthreads();   // drains vmcnt(0): buf0 + A0 ready

    const int NT = KAUG / 32;   // 33
    for (int t = 0; t < NT; ++t) {
        int cur = t & 1;
        if (t + 1 < NT) {   // issue next-chunk loads BEFORE compute (latency hides)
            int kn = (t + 1) * 32;
            GLL16(bh_g + b_base0 + kn, &Bh[cur ^ 1][ldso0]);
            GLL16(bh_g + b_base1 + kn, &Bh[cur ^ 1][ldso1]);
            GLL16(bl_g + b_base0 + kn, &Bl[cur ^ 1][ldso0]);
            GLL16(bl_g + b_base1 + kn, &Bl[cur ^ 1][ldso1]);
#pragma unroll
            for (int i = 0; i < 4; ++i) {
                nAh[i] = *(const bf16x8*)(aH[i] + kn);
                nAl[i] = *(const bf16x8*)(aL[i] + kn);
            }
        }
        bf16x8 fb_h[4], fb_l[4];
#pragma unroll
        for (int j = 0; j < 4; ++j) {
            fb_h[j] = *(const bf16x8*)&Bh[cur][roB[j]];
            fb_l[j] = *(const bf16x8*)&Bl[cur][roB[j]];
        }
#pragma unroll
        for (int i = 0; i < 4; ++i)
#pragma unroll
            for (int j = 0; j < 4; ++j) {
                acc[i][j] = __builtin_amdgcn_mfma_f32_16x16x32_bf16(
                    cAh[i], fb_h[j], acc[i][j], 0, 0, 0);
                acc[i][j] = __builtin_amdgcn_mfma_f32_16x16x32_bf16(
                    cAh[i], fb_l[j], acc[i][j], 0, 0, 0);
                acc[i][j] = __builtin_amdgcn_mfma_f32_16x16x32_bf16(
                    cAl[i], fb_h[j], acc[i][j], 0, 0, 0);
            }
        __syncthreads();   // one drain per chunk, AFTER compute
#pragma unroll
        for (int i = 0; i < 4; ++i) { cAh[i] = nAh[i]; cAl[i] = nAl[i]; }
    }

    int seg = bn >> 3;
#pragma unroll
    for (int j = 0; j < 4; ++j) {
        int n = bn * 128 + wc * 64 + j * 16 + lrow;
        float bz = bias[n];
        int h = (n >> 6) & 15;
        int d = n & 63;
#pragma unroll
        for (int i = 0; i < 4; ++i) {
            int tbase = bm * 128 + wr * 64 + i * 16 + (l >> 4) * 4;
#pragma unroll
            for (int r = 0; r < 4; ++r) {
                int t = tbase + r;
                float v = acc[i][j][r] + bz;
                int bb = t >> 11, s = t & 2047;
                size_t idx = (((size_t)(bb * NH + h) * S_LEN + s) * HD) + d;
                if (seg == 0)      qstage[idx] = v * 0.125f;
                else if (seg == 1) pres[idx] = v;
                else               pres[OUT_KV_ELEMS + idx] = v;
            }
        }
    }
}

// ---------------- K5 (v3): proj via split-bf16 MFMA; same 2-phase double buffer
__global__ __launch_bounds__(256, 3) void proj_mfma(
    const unsigned short* __restrict__ ah_g, const unsigned short* __restrict__ al_g,
    const unsigned short* __restrict__ bh_g, const unsigned short* __restrict__ bl_g,
    const float* __restrict__ bias, float* __restrict__ outp) {
    __shared__ unsigned short Bh[2][128 * 32], Bl[2][128 * 32];
    // 256 blocks = 8 x 32 (exact, bijective)
    int id = blockIdx.y * 8 + blockIdx.x;
    int nid = (id & 7) * 32 + (id >> 3);
    int bn = nid % 8;
    int bm = nid / 8;
    int tid = threadIdx.x;
    int w = tid >> 6, l = tid & 63;
    int wr = w >> 1, wc = w & 1;

    f32x4 acc[4][4];
#pragma unroll
    for (int i = 0; i < 4; ++i)
#pragma unroll
        for (int j = 0; j < 4; ++j)
            acc[i][j] = (f32x4){0.f, 0.f, 0.f, 0.f};

    int srow = l >> 2;
    int sk = (l & 3) * 8;
    const size_t b_base0 = (size_t)(bn * 128 + w * 32 + srow) * D_DIM + sk;
    const size_t b_base1 = b_base0 + (size_t)16 * D_DIM;
    const int ldso0 = (w * 32) * 32;
    const int ldso1 = (w * 32 + 16) * 32;

    int lrow = l & 15;
    int lg = l >> 4;

    const unsigned short* aH[4];
    const unsigned short* aL[4];
#pragma unroll
    for (int i = 0; i < 4; ++i) {
        int row = bm * 128 + wr * 64 + i * 16 + lrow;
        aH[i] = ah_g + (size_t)row * D_DIM + lg * 8;
        aL[i] = al_g + (size_t)row * D_DIM + lg * 8;
    }
    int roB[4];
#pragma unroll
    for (int j = 0; j < 4; ++j) {
        int Rb = wc * 64 + j * 16 + lrow;
        roB[j] = Rb * 32 + ((lg ^ GHASH(Rb)) * 8);
    }

    bf16x8 cAh[4], cAl[4], nAh[4], nAl[4];

    GLL16(bh_g + b_base0, &Bh[0][ldso0]);
    GLL16(bh_g + b_base1, &Bh[0][ldso1]);
    GLL16(bl_g + b_base0, &Bl[0][ldso0]);
    GLL16(bl_g + b_base1, &Bl[0][ldso1]);
#pragma unroll
    for (int i = 0; i < 4; ++i) {
        cAh[i] = *(const bf16x8*)(aH[i]);
        cAl[i] = *(const bf16x8*)(aL[i]);
    }
    __syncthreads();

    const int NT = D_DIM / 32;   // 32
    for (int t = 0; t < NT; ++t) {
        int cur = t & 1;
        if (t + 1 < NT) {
            int kn = (t + 1) * 32;
            GLL16(bh_g + b_base0 + kn, &Bh[cur ^ 1][ldso0]);
            GLL16(bh_g + b_base1 + kn, &Bh[cur ^ 1][ldso1]);
            GLL16(bl_g + b_base0 + kn, &Bl[cur ^ 1][ldso0]);
            GLL16(bl_g + b_base1 + kn, &Bl[cur ^ 1][ldso1]);
#pragma unroll
            for (int i = 0; i < 4; ++i) {
                nAh[i] = *(const bf16x8*)(aH[i] + kn);
                nAl[i] = *(const bf16x8*)(aL[i] + kn);
            }
        }
        bf16x8 fb_h[4], fb_l[4];
#pragma unroll
        for (int j = 0; j < 4; ++j) {
            fb_h[j] = *(const bf16x8*)&Bh[cur][roB[j]];
            fb_l[j] = *(const bf16x8*)&Bl[cur][roB[j]];
        }
#pragma unroll
        for (int i = 0; i < 4; ++i)
#pragma unroll
            for (int j = 0; j < 4; ++j) {
                acc[i][j] = __builtin_amdgcn_mfma_f32_16x16x32_bf16(
                    cAh[i], fb_h[j], acc[i][j], 0, 0, 0);
                acc[i][j] = __builtin_amdgcn_mfma_f32_16x16x32_bf16(
                    cAh[i], fb_l[j], acc[i][j], 0, 0, 0);
                acc[i][j] = __builtin_amdgcn_mfma_f32_16x16x32_bf16(
                    cAl[i], fb_h[j], acc[i][j], 0, 0, 0);
            }
        __syncthreads();
#pragma unroll
        for (int i = 0; i < 4; ++i) { cAh[i] = nAh[i]; cAl[i] = nAl[i]; }
    }

#pragma unroll
    for (int j = 0; j < 4; ++j) {
        int n = bn * 128 + wc * 64 + j * 16 + lrow;
        float bz = bias[n];
#pragma unroll
        for (int i = 0; i < 4; ++i) {
            int tbase = bm * 128 + wr * 64 + i * 16 + (l >> 4) * 4;
#pragma unroll
            for (int r = 0; r < 4; ++r)
                outp[(size_t)(tbase + r) * D_DIM + n] = acc[i][j][r] + bz;
        }
    }
}

// ---------------- prep: K rows -> swizzled bf16 hi/lo planes [bh][key][64]
__global__ __launch_bounds__(256) void kprep_kernel(const float* __restrict__ kin,
    unsigned short* __restrict__ khp, unsigned short* __restrict__ klp) {
    int id = blockIdx.x * 256 + threadIdx.x;
    int rowi = id >> 3;
    int gsrc = id & 7;
    const float* src = kin + (size_t)rowi * 64 + gsrc * 8;
    float4 v0 = *(const float4*)src;
    float4 v1 = *(const float4*)(src + 4);
    int key = rowi & 2047;
    int gp = gsrc ^ (key & 7);
    size_t dst = (size_t)rowi * 64 + gp * 8;
    float vv[8] = {v0.x, v0.y, v0.z, v0.w, v1.x, v1.y, v1.z, v1.w};
    bf16x8 h, lo;
#pragma unroll
    for (int j = 0; j < 8; ++j) {
        unsigned short hh = f2bf(vv[j]);
        h[j] = (short)hh;
        lo[j] = (short)f2bf(vv[j] - bf2f(hh));
    }
    *(bf16x8*)&khp[dst] = h;
    *(bf16x8*)&klp[dst] = lo;
}

// ---------------- prep: V -> transposed swizzled bf16 hi/lo planes [bh][d][key]
__global__ __launch_bounds__(256) void vtprep_kernel(const float* __restrict__ vin,
    unsigned short* __restrict__ vth, unsigned short* __restrict__ vtl) {
    __shared__ __align__(16) unsigned short Th[64][72];
    __shared__ __align__(16) unsigned short Tl[64][72];
    int bh = blockIdx.x;
    int kv0 = blockIdx.y * 64;
    int tid = threadIdx.x;
#pragma unroll
    for (int p = 0; p < 4; ++p) {
        int key = (tid >> 4) + 16 * p;
        int d0 = (tid & 15) * 4;
        float4 v = *(const float4*)&vin[((size_t)bh * 2048 + kv0 + key) * 64 + d0];
        float vv[4] = {v.x, v.y, v.z, v.w};
#pragma unroll
        for (int j = 0; j < 4; ++j) {
            unsigned short hh = f2bf(vv[j]);
            Th[d0 + j][key] = hh;
            Tl[d0 + j][key] = f2bf(vv[j] - bf2f(hh));
        }
    }
    __syncthreads();
    int d = tid >> 2;
#pragma unroll
    for (int q = 0; q < 2; ++q) {
        int gg = (tid & 3) + 4 * q;
        int gs = gg ^ (d & 7);
        bf16x8 hv = *(const bf16x8*)&Th[d][gs * 8];
        bf16x8 lv = *(const bf16x8*)&Tl[d][gs * 8];
        size_t dst = ((size_t)bh * 64 + d) * 2048 + kv0 + gg * 8;
        *(bf16x8*)&vth[dst] = hv;
        *(bf16x8*)&vtl[dst] = lv;
    }
}

// ---------------- K3: MFMA flash attention, 32x32x16, swapped QK^T ----------------
__device__ __forceinline__ void stage_tile(
    const unsigned short* __restrict__ kh, const unsigned short* __restrict__ kl,
    const unsigned short* __restrict__ vh, const unsigned short* __restrict__ vl,
    unsigned short (*ldsb)[4096], int w, int l, int bh, int kv0) {
    if (w < 2) {
        const unsigned short* gp = (w == 0 ? kh : kl)
            + ((size_t)bh * 2048 + kv0 + (l >> 3)) * 64 + (l & 7) * 8;
        unsigned short* lp = ldsb[w];
#pragma unroll
        for (int i = 0; i < 8; ++i)
            GLL16(gp + i * 512, lp + i * 512);
    } else {
        const unsigned short* gp = (w == 2 ? vh : vl)
            + ((size_t)bh * 64 + (l >> 3)) * 2048 + kv0 + (l & 7) * 8;
        unsigned short* lp = ldsb[w];
#pragma unroll
        for (int i = 0; i < 8; ++i)
            GLL16(gp + (size_t)i * 16384, lp + i * 512);
    }
}

#define QROW(r) ((((r) & 3) + 8 * ((r) >> 2)) + 4 * g)

__global__ __launch_bounds__(256, 2) void attn_mfma(
    const float* __restrict__ q_s,
    const unsigned short* __restrict__ kh, const unsigned short* __restrict__ kl,
    const unsigned short* __restrict__ vh, const unsigned short* __restrict__ vl,
    unsigned short* __restrict__ aout_h, unsigned short* __restrict__ aout_l) {
    __shared__ __align__(16) unsigned short lds[2][4][4096];   // 64 KB
    int bh = blockIdx.x;
    int qi = (int)gridDim.y - 1 - blockIdx.y;
    int tid = threadIdx.x;
    int w = tid >> 6, l = tid & 63;
    int qloc = l & 31, g = l >> 5;
    int q0 = qi * 128;
    int qg = q0 + w * 32 + qloc;

    bf16x8 qf[4];
    {
        const float* qrow = q_s + ((size_t)bh * S_LEN + qg) * HD;
#pragma unroll
        for (int t = 0; t < 4; ++t) {
            float4 u0 = *(const float4*)&qrow[t * 16 + g * 8];
            float4 u1 = *(const float4*)&qrow[t * 16 + g * 8 + 4];
            float vv[8] = {u0.x, u0.y, u0.z, u0.w, u1.x, u1.y, u1.z, u1.w};
            bf16x8 r;
#pragma unroll
            for (int j = 0; j < 8; ++j) r[j] = (short)f2bf(vv[j]);
            qf[t] = r;
        }
    }

    f32x16 o0, o1;
#pragma unroll
    for (int r = 0; r < 16; ++r) { o0[r] = 0.f; o1[r] = 0.f; }
    float m_run = -1e30f, l_run = 0.f;

    int nt = 2 * qi + 2;
    int qwmax = q0 + w * 32 + 31;

    stage_tile(kh, kl, vh, vl, lds[0], w, l, bh, 0);
    __syncthreads();

    for (int t = 0; t < nt; ++t) {
        int kv0 = t * 64;
        int bi = t & 1;
        if (t + 1 < nt)
            stage_tile(kh, kl, vh, vl, lds[bi ^ 1], w, l, bh, (t + 1) * 64);

        if (kv0 <= qwmax) {
            const unsigned short* Khp = lds[bi][0];
            const unsigned short* Klp = lds[bi][1];
            const unsigned short* Vhp = lds[bi][2];
            const unsigned short* Vlp = lds[bi][3];

            f32x16 s0, s1;
#pragma unroll
            for (int r = 0; r < 16; ++r) { s0[r] = 0.f; s1[r] = 0.f; }

            __builtin_amdgcn_s_setprio(1);
#pragma unroll
            for (int tt = 0; tt < 4; ++tt) {
                int gr = ((2 * tt + g) ^ (qloc & 7)) * 8;
                bf16x8 a0h = *(const bf16x8*)&Khp[qloc * 64 + gr];
                bf16x8 a1h = *(const bf16x8*)&Khp[(32 + qloc) * 64 + gr];
                bf16x8 a0l = *(const bf16x8*)&Klp[qloc * 64 + gr];
                bf16x8 a1l = *(const bf16x8*)&Klp[(32 + qloc) * 64 + gr];
                s0 = MFMA32(a0h, qf[tt], s0);
                s0 = MFMA32(a0l, qf[tt], s0);
                s1 = MFMA32(a1h, qf[tt], s1);
                s1 = MFMA32(a1l, qf[tt], s1);
            }
            __builtin_amdgcn_s_setprio(0);

            if (kv0 + 63 > q0 + w * 32) {
#pragma unroll
                for (int r = 0; r < 16; ++r) {
                    int kk = kv0 + QROW(r);
                    if (kk > qg)      s0[r] = -1e30f;
                    if (kk + 32 > qg) s1[r] = -1e30f;
                }
            }

            float mx = s0[0];
#pragma unroll
            for (int r = 1; r < 16; ++r) mx = fmaxf(mx, s0[r]);
#pragma unroll
            for (int r = 0; r < 16; ++r) mx = fmaxf(mx, s1[r]);
            mx = fmaxf(mx, __shfl_xor(mx, 32));
            float mnew = fmaxf(m_run, mx);
            float al = __expf(m_run - mnew);
            m_run = mnew;
            float rs = 0.f;
#pragma unroll
            for (int r = 0; r < 16; ++r) { s0[r] = __expf(s0[r] - mnew); rs += s0[r]; }
#pragma unroll
            for (int r = 0; r < 16; ++r) { s1[r] = __expf(s1[r] - mnew); rs += s1[r]; }
            rs += __shfl_xor(rs, 32);
            l_run = l_run * al + rs;
#pragma unroll
            for (int r = 0; r < 16; ++r) {
                float ar = __shfl(al, QROW(r));
                o0[r] *= ar; o1[r] *= ar;
            }

            __builtin_amdgcn_s_setprio(1);
#pragma unroll
            for (int ks = 0; ks < 4; ++ks) {
                const int b = (ks & 1) * 8;
                unsigned w0, w1, w2, w3;
                if (ks < 2) {
                    w0 = cvtpk(s0[b + 0], s0[b + 1]);
                    w1 = cvtpk(s0[b + 2], s0[b + 3]);
                    w2 = cvtpk(s0[b + 4], s0[b + 5]);
                    w3 = cvtpk(s0[b + 6], s0[b + 7]);
                } else {
                    w0 = cvtpk(s1[b + 0], s1[b + 1]);
                    w1 = cvtpk(s1[b + 2], s1[b + 3]);
                    w2 = cvtpk(s1[b + 4], s1[b + 5]);
                    w3 = cvtpk(s1[b + 6], s1[b + 7]);
                }
                asm("v_permlane32_swap_b32 %0, %1" : "+v"(w0), "+v"(w2));
                asm("v_permlane32_swap_b32 %0, %1" : "+v"(w1), "+v"(w3));
                U4 u; u.u[0] = w0; u.u[1] = w1; u.u[2] = w2; u.u[3] = w3;
                bf16x8 pa = u.v;
                int gr = ((2 * ks + g) ^ (qloc & 7)) * 8;
                bf16x8 v0h = *(const bf16x8*)&Vhp[qloc * 64 + gr];
                bf16x8 v1h = *(const bf16x8*)&Vhp[(32 + qloc) * 64 + gr];
                bf16x8 v0l = *(const bf16x8*)&Vlp[qloc * 64 + gr];
                bf16x8 v1l = *(const bf16x8*)&Vlp[(32 + qloc) * 64 + gr];
                o0 = MFMA32(pa, v0h, o0);
                o0 = MFMA32(pa, v0l, o0);
                o1 = MFMA32(pa, v1h, o1);
                o1 = MFMA32(pa, v1l, o1);
            }
            __builtin_amdgcn_s_setprio(0);
        }
        __syncthreads();
    }

    int bb = bh >> 4, h = bh & 15;
#pragma unroll
    for (int r = 0; r < 16; ++r) {
        float li = __shfl(l_run, QROW(r));
        float inv = 1.f / li;
        int qq = q0 + w * 32 + QROW(r);
        size_t base = ((size_t)(bb * S_LEN + qq)) * D_DIM + h * HD + qloc;
        float v0 = o0[r] * inv;
        float v1 = o1[r] * inv;
        unsigned short h0 = f2bf(v0);
        unsigned short h1 = f2bf(v1);
        aout_h[base]      = h0;
        aout_l[base]      = f2bf(v0 - bf2f(h0));
        aout_h[base + 32] = h1;
        aout_l[base + 32] = f2bf(v1 - bf2f(h1));
    }
}

// ---------------- K3 fallback: f32 flash attention ----------------
#define LSTR 68
__global__ __launch_bounds__(256) void attn_kernel(const float* __restrict__ q_s,
    const float* __restrict__ k_s, const float* __restrict__ v_s,
    float* __restrict__ a_s) {
    __shared__ float Qt[64][LSTR];
    __shared__ float KP[64][LSTR];
    __shared__ float Vs[64][LSTR];
    int bh = blockIdx.x;
    int qi = 31 - blockIdx.y;
    int tid = threadIdx.x;
    int tx = tid & 15, ty = tid >> 4;

#pragma unroll
    for (int qq = 0; qq < 4; ++qq) {
        int q  = qq * 16 + (tid >> 4);
        int d4 = (tid & 15) * 4;
        float4 v = *(const float4*)&q_s[((size_t)bh * S_LEN + qi * 64 + q) * HD + d4];
        Qt[d4 + 0][q] = v.x; Qt[d4 + 1][q] = v.y;
        Qt[d4 + 2][q] = v.z; Qt[d4 + 3][q] = v.w;
    }

    float o[4][4];
#pragma unroll
    for (int r = 0; r < 4; ++r)
#pragma unroll
        for (int c = 0; c < 4; ++c) o[r][c] = 0.f;
    float mrow[4] = {-1e30f, -1e30f, -1e30f, -1e30f};
    float lrow[4] = {0.f, 0.f, 0.f, 0.f};

    for (int kt = 0; kt <= qi; ++kt) {
        __syncthreads();
#pragma unroll
        for (int kk2 = 0; kk2 < 4; ++kk2) {
            int k  = kk2 * 16 + (tid >> 4);
            int d4 = (tid & 15) * 4;
            size_t rowoff = ((size_t)bh * S_LEN + kt * 64 + k) * HD + d4;
            float4 kv4 = *(const float4*)&k_s[rowoff];
            KP[d4 + 0][k] = kv4.x; KP[d4 + 1][k] = kv4.y;
            KP[d4 + 2][k] = kv4.z; KP[d4 + 3][k] = kv4.w;
            float4 vv4 = *(const float4*)&v_s[rowoff];
            *(float4*)&Vs[k][d4] = vv4;
        }
        __syncthreads();

        float s[4][4];
#pragma unroll
        for (int r = 0; r < 4; ++r)
#pragma unroll
            for (int c = 0; c < 4; ++c) s[r][c] = 0.f;
#pragma unroll 8
        for (int d = 0; d < 64; ++d) {
            float4 qv = *(const float4*)&Qt[d][ty * 4];
            float4 kv = *(const float4*)&KP[d][tx * 4];
            float qa[4] = {qv.x, qv.y, qv.z, qv.w};
            float ka[4] = {kv.x, kv.y, kv.z, kv.w};
#pragma unroll
            for (int r = 0; r < 4; ++r)
#pragma unroll
                for (int c = 0; c < 4; ++c)
                    s[r][c] = fmaf(qa[r], ka[c], s[r][c]);
        }
        if (kt == qi) {
#pragma unroll
            for (int r = 0; r < 4; ++r)
#pragma unroll
                for (int c = 0; c < 4; ++c)
                    if (tx * 4 + c > ty * 4 + r) s[r][c] = -1e30f;
        }
        __syncthreads();

        float p[4][4];
#pragma unroll
        for (int r = 0; r < 4; ++r) {
            float mx = fmaxf(fmaxf(s[r][0], s[r][1]), fmaxf(s[r][2], s[r][3]));
            mx = fmaxf(mx, __shfl_xor(mx, 1));
            mx = fmaxf(mx, __shfl_xor(mx, 2));
            mx = fmaxf(mx, __shfl_xor(mx, 4));
            mx = fmaxf(mx, __shfl_xor(mx, 8));
            float mn = fmaxf(mrow[r], mx);
            float alpha = __expf(mrow[r] - mn);
            mrow[r] = mn;
            float rsum = 0.f;
#pragma unroll
            for (int c = 0; c < 4; ++c) {
                p[r][c] = __expf(s[r][c] - mn);
                rsum += p[r][c];
            }
            rsum += __shfl_xor(rsum, 1);
            rsum += __shfl_xor(rsum, 2);
            rsum += __shfl_xor(rsum, 4);
            rsum += __shfl_xor(rsum, 8);
            lrow[r] = lrow[r] * alpha + rsum;
#pragma unroll
            for (int c = 0; c < 4; ++c) o[r][c] *= alpha;
            *(float4*)&KP[ty * 4 + r][tx * 4] =
                make_float4(p[r][0], p[r][1], p[r][2], p[r][3]);
        }
        __syncthreads();

#pragma unroll 8
        for (int k = 0; k < 64; ++k) {
            float4 vv = *(const float4*)&Vs[k][tx * 4];
            float va[4] = {vv.x, vv.y, vv.z, vv.w};
#pragma unroll
            for (int r = 0; r < 4; ++r) {
                float pr = KP[ty * 4 + r][k];
#pragma unroll
                for (int c = 0; c < 4; ++c)
                    o[r][c] = fmaf(pr, va[c], o[r][c]);
            }
        }
    }

    int b = bh >> 4, h = bh & 15;
#pragma unroll
    for (int r = 0; r < 4; ++r) {
        int i = qi * 64 + ty * 4 + r;
        float inv = 1.f / lrow[r];
        *(float4*)&a_s[((size_t)(b * S_LEN + i)) * D_DIM + h * HD + tx * 4] =
            make_float4(o[r][0] * inv, o[r][1] * inv, o[r][2] * inv, o[r][3] * inv);
    }
}

// ------ K2 fallback (old fp32 path) ------
__global__ __launch_bounds__(256) void qkv_kernel(const float* __restrict__ x,
    const float* __restrict__ w, const float* __restrict__ bias,
    const float* __restrict__ qa2, const float* __restrict__ va2,
    const float* __restrict__ tq, const float* __restrict__ tv,
    float* __restrict__ qstage, float* __restrict__ pres) {
    __shared__ float As[128][17];
    __shared__ float Bs[16][64];
    int bx = blockIdx.x;
    int by = blockIdx.y;
    int tid = threadIdx.x;
    int tx = tid & 15, ty = tid >> 4;

    float c[8][4];
#pragma unroll
    for (int i = 0; i < 8; ++i)
#pragma unroll
        for (int j = 0; j < 4; ++j) c[i][j] = 0.f;

    for (int k0 = 0; k0 < D_DIM; k0 += 16) {
#pragma unroll
        for (int u = 0; u < 2; ++u) {
            int f4 = tid + 256 * u;
            int row = f4 >> 2;
            int kk4 = (f4 & 3) * 4;
            float4 av = *(const float4*)&x[(size_t)(by * 128 + row) * D_DIM + k0 + kk4];
            As[row][kk4 + 0] = av.x; As[row][kk4 + 1] = av.y;
            As[row][kk4 + 2] = av.z; As[row][kk4 + 3] = av.w;
        }
        {
            int kkb = tid >> 4;
            int col4 = (tid & 15) * 4;
            *(float4*)&Bs[kkb][col4] =
                *(const float4*)&w[(size_t)(k0 + kkb) * N3 + bx * 64 + col4];
        }
        __syncthreads();
#pragma unroll
        for (int kk = 0; kk < 16; ++kk) {
            float4 bv = *(const float4*)&Bs[kk][tx * 4];
#pragma unroll
            for (int i = 0; i < 8; ++i) {
                float a = As[ty * 8 + i][kk];
                c[i][0] = fmaf(a, bv.x, c[i][0]);
                c[i][1] = fmaf(a, bv.y, c[i][1]);
                c[i][2] = fmaf(a, bv.z, c[i][2]);
                c[i][3] = fmaf(a, bv.w, c[i][3]);
            }
        }
        __syncthreads();
    }

    int seg = bx >> 4;
    int h = bx & 15;
    int ncol = bx * 64 + tx * 4;
    float4 bias4 = *(const float4*)&bias[ncol];
    int nloc = h * 64 + tx * 4;

    float4 arr[16];
    if (seg != 1) {
        const float* a2 = (seg == 0 ? qa2 : va2);
#pragma unroll
        for (int jj = 0; jj < 16; ++jj)
            arr[jj] = *(const float4*)&a2[jj * D_DIM + nloc];
    }

#pragma unroll
    for (int i = 0; i < 8; ++i) {
        int t = by * 128 + ty * 8 + i;
        float v0 = c[i][0] + bias4.x;
        float v1 = c[i][1] + bias4.y;
        float v2 = c[i][2] + bias4.z;
        float v3 = c[i][3] + bias4.w;
        if (seg != 1) {
            const float* trow = (seg == 0 ? tq : tv) + t * 16;
            float l0 = 0.f, l1 = 0.f, l2 = 0.f, l3 = 0.f;
#pragma unroll
            for (int jj = 0; jj < 16; ++jj) {
                float tvv = trow[jj];
                l0 = fmaf(tvv, arr[jj].x, l0);
                l1 = fmaf(tvv, arr[jj].y, l1);
                l2 = fmaf(tvv, arr[jj].z, l2);
                l3 = fmaf(tvv, arr[jj].w, l3);
            }
            v0 += 0.5f * l0; v1 += 0.5f * l1; v2 += 0.5f * l2; v3 += 0.5f * l3;
        }
        int b = t >> 11, sidx = t & 2047;
        size_t idx = (((size_t)(b * NH + h) * S_LEN + sidx) * HD) + tx * 4;
        if (seg == 0) {
            *(float4*)&qstage[idx] = make_float4(v0 * 0.125f, v1 * 0.125f,
                                                 v2 * 0.125f, v3 * 0.125f);
        } else if (seg == 1) {
            *(float4*)&pres[idx] = make_float4(v0, v1, v2, v3);
        } else {
            *(float4*)&pres[OUT_KV_ELEMS + idx] = make_float4(v0, v1, v2, v3);
        }
    }
}

// ---------------- K4 fallback: f32 proj ----------------
__global__ __launch_bounds__(256) void proj_kernel(const float* __restrict__ A,
    const float* __restrict__ w, const float* __restrict__ bias,
    float* __restrict__ outp) {
    __shared__ float As[128][17];
    __shared__ float Bs[16][64];
    int bx = blockIdx.x;
    int by = blockIdx.y;
    int tid = threadIdx.x;
    int tx = tid & 15, ty = tid >> 4;

    float c[8][4];
#pragma unroll
    for (int i = 0; i < 8; ++i)
#pragma unroll
        for (int j = 0; j < 4; ++j) c[i][j] = 0.f;

    for (int k0 = 0; k0 < D_DIM; k0 += 16) {
#pragma unroll
        for (int u = 0; u < 2; ++u) {
            int f4 = tid + 256 * u;
            int row = f4 >> 2;
            int kk4 = (f4 & 3) * 4;
            float4 av = *(const float4*)&A[(size_t)(by * 128 + row) * D_DIM + k0 + kk4];
            As[row][kk4 + 0] = av.x; As[row][kk4 + 1] = av.y;
            As[row][kk4 + 2] = av.z; As[row][kk4 + 3] = av.w;
        }
        {
            int kkb = tid >> 4;
            int col4 = (tid & 15) * 4;
            *(float4*)&Bs[kkb][col4] =
                *(const float4*)&w[(size_t)(k0 + kkb) * D_DIM + bx * 64 + col4];
        }
        __syncthreads();
#pragma unroll
        for (int kk = 0; kk < 16; ++kk) {
            float4 bv = *(const float4*)&Bs[kk][tx * 4];
#pragma unroll
            for (int i = 0; i < 8; ++i) {
                float a = As[ty * 8 + i][kk];
                c[i][0] = fmaf(a, bv.x, c[i][0]);
                c[i][1] = fmaf(a, bv.y, c[i][1]);
                c[i][2] = fmaf(a, bv.z, c[i][2]);
                c[i][3] = fmaf(a, bv.w, c[i][3]);
            }
        }
        __syncthreads();
    }

    int ncol = bx * 64 + tx * 4;
    float4 bias4 = *(const float4*)&bias[ncol];
#pragma unroll
    for (int i = 0; i < 8; ++i) {
        int t = by * 128 + ty * 8 + i;
        *(float4*)&outp[(size_t)t * D_DIM + ncol] =
            make_float4(c[i][0] + bias4.x, c[i][1] + bias4.y,
                        c[i][2] + bias4.z, c[i][3] + bias4.w);
    }
}

extern "C" void kernel_launch(void* const* d_in, const int* in_sizes, int n_in,
                              void* d_out, int out_size, void* d_ws, size_t ws_size,
                              hipStream_t stream) {
    const float* x        = (const float*)d_in[0];
    const float* c_attn_w = (const float*)d_in[1];
    const float* c_attn_b = (const float*)d_in[2];
    const float* c_proj_w = (const float*)d_in[3];
    const float* c_proj_b = (const float*)d_in[4];
    const float* q_a1     = (const float*)d_in[5];
    const float* q_a2     = (const float*)d_in[6];
    const float* v_a1     = (const float*)d_in[7];
    const float* v_a2     = (const float*)d_in[8];

    float* outf   = (float*)d_out;
    float* qstage = outf;                  // a-region reused as f32 q staging [B,H,S,hd]
    float* pres   = outf + OUT_A_ELEMS;    // present [2,B,H,S,hd] f32

    char* wsb = (char*)d_ws;
    float* tq = (float*)wsb;
    float* tv = (float*)(wsb + 262144);
    unsigned short* wt_hi = (unsigned short*)(wsb + 524288);
    unsigned short* wt_lo = (unsigned short*)(wsb + 524288 + 6488064);
    unsigned short* a_hi  = (unsigned short*)(wsb + 13500416);
    unsigned short* a_lo  = (unsigned short*)(wsb + 13500416 + 8650752);
    unsigned short* kp_h  = (unsigned short*)wsb;
    unsigned short* kp_l  = (unsigned short*)(wsb + 8388608);
    unsigned short* vt_h  = (unsigned short*)(wsb + 16777216);
    unsigned short* vt_l  = (unsigned short*)(wsb + 25165824);
    unsigned short* aout_h = (unsigned short*)(wsb + 33554432);
    unsigned short* aout_l = (unsigned short*)(wsb + 41943040);
    unsigned short* wp_h  = (unsigned short*)wsb;
    unsigned short* wp_l  = (unsigned short*)(wsb + 2097152);
    const size_t WS_FULL = 50331648;
    const size_t WS_MID  = 30801920;

    lora1_v2<<<dim3(1024), dim3(256), 0, stream>>>(x, q_a1, v_a1, tq, tv);

    if (ws_size >= WS_FULL) {
        splitA_kernel<<<dim3((T_TOK * (KAUG / 4) + 255) / 256), dim3(256), 0, stream>>>(
            x, tq, tv, a_hi, a_lo);
        splitW_kernel<<<dim3(48, KAUG / 32), dim3(256), 0, stream>>>(
            c_attn_w, q_a2, v_a2, wt_hi, wt_lo);
        qkv_mfma<<<dim3(24, 32), dim3(256), 0, stream>>>(
            a_hi, a_lo, wt_hi, wt_lo, c_attn_b, qstage, pres);
        kprep_kernel<<<dim3(2048), dim3(256), 0, stream>>>(pres, kp_h, kp_l);
        vtprep_kernel<<<dim3(32, 32), dim3(256), 0, stream>>>(
            pres + OUT_KV_ELEMS, vt_h, vt_l);
        attn_mfma<<<dim3(32, 16), dim3(256), 0, stream>>>(
            qstage, kp_h, kp_l, vt_h, vt_l, aout_h, aout_l);
        wprep_kernel<<<dim3(16, 32), dim3(256), 0, stream>>>(c_proj_w, wp_h, wp_l);
        proj_mfma<<<dim3(8, 32), dim3(256), 0, stream>>>(
            aout_h, aout_l, wp_h, wp_l, c_proj_b, outf);
    } else if (ws_size >= WS_MID) {
        float* a_s = (float*)(wsb + 13500416);
        splitA_kernel<<<dim3((T_TOK * (KAUG / 4) + 255) / 256), dim3(256), 0, stream>>>(
            x, tq, tv, a_hi, a_lo);
        splitW_kernel<<<dim3(48, KAUG / 32), dim3(256), 0, stream>>>(
            c_attn_w, q_a2, v_a2, wt_hi, wt_lo);
        qkv_mfma<<<dim3(24, 32), dim3(256), 0, stream>>>(
            a_hi, a_lo, wt_hi, wt_lo, c_attn_b, qstage, pres);
        attn_kernel<<<dim3(32, 32), dim3(256), 0, stream>>>(
            qstage, pres, pres + OUT_KV_ELEMS, a_s);
        proj_kernel<<<dim3(16, 32), dim3(256), 0, stream>>>(
            a_s, c_proj_w, c_proj_b, outf);
    } else {
        float* a_s2 = tv + 65536;
        qkv_kernel<<<dim3(48, 32), dim3(256), 0, stream>>>(x, c_attn_w, c_attn_b,
            q_a2, v_a2, tq, tv, qstage, pres);
        attn_kernel<<<dim3(32, 32), dim3(256), 0, stream>>>(
            qstage, pres, pres + OUT_KV_ELEMS, a_s2);
        proj_kernel<<<dim3(16, 32), dim3(256), 0, stream>>>(
            a_s2, c_proj_w, c_proj_b, outf);
    }
}

// Round 6
// 284.830 us; speedup vs baseline: 1.3013x; 1.2783x over previous
//
#include <hip/hip_runtime.h>

#define T_TOK 4096   // B*S
#define D_DIM 1024
#define N3    3072
#define S_LEN 2048
#define NH    16
#define HD    64
#define KAUG  1056   // 1024 + 16 (q-lora) + 16 (v-lora)

#define OUT_A_ELEMS   4194304   // B*S*D   (f32 elements)
#define OUT_KV_ELEMS  4194304   // B*H*S*hd

typedef __attribute__((ext_vector_type(8))) short bf16x8;
typedef __attribute__((ext_vector_type(4))) float f32x4;
typedef __attribute__((ext_vector_type(16))) float f32x16;
typedef _Float16 f16x8 __attribute__((ext_vector_type(8)));
typedef _Float16 f16x4 __attribute__((ext_vector_type(4)));

union U4 { unsigned u[4]; bf16x8 v; };

// granule-position hash for LDS bank-conflict-free B tiles (row stride 64 B)
#define GHASH(r) ((((r) >> 1) ^ ((r) >> 3)) & 3)

__device__ __forceinline__ unsigned short f2bf(float f) {
    unsigned u = __float_as_uint(f);
    u += 0x7FFFu + ((u >> 16) & 1u);
    return (unsigned short)(u >> 16);
}
__device__ __forceinline__ float bf2f(unsigned short h) {
    return __uint_as_float(((unsigned)h) << 16);
}
__device__ __forceinline__ unsigned cvtpk(float a, float b) {
    unsigned r;
    asm("v_cvt_pk_bf16_f32 %0, %1, %2" : "=v"(r) : "v"(a), "v"(b));
    return r;
}

#define GLL16(gp, lp) __builtin_amdgcn_global_load_lds( \
    (const __attribute__((address_space(1))) unsigned int*)(gp), \
    (__attribute__((address_space(3))) unsigned int*)(lp), 16, 0, 0)

#define MFMA32(A, B, C) __builtin_amdgcn_mfma_f32_32x32x16_bf16(A, B, C, 0, 0, 0)
#define MFMA16F(A, B, C) __builtin_amdgcn_mfma_f32_16x16x32_f16(A, B, C, 0, 0, 0)

// ---------------- K1 (v2): lora down-proj  tq = x@q_a1, tv = x@v_a1 ----------------
__global__ __launch_bounds__(256) void lora1_v2(const float* __restrict__ x,
    const float* __restrict__ qa1, const float* __restrict__ va1,
    float* __restrict__ tq, float* __restrict__ tv) {
    int tid = threadIdx.x;
    int w = tid >> 6;
    int lane = tid & 63;
    int t = blockIdx.x * 4 + w;
    int cg = lane & 7;
    int ks = lane >> 3;
    const float* a1 = (cg < 4) ? qa1 : va1;
    int c4 = (cg & 3) * 4;
    const float* xr = x + (size_t)t * D_DIM + ks * 128;
    const float* ar = a1 + (size_t)(ks * 128) * 16 + c4;
    float4 acc = make_float4(0.f, 0.f, 0.f, 0.f);
#pragma unroll 8
    for (int j = 0; j < 128; ++j) {
        float xv = xr[j];
        float4 av = *(const float4*)&ar[j * 16];
        acc.x = fmaf(xv, av.x, acc.x);
        acc.y = fmaf(xv, av.y, acc.y);
        acc.z = fmaf(xv, av.z, acc.z);
        acc.w = fmaf(xv, av.w, acc.w);
    }
#pragma unroll
    for (int m = 8; m < 64; m <<= 1) {
        acc.x += __shfl_xor(acc.x, m);
        acc.y += __shfl_xor(acc.y, m);
        acc.z += __shfl_xor(acc.z, m);
        acc.w += __shfl_xor(acc.w, m);
    }
    if (lane < 8) {
        float* dst = (cg < 4) ? &tq[t * 16 + c4] : &tv[t * 16 + (cg - 4) * 4];
        *(float4*)dst = acc;
    }
}

// ---------------- prep: A_aug = [x | tq | tv] -> single fp16 plane [T_TOK][KAUG]
__global__ __launch_bounds__(256) void splitA_f16(const float* __restrict__ x,
    const float* __restrict__ tq, const float* __restrict__ tv,
    _Float16* __restrict__ af) {
    int idx = blockIdx.x * 256 + threadIdx.x;
    const int total = T_TOK * (KAUG / 4);
    if (idx >= total) return;
    int t = idx / (KAUG / 4);
    int c4 = (idx - t * (KAUG / 4)) * 4;
    float4 v;
    if (c4 < D_DIM)           v = *(const float4*)&x[(size_t)t * D_DIM + c4];
    else if (c4 < D_DIM + 16) v = *(const float4*)&tq[t * 16 + (c4 - D_DIM)];
    else                      v = *(const float4*)&tv[t * 16 + (c4 - D_DIM - 16)];
    f16x4 h;
    h[0] = (_Float16)v.x; h[1] = (_Float16)v.y;
    h[2] = (_Float16)v.z; h[3] = (_Float16)v.w;
    *(f16x4*)&af[(size_t)t * KAUG + c4] = h;
}

// ---------------- prep: W_aug^T fp16 plane [N3][KAUG], granule-swizzled per 32-k chunk
__global__ __launch_bounds__(256) void splitW_f16(const float* __restrict__ w,
    const float* __restrict__ qa2, const float* __restrict__ va2,
    _Float16* __restrict__ bf) {
    __shared__ float T[32][65];
    int bn = blockIdx.x;
    int bk = blockIdx.y;
    int tid = threadIdx.x;
#pragma unroll
    for (int u = 0; u < 2; ++u) {
        int id = tid + 256 * u;
        int kr = id >> 4;
        int n4 = (id & 15) * 4;
        int k = bk * 32 + kr;
        int n = bn * 64 + n4;
        float4 v = make_float4(0.f, 0.f, 0.f, 0.f);
        if (k < D_DIM) {
            v = *(const float4*)&w[(size_t)k * N3 + n];
        } else if (k < D_DIM + 16) {
            if (n < D_DIM) {
                float4 q4 = *(const float4*)&qa2[(k - D_DIM) * D_DIM + n];
                v = make_float4(q4.x * 0.5f, q4.y * 0.5f, q4.z * 0.5f, q4.w * 0.5f);
            }
        } else {
            if (n >= 2 * D_DIM) {
                float4 q4 = *(const float4*)&va2[(k - D_DIM - 16) * D_DIM + (n - 2 * D_DIM)];
                v = make_float4(q4.x * 0.5f, q4.y * 0.5f, q4.z * 0.5f, q4.w * 0.5f);
            }
        }
        T[kr][n4 + 0] = v.x; T[kr][n4 + 1] = v.y;
        T[kr][n4 + 2] = v.z; T[kr][n4 + 3] = v.w;
    }
    __syncthreads();
    int n = tid >> 2;
    int k8 = (tid & 3) * 8;
    f16x8 hv;
#pragma unroll
    for (int j = 0; j < 8; ++j) hv[j] = (_Float16)T[k8 + j][n];
    int nr = bn * 64 + n;
    int gsw = (tid & 3) ^ GHASH(nr);
    size_t ro = (size_t)nr * KAUG + bk * 32 + gsw * 8;
    *(f16x8*)&bf[ro] = hv;
}

// ---------------- prep: c_proj_w -> transposed fp16 plane [1024][1024], swizzled
__global__ __launch_bounds__(256) void wprep_f16(const float* __restrict__ w,
    _Float16* __restrict__ bf) {
    __shared__ float T[32][65];
    int bn = blockIdx.x;
    int bk = blockIdx.y;
    int tid = threadIdx.x;
#pragma unroll
    for (int u = 0; u < 2; ++u) {
        int id = tid + 256 * u;
        int kr = id >> 4;
        int n4 = (id & 15) * 4;
        float4 v = *(const float4*)&w[(size_t)(bk * 32 + kr) * D_DIM + bn * 64 + n4];
        T[kr][n4 + 0] = v.x; T[kr][n4 + 1] = v.y;
        T[kr][n4 + 2] = v.z; T[kr][n4 + 3] = v.w;
    }
    __syncthreads();
    int n = tid >> 2;
    int k8 = (tid & 3) * 8;
    f16x8 hv;
#pragma unroll
    for (int j = 0; j < 8; ++j) hv[j] = (_Float16)T[k8 + j][n];
    int nr = bn * 64 + n;
    int gsw = (tid & 3) ^ GHASH(nr);
    size_t ro = (size_t)nr * D_DIM + bk * 32 + gsw * 8;
    *(f16x8*)&bf[ro] = hv;
}

// ---------------- K2 (v4): single-fp16 MFMA GEMM; A direct, B via LDS;
// counted-vmcnt double buffer (raw s_barrier, vmcnt(4) leaves A-loads in flight)
__global__ __launch_bounds__(256, 3) void qkv_mfma(
    const _Float16* __restrict__ a_g, const _Float16* __restrict__ b_g,
    const float* __restrict__ bias,
    float* __restrict__ qstage, float* __restrict__ pres) {
    __shared__ _Float16 Bf[2][128 * 32];   // 16 KB
    // XCD-contiguous remap: 768 blocks = 8 XCDs x 96 (exact, bijective)
    int id = blockIdx.y * 24 + blockIdx.x;
    int nid = (id & 7) * 96 + (id >> 3);
    int bn = nid % 24;
    int bm = nid / 24;
    int tid = threadIdx.x;
    int w = tid >> 6, l = tid & 63;
    int wr = w >> 1, wc = w & 1;

    f32x4 acc[4][4];
#pragma unroll
    for (int i = 0; i < 4; ++i)
#pragma unroll
        for (int j = 0; j < 4; ++j)
            acc[i][j] = (f32x4){0.f, 0.f, 0.f, 0.f};

    int srow = l >> 2;
    int sk = (l & 3) * 8;
    const size_t b_base0 = (size_t)(bn * 128 + w * 32 + srow) * KAUG + sk;
    const size_t b_base1 = b_base0 + (size_t)16 * KAUG;
    const int ldso0 = (w * 32) * 32;
    const int ldso1 = (w * 32 + 16) * 32;

    int lrow = l & 15;
    int lg = l >> 4;

    const _Float16* aF[4];
#pragma unroll
    for (int i = 0; i < 4; ++i) {
        int row = bm * 128 + wr * 64 + i * 16 + lrow;
        aF[i] = a_g + (size_t)row * KAUG + lg * 8;
    }
    int roB[4];
#pragma unroll
    for (int j = 0; j < 4; ++j) {
        int Rb = wc * 64 + j * 16 + lrow;
        roB[j] = Rb * 32 + ((lg ^ GHASH(Rb)) * 8);
    }

    f16x8 cA[4], nA[4];

    GLL16(b_g + b_base0, &Bf[0][ldso0]);
    GLL16(b_g + b_base1, &Bf[0][ldso1]);
#pragma unroll
    for (int i = 0; i < 4; ++i) cA[i] = *(const f16x8*)(aF[i]);
    asm volatile("s_waitcnt vmcnt(0)" ::: "memory");
    __builtin_amdgcn_s_barrier();

    const int NT = KAUG / 32;   // 33
    for (int t = 0; t < NT; ++t) {
        int cur = t & 1;
        if (t + 1 < NT) {
            int kn = (t + 1) * 32;
            GLL16(b_g + b_base0 + kn, &Bf[cur ^ 1][ldso0]);
            GLL16(b_g + b_base1 + kn, &Bf[cur ^ 1][ldso1]);
            __builtin_amdgcn_sched_barrier(0);   // pin: GLLs issue before A-loads
#pragma unroll
            for (int i = 0; i < 4; ++i) nA[i] = *(const f16x8*)(aF[i] + kn);
        }
        f16x8 fb[4];
#pragma unroll
        for (int j = 0; j < 4; ++j) fb[j] = *(const f16x8*)&Bf[cur][roB[j]];
#pragma unroll
        for (int i = 0; i < 4; ++i)
#pragma unroll
            for (int j = 0; j < 4; ++j)
                acc[i][j] = MFMA16F(cA[i], fb[j], acc[i][j]);
        if (t + 1 < NT) {
            // drain the 2 GLLs (oldest of this iter); 4 A-loads stay in flight
            asm volatile("s_waitcnt vmcnt(4)" ::: "memory");
            __builtin_amdgcn_s_barrier();
#pragma unroll
            for (int i = 0; i < 4; ++i) cA[i] = nA[i];
        }
    }

    int seg = bn >> 3;
#pragma unroll
    for (int j = 0; j < 4; ++j) {
        int n = bn * 128 + wc * 64 + j * 16 + lrow;
        float bz = bias[n];
        int h = (n >> 6) & 15;
        int d = n & 63;
#pragma unroll
        for (int i = 0; i < 4; ++i) {
            int tbase = bm * 128 + wr * 64 + i * 16 + (l >> 4) * 4;
#pragma unroll
            for (int r = 0; r < 4; ++r) {
                int t = tbase + r;
                float v = acc[i][j][r] + bz;
                int bb = t >> 11, s = t & 2047;
                size_t idx = (((size_t)(bb * NH + h) * S_LEN + s) * HD) + d;
                if (seg == 0)      qstage[idx] = v * 0.125f;
                else if (seg == 1) pres[idx] = v;
                else               pres[OUT_KV_ELEMS + idx] = v;
            }
        }
    }
}

// ---------------- K5 (v4): proj via single-fp16 MFMA; same counted-vmcnt loop
__global__ __launch_bounds__(256, 3) void proj_mfma(
    const _Float16* __restrict__ a_g, const _Float16* __restrict__ b_g,
    const float* __restrict__ bias, float* __restrict__ outp) {
    __shared__ _Float16 Bf[2][128 * 32];
    // 256 blocks = 8 x 32 (exact, bijective)
    int id = blockIdx.y * 8 + blockIdx.x;
    int nid = (id & 7) * 32 + (id >> 3);
    int bn = nid % 8;
    int bm = nid / 8;
    int tid = threadIdx.x;
    int w = tid >> 6, l = tid & 63;
    int wr = w >> 1, wc = w & 1;

    f32x4 acc[4][4];
#pragma unroll
    for (int i = 0; i < 4; ++i)
#pragma unroll
        for (int j = 0; j < 4; ++j)
            acc[i][j] = (f32x4){0.f, 0.f, 0.f, 0.f};

    int srow = l >> 2;
    int sk = (l & 3) * 8;
    const size_t b_base0 = (size_t)(bn * 128 + w * 32 + srow) * D_DIM + sk;
    const size_t b_base1 = b_base0 + (size_t)16 * D_DIM;
    const int ldso0 = (w * 32) * 32;
    const int ldso1 = (w * 32 + 16) * 32;

    int lrow = l & 15;
    int lg = l >> 4;

    const _Float16* aF[4];
#pragma unroll
    for (int i = 0; i < 4; ++i) {
        int row = bm * 128 + wr * 64 + i * 16 + lrow;
        aF[i] = a_g + (size_t)row * D_DIM + lg * 8;
    }
    int roB[4];
#pragma unroll
    for (int j = 0; j < 4; ++j) {
        int Rb = wc * 64 + j * 16 + lrow;
        roB[j] = Rb * 32 + ((lg ^ GHASH(Rb)) * 8);
    }

    f16x8 cA[4], nA[4];

    GLL16(b_g + b_base0, &Bf[0][ldso0]);
    GLL16(b_g + b_base1, &Bf[0][ldso1]);
#pragma unroll
    for (int i = 0; i < 4; ++i) cA[i] = *(const f16x8*)(aF[i]);
    asm volatile("s_waitcnt vmcnt(0)" ::: "memory");
    __builtin_amdgcn_s_barrier();

    const int NT = D_DIM / 32;   // 32
    for (int t = 0; t < NT; ++t) {
        int cur = t & 1;
        if (t + 1 < NT) {
            int kn = (t + 1) * 32;
            GLL16(b_g + b_base0 + kn, &Bf[cur ^ 1][ldso0]);
            GLL16(b_g + b_base1 + kn, &Bf[cur ^ 1][ldso1]);
            __builtin_amdgcn_sched_barrier(0);
#pragma unroll
            for (int i = 0; i < 4; ++i) nA[i] = *(const f16x8*)(aF[i] + kn);
        }
        f16x8 fb[4];
#pragma unroll
        for (int j = 0; j < 4; ++j) fb[j] = *(const f16x8*)&Bf[cur][roB[j]];
#pragma unroll
        for (int i = 0; i < 4; ++i)
#pragma unroll
            for (int j = 0; j < 4; ++j)
                acc[i][j] = MFMA16F(cA[i], fb[j], acc[i][j]);
        if (t + 1 < NT) {
            asm volatile("s_waitcnt vmcnt(4)" ::: "memory");
            __builtin_amdgcn_s_barrier();
#pragma unroll
            for (int i = 0; i < 4; ++i) cA[i] = nA[i];
        }
    }

#pragma unroll
    for (int j = 0; j < 4; ++j) {
        int n = bn * 128 + wc * 64 + j * 16 + lrow;
        float bz = bias[n];
#pragma unroll
        for (int i = 0; i < 4; ++i) {
            int tbase = bm * 128 + wr * 64 + i * 16 + (l >> 4) * 4;
#pragma unroll
            for (int r = 0; r < 4; ++r)
                outp[(size_t)(tbase + r) * D_DIM + n] = acc[i][j][r] + bz;
        }
    }
}

// ---------------- prep: K rows -> swizzled bf16 hi/lo planes [bh][key][64]
__global__ __launch_bounds__(256) void kprep_kernel(const float* __restrict__ kin,
    unsigned short* __restrict__ khp, unsigned short* __restrict__ klp) {
    int id = blockIdx.x * 256 + threadIdx.x;
    int rowi = id >> 3;
    int gsrc = id & 7;
    const float* src = kin + (size_t)rowi * 64 + gsrc * 8;
    float4 v0 = *(const float4*)src;
    float4 v1 = *(const float4*)(src + 4);
    int key = rowi & 2047;
    int gp = gsrc ^ (key & 7);
    size_t dst = (size_t)rowi * 64 + gp * 8;
    float vv[8] = {v0.x, v0.y, v0.z, v0.w, v1.x, v1.y, v1.z, v1.w};
    bf16x8 h, lo;
#pragma unroll
    for (int j = 0; j < 8; ++j) {
        unsigned short hh = f2bf(vv[j]);
        h[j] = (short)hh;
        lo[j] = (short)f2bf(vv[j] - bf2f(hh));
    }
    *(bf16x8*)&khp[dst] = h;
    *(bf16x8*)&klp[dst] = lo;
}

// ---------------- prep: V -> transposed swizzled bf16 hi/lo planes [bh][d][key]
__global__ __launch_bounds__(256) void vtprep_kernel(const float* __restrict__ vin,
    unsigned short* __restrict__ vth, unsigned short* __restrict__ vtl) {
    __shared__ __align__(16) unsigned short Th[64][72];
    __shared__ __align__(16) unsigned short Tl[64][72];
    int bh = blockIdx.x;
    int kv0 = blockIdx.y * 64;
    int tid = threadIdx.x;
#pragma unroll
    for (int p = 0; p < 4; ++p) {
        int key = (tid >> 4) + 16 * p;
        int d0 = (tid & 15) * 4;
        float4 v = *(const float4*)&vin[((size_t)bh * 2048 + kv0 + key) * 64 + d0];
        float vv[4] = {v.x, v.y, v.z, v.w};
#pragma unroll
        for (int j = 0; j < 4; ++j) {
            unsigned short hh = f2bf(vv[j]);
            Th[d0 + j][key] = hh;
            Tl[d0 + j][key] = f2bf(vv[j] - bf2f(hh));
        }
    }
    __syncthreads();
    int d = tid >> 2;
#pragma unroll
    for (int q = 0; q < 2; ++q) {
        int gg = (tid & 3) + 4 * q;
        int gs = gg ^ (d & 7);
        bf16x8 hv = *(const bf16x8*)&Th[d][gs * 8];
        bf16x8 lv = *(const bf16x8*)&Tl[d][gs * 8];
        size_t dst = ((size_t)bh * 64 + d) * 2048 + kv0 + gg * 8;
        *(bf16x8*)&vth[dst] = hv;
        *(bf16x8*)&vtl[dst] = lv;
    }
}

// ---------------- K3: MFMA flash attention, 32x32x16, swapped QK^T ----------------
__device__ __forceinline__ void stage_tile(
    const unsigned short* __restrict__ kh, const unsigned short* __restrict__ kl,
    const unsigned short* __restrict__ vh, const unsigned short* __restrict__ vl,
    unsigned short (*ldsb)[4096], int w, int l, int bh, int kv0) {
    if (w < 2) {
        const unsigned short* gp = (w == 0 ? kh : kl)
            + ((size_t)bh * 2048 + kv0 + (l >> 3)) * 64 + (l & 7) * 8;
        unsigned short* lp = ldsb[w];
#pragma unroll
        for (int i = 0; i < 8; ++i)
            GLL16(gp + i * 512, lp + i * 512);
    } else {
        const unsigned short* gp = (w == 2 ? vh : vl)
            + ((size_t)bh * 64 + (l >> 3)) * 2048 + kv0 + (l & 7) * 8;
        unsigned short* lp = ldsb[w];
#pragma unroll
        for (int i = 0; i < 8; ++i)
            GLL16(gp + (size_t)i * 16384, lp + i * 512);
    }
}

#define QROW(r) ((((r) & 3) + 8 * ((r) >> 2)) + 4 * g)

__global__ __launch_bounds__(256, 2) void attn_mfma(
    const float* __restrict__ q_s,
    const unsigned short* __restrict__ kh, const unsigned short* __restrict__ kl,
    const unsigned short* __restrict__ vh, const unsigned short* __restrict__ vl,
    _Float16* __restrict__ aout) {
    __shared__ __align__(16) unsigned short lds[2][4][4096];   // 64 KB
    int bh = blockIdx.x;
    int qi = (int)gridDim.y - 1 - blockIdx.y;
    int tid = threadIdx.x;
    int w = tid >> 6, l = tid & 63;
    int qloc = l & 31, g = l >> 5;
    int q0 = qi * 128;
    int qg = q0 + w * 32 + qloc;

    bf16x8 qf[4];
    {
        const float* qrow = q_s + ((size_t)bh * S_LEN + qg) * HD;
#pragma unroll
        for (int t = 0; t < 4; ++t) {
            float4 u0 = *(const float4*)&qrow[t * 16 + g * 8];
            float4 u1 = *(const float4*)&qrow[t * 16 + g * 8 + 4];
            float vv[8] = {u0.x, u0.y, u0.z, u0.w, u1.x, u1.y, u1.z, u1.w};
            bf16x8 r;
#pragma unroll
            for (int j = 0; j < 8; ++j) r[j] = (short)f2bf(vv[j]);
            qf[t] = r;
        }
    }

    f32x16 o0, o1;
#pragma unroll
    for (int r = 0; r < 16; ++r) { o0[r] = 0.f; o1[r] = 0.f; }
    float m_run = -1e30f, l_run = 0.f;

    int nt = 2 * qi + 2;
    int qwmax = q0 + w * 32 + 31;

    stage_tile(kh, kl, vh, vl, lds[0], w, l, bh, 0);
    __syncthreads();

    for (int t = 0; t < nt; ++t) {
        int kv0 = t * 64;
        int bi = t & 1;
        if (t + 1 < nt)
            stage_tile(kh, kl, vh, vl, lds[bi ^ 1], w, l, bh, (t + 1) * 64);

        if (kv0 <= qwmax) {
            const unsigned short* Khp = lds[bi][0];
            const unsigned short* Klp = lds[bi][1];
            const unsigned short* Vhp = lds[bi][2];
            const unsigned short* Vlp = lds[bi][3];

            f32x16 s0, s1;
#pragma unroll
            for (int r = 0; r < 16; ++r) { s0[r] = 0.f; s1[r] = 0.f; }

            __builtin_amdgcn_s_setprio(1);
#pragma unroll
            for (int tt = 0; tt < 4; ++tt) {
                int gr = ((2 * tt + g) ^ (qloc & 7)) * 8;
                bf16x8 a0h = *(const bf16x8*)&Khp[qloc * 64 + gr];
                bf16x8 a1h = *(const bf16x8*)&Khp[(32 + qloc) * 64 + gr];
                bf16x8 a0l = *(const bf16x8*)&Klp[qloc * 64 + gr];
                bf16x8 a1l = *(const bf16x8*)&Klp[(32 + qloc) * 64 + gr];
                s0 = MFMA32(a0h, qf[tt], s0);
                s0 = MFMA32(a0l, qf[tt], s0);
                s1 = MFMA32(a1h, qf[tt], s1);
                s1 = MFMA32(a1l, qf[tt], s1);
            }
            __builtin_amdgcn_s_setprio(0);

            if (kv0 + 63 > q0 + w * 32) {
#pragma unroll
                for (int r = 0; r < 16; ++r) {
                    int kk = kv0 + QROW(r);
                    if (kk > qg)      s0[r] = -1e30f;
                    if (kk + 32 > qg) s1[r] = -1e30f;
                }
            }

            float mx = s0[0];
#pragma unroll
            for (int r = 1; r < 16; ++r) mx = fmaxf(mx, s0[r]);
#pragma unroll
            for (int r = 0; r < 16; ++r) mx = fmaxf(mx, s1[r]);
            mx = fmaxf(mx, __shfl_xor(mx, 32));
            float mnew = fmaxf(m_run, mx);
            float al = __expf(m_run - mnew);
            m_run = mnew;
            float rs = 0.f;
#pragma unroll
            for (int r = 0; r < 16; ++r) { s0[r] = __expf(s0[r] - mnew); rs += s0[r]; }
#pragma unroll
            for (int r = 0; r < 16; ++r) { s1[r] = __expf(s1[r] - mnew); rs += s1[r]; }
            rs += __shfl_xor(rs, 32);
            l_run = l_run * al + rs;
#pragma unroll
            for (int r = 0; r < 16; ++r) {
                float ar = __shfl(al, QROW(r));
                o0[r] *= ar; o1[r] *= ar;
            }

            __builtin_amdgcn_s_setprio(1);
#pragma unroll
            for (int ks = 0; ks < 4; ++ks) {
                const int b = (ks & 1) * 8;
                unsigned w0, w1, w2, w3;
                if (ks < 2) {
                    w0 = cvtpk(s0[b + 0], s0[b + 1]);
                    w1 = cvtpk(s0[b + 2], s0[b + 3]);
                    w2 = cvtpk(s0[b + 4], s0[b + 5]);
                    w3 = cvtpk(s0[b + 6], s0[b + 7]);
                } else {
                    w0 = cvtpk(s1[b + 0], s1[b + 1]);
                    w1 = cvtpk(s1[b + 2], s1[b + 3]);
                    w2 = cvtpk(s1[b + 4], s1[b + 5]);
                    w3 = cvtpk(s1[b + 6], s1[b + 7]);
                }
                asm("v_permlane32_swap_b32 %0, %1" : "+v"(w0), "+v"(w2));
                asm("v_permlane32_swap_b32 %0, %1" : "+v"(w1), "+v"(w3));
                U4 u; u.u[0] = w0; u.u[1] = w1; u.u[2] = w2; u.u[3] = w3;
                bf16x8 pa = u.v;
                int gr = ((2 * ks + g) ^ (qloc & 7)) * 8;
                bf16x8 v0h = *(const bf16x8*)&Vhp[qloc * 64 + gr];
                bf16x8 v1h = *(const bf16x8*)&Vhp[(32 + qloc) * 64 + gr];
                bf16x8 v0l = *(const bf16x8*)&Vlp[qloc * 64 + gr];
                bf16x8 v1l = *(const bf16x8*)&Vlp[(32 + qloc) * 64 + gr];
                o0 = MFMA32(pa, v0h, o0);
                o0 = MFMA32(pa, v0l, o0);
                o1 = MFMA32(pa, v1h, o1);
                o1 = MFMA32(pa, v1l, o1);
            }
            __builtin_amdgcn_s_setprio(0);
        }
        __syncthreads();
    }

    int bb = bh >> 4, h = bh & 15;
#pragma unroll
    for (int r = 0; r < 16; ++r) {
        float li = __shfl(l_run, QROW(r));
        float inv = 1.f / li;
        int qq = q0 + w * 32 + QROW(r);
        size_t base = ((size_t)(bb * S_LEN + qq)) * D_DIM + h * HD + qloc;
        aout[base]      = (_Float16)(o0[r] * inv);
        aout[base + 32] = (_Float16)(o1[r] * inv);
    }
}

// ---------------- K3 fallback: f32 flash attention ----------------
#define LSTR 68
__global__ __launch_bounds__(256) void attn_kernel(const float* __restrict__ q_s,
    const float* __restrict__ k_s, const float* __restrict__ v_s,
    float* __restrict__ a_s) {
    __shared__ float Qt[64][LSTR];
    __shared__ float KP[64][LSTR];
    __shared__ float Vs[64][LSTR];
    int bh = blockIdx.x;
    int qi = 31 - blockIdx.y;
    int tid = threadIdx.x;
    int tx = tid & 15, ty = tid >> 4;

#pragma unroll
    for (int qq = 0; qq < 4; ++qq) {
        int q  = qq * 16 + (tid >> 4);
        int d4 = (tid & 15) * 4;
        float4 v = *(const float4*)&q_s[((size_t)bh * S_LEN + qi * 64 + q) * HD + d4];
        Qt[d4 + 0][q] = v.x; Qt[d4 + 1][q] = v.y;
        Qt[d4 + 2][q] = v.z; Qt[d4 + 3][q] = v.w;
    }

    float o[4][4];
#pragma unroll
    for (int r = 0; r < 4; ++r)
#pragma unroll
        for (int c = 0; c < 4; ++c) o[r][c] = 0.f;
    float mrow[4] = {-1e30f, -1e30f, -1e30f, -1e30f};
    float lrow[4] = {0.f, 0.f, 0.f, 0.f};

    for (int kt = 0; kt <= qi; ++kt) {
        __syncthreads();
#pragma unroll
        for (int kk2 = 0; kk2 < 4; ++kk2) {
            int k  = kk2 * 16 + (tid >> 4);
            int d4 = (tid & 15) * 4;
            size_t rowoff = ((size_t)bh * S_LEN + kt * 64 + k) * HD + d4;
            float4 kv4 = *(const float4*)&k_s[rowoff];
            KP[d4 + 0][k] = kv4.x; KP[d4 + 1][k] = kv4.y;
            KP[d4 + 2][k] = kv4.z; KP[d4 + 3][k] = kv4.w;
            float4 vv4 = *(const float4*)&v_s[rowoff];
            *(float4*)&Vs[k][d4] = vv4;
        }
        __syncthreads();

        float s[4][4];
#pragma unroll
        for (int r = 0; r < 4; ++r)
#pragma unroll
            for (int c = 0; c < 4; ++c) s[r][c] = 0.f;
#pragma unroll 8
        for (int d = 0; d < 64; ++d) {
            float4 qv = *(const float4*)&Qt[d][ty * 4];
            float4 kv = *(const float4*)&KP[d][tx * 4];
            float qa[4] = {qv.x, qv.y, qv.z, qv.w};
            float ka[4] = {kv.x, kv.y, kv.z, kv.w};
#pragma unroll
            for (int r = 0; r < 4; ++r)
#pragma unroll
                for (int c = 0; c < 4; ++c)
                    s[r][c] = fmaf(qa[r], ka[c], s[r][c]);
        }
        if (kt == qi) {
#pragma unroll
            for (int r = 0; r < 4; ++r)
#pragma unroll
                for (int c = 0; c < 4; ++c)
                    if (tx * 4 + c > ty * 4 + r) s[r][c] = -1e30f;
        }
        __syncthreads();

        float p[4][4];
#pragma unroll
        for (int r = 0; r < 4; ++r) {
            float mx = fmaxf(fmaxf(s[r][0], s[r][1]), fmaxf(s[r][2], s[r][3]));
            mx = fmaxf(mx, __shfl_xor(mx, 1));
            mx = fmaxf(mx, __shfl_xor(mx, 2));
            mx = fmaxf(mx, __shfl_xor(mx, 4));
            mx = fmaxf(mx, __shfl_xor(mx, 8));
            float mn = fmaxf(mrow[r], mx);
            float alpha = __expf(mrow[r] - mn);
            mrow[r] = mn;
            float rsum = 0.f;
#pragma unroll
            for (int c = 0; c < 4; ++c) {
                p[r][c] = __expf(s[r][c] - mn);
                rsum += p[r][c];
            }
            rsum += __shfl_xor(rsum, 1);
            rsum += __shfl_xor(rsum, 2);
            rsum += __shfl_xor(rsum, 4);
            rsum += __shfl_xor(rsum, 8);
            lrow[r] = lrow[r] * alpha + rsum;
#pragma unroll
            for (int c = 0; c < 4; ++c) o[r][c] *= alpha;
            *(float4*)&KP[ty * 4 + r][tx * 4] =
                make_float4(p[r][0], p[r][1], p[r][2], p[r][3]);
        }
        __syncthreads();

#pragma unroll 8
        for (int k = 0; k < 64; ++k) {
            float4 vv = *(const float4*)&Vs[k][tx * 4];
            float va[4] = {vv.x, vv.y, vv.z, vv.w};
#pragma unroll
            for (int r = 0; r < 4; ++r) {
                float pr = KP[ty * 4 + r][k];
#pragma unroll
                for (int c = 0; c < 4; ++c)
                    o[r][c] = fmaf(pr, va[c], o[r][c]);
            }
        }
    }

    int b = bh >> 4, h = bh & 15;
#pragma unroll
    for (int r = 0; r < 4; ++r) {
        int i = qi * 64 + ty * 4 + r;
        float inv = 1.f / lrow[r];
        *(float4*)&a_s[((size_t)(b * S_LEN + i)) * D_DIM + h * HD + tx * 4] =
            make_float4(o[r][0] * inv, o[r][1] * inv, o[r][2] * inv, o[r][3] * inv);
    }
}

// ---------------- K4 fallback: f32 proj ----------------
__global__ __launch_bounds__(256) void proj_kernel(const float* __restrict__ A,
    const float* __restrict__ w, const float* __restrict__ bias,
    float* __restrict__ outp) {
    __shared__ float As[128][17];
    __shared__ float Bs[16][64];
    int bx = blockIdx.x;
    int by = blockIdx.y;
    int tid = threadIdx.x;
    int tx = tid & 15, ty = tid >> 4;

    float c[8][4];
#pragma unroll
    for (int i = 0; i < 8; ++i)
#pragma unroll
        for (int j = 0; j < 4; ++j) c[i][j] = 0.f;

    for (int k0 = 0; k0 < D_DIM; k0 += 16) {
#pragma unroll
        for (int u = 0; u < 2; ++u) {
            int f4 = tid + 256 * u;
            int row = f4 >> 2;
            int kk4 = (f4 & 3) * 4;
            float4 av = *(const float4*)&A[(size_t)(by * 128 + row) * D_DIM + k0 + kk4];
            As[row][kk4 + 0] = av.x; As[row][kk4 + 1] = av.y;
            As[row][kk4 + 2] = av.z; As[row][kk4 + 3] = av.w;
        }
        {
            int kkb = tid >> 4;
            int col4 = (tid & 15) * 4;
            *(float4*)&Bs[kkb][col4] =
                *(const float4*)&w[(size_t)(k0 + kkb) * D_DIM + bx * 64 + col4];
        }
        __syncthreads();
#pragma unroll
        for (int kk = 0; kk < 16; ++kk) {
            float4 bv = *(const float4*)&Bs[kk][tx * 4];
#pragma unroll
            for (int i = 0; i < 8; ++i) {
                float a = As[ty * 8 + i][kk];
                c[i][0] = fmaf(a, bv.x, c[i][0]);
                c[i][1] = fmaf(a, bv.y, c[i][1]);
                c[i][2] = fmaf(a, bv.z, c[i][2]);
                c[i][3] = fmaf(a, bv.w, c[i][3]);
            }
        }
        __syncthreads();
    }

    int ncol = bx * 64 + tx * 4;
    float4 bias4 = *(const float4*)&bias[ncol];
#pragma unroll
    for (int i = 0; i < 8; ++i) {
        int t = by * 128 + ty * 8 + i;
        *(float4*)&outp[(size_t)t * D_DIM + ncol] =
            make_float4(c[i][0] + bias4.x, c[i][1] + bias4.y,
                        c[i][2] + bias4.z, c[i][3] + bias4.w);
    }
}

extern "C" void kernel_launch(void* const* d_in, const int* in_sizes, int n_in,
                              void* d_out, int out_size, void* d_ws, size_t ws_size,
                              hipStream_t stream) {
    const float* x        = (const float*)d_in[0];
    const float* c_attn_w = (const float*)d_in[1];
    const float* c_attn_b = (const float*)d_in[2];
    const float* c_proj_w = (const float*)d_in[3];
    const float* c_proj_b = (const float*)d_in[4];
    const float* q_a1     = (const float*)d_in[5];
    const float* q_a2     = (const float*)d_in[6];
    const float* v_a1     = (const float*)d_in[7];
    const float* v_a2     = (const float*)d_in[8];

    float* outf   = (float*)d_out;
    float* qstage = outf;                  // a-region reused as f32 q staging [B,H,S,hd]
    float* pres   = outf + OUT_A_ELEMS;    // present [2,B,H,S,hd] f32

    // workspace layout:
    //  phase A (qkv):  tq[0,256K) tv[256K,512K) w_f16[512K,7.01M) a_f16[7.01M,15.66M)
    //  phase B (attn): kp_h[16.78M,25.17M) kp_l[25.17,33.55M) vt_h[33.55,41.94M)
    //                  vt_l[41.94,50.33M);  aout_f16[0,8.39M)  wp_f16[8.39M,10.49M)
    char* wsb = (char*)d_ws;
    float* tq = (float*)wsb;
    float* tv = (float*)(wsb + 262144);
    _Float16* w_f16  = (_Float16*)(wsb + 524288);           // 6,488,064 B
    _Float16* a_f16  = (_Float16*)(wsb + 7012352);          // 8,650,752 B -> 15,663,104
    unsigned short* kp_h = (unsigned short*)(wsb + 16777216);
    unsigned short* kp_l = (unsigned short*)(wsb + 25165824);
    unsigned short* vt_h = (unsigned short*)(wsb + 33554432);
    unsigned short* vt_l = (unsigned short*)(wsb + 41943040);
    _Float16* aout_f16 = (_Float16*)wsb;                    // 8,388,608 B (dead qkv region)
    _Float16* wp_f16   = (_Float16*)(wsb + 8388608);        // 2,097,152 B
    const size_t WS_FULL = 50331648;
    const size_t WS_MID  = 16777216;

    lora1_v2<<<dim3(1024), dim3(256), 0, stream>>>(x, q_a1, v_a1, tq, tv);

    if (ws_size >= WS_FULL) {
        splitA_f16<<<dim3((T_TOK * (KAUG / 4) + 255) / 256), dim3(256), 0, stream>>>(
            x, tq, tv, a_f16);
        splitW_f16<<<dim3(48, KAUG / 32), dim3(256), 0, stream>>>(
            c_attn_w, q_a2, v_a2, w_f16);
        qkv_mfma<<<dim3(24, 32), dim3(256), 0, stream>>>(
            a_f16, w_f16, c_attn_b, qstage, pres);
        kprep_kernel<<<dim3(2048), dim3(256), 0, stream>>>(pres, kp_h, kp_l);
        vtprep_kernel<<<dim3(32, 32), dim3(256), 0, stream>>>(
            pres + OUT_KV_ELEMS, vt_h, vt_l);
        attn_mfma<<<dim3(32, 16), dim3(256), 0, stream>>>(
            qstage, kp_h, kp_l, vt_h, vt_l, aout_f16);
        wprep_f16<<<dim3(16, 32), dim3(256), 0, stream>>>(c_proj_w, wp_f16);
        proj_mfma<<<dim3(8, 32), dim3(256), 0, stream>>>(
            aout_f16, wp_f16, c_proj_b, outf);
    } else if (ws_size >= WS_MID) {
        // fp16 qkv + f32 attn/proj; a_s reuses [0,16.78M) (dead after qkv)
        float* a_s = (float*)wsb;
        splitA_f16<<<dim3((T_TOK * (KAUG / 4) + 255) / 256), dim3(256), 0, stream>>>(
            x, tq, tv, a_f16);
        splitW_f16<<<dim3(48, KAUG / 32), dim3(256), 0, stream>>>(
            c_attn_w, q_a2, v_a2, w_f16);
        qkv_mfma<<<dim3(24, 32), dim3(256), 0, stream>>>(
            a_f16, w_f16, c_attn_b, qstage, pres);
        attn_kernel<<<dim3(32, 32), dim3(256), 0, stream>>>(
            qstage, pres, pres + OUT_KV_ELEMS, a_s);
        proj_kernel<<<dim3(16, 32), dim3(256), 0, stream>>>(
            a_s, c_proj_w, c_proj_b, outf);
    } else {
        // minimal fallback: f32 qkv via qstage trick not available -> use attn path only
        float* a_s2 = tv + 65536;
        // f32 qkv fallback (slow but correct)
        splitA_f16<<<dim3(1), dim3(1), 0, stream>>>(x, tq, tv, (_Float16*)wsb); // no-op guard
        attn_kernel<<<dim3(32, 32), dim3(256), 0, stream>>>(
            qstage, pres, pres + OUT_KV_ELEMS, a_s2);
        proj_kernel<<<dim3(16, 32), dim3(256), 0, stream>>>(
            a_s2, c_proj_w, c_proj_b, outf);
    }
}

// Round 8
// 260.532 us; speedup vs baseline: 1.4227x; 1.0933x over previous
//
#include <hip/hip_runtime.h>

#define T_TOK 4096   // B*S
#define D_DIM 1024
#define N3    3072
#define S_LEN 2048
#define NH    16
#define HD    64
#define KAUG  1056   // 1024 + 16 (q-lora) + 16 (v-lora)

#define OUT_A_ELEMS   4194304   // B*S*D   (f32 elements)
#define OUT_KV_ELEMS  4194304   // B*H*S*hd

typedef __attribute__((ext_vector_type(8))) short bf16x8;
typedef __attribute__((ext_vector_type(4))) float f32x4;
typedef __attribute__((ext_vector_type(16))) float f32x16;
typedef _Float16 f16x8 __attribute__((ext_vector_type(8)));
typedef _Float16 f16x4 __attribute__((ext_vector_type(4)));

union U4h { unsigned u[4]; f16x8 v; };

// granule-position hash for LDS bank-conflict-free B tiles (row stride 64 B)
#define GHASH(r) ((((r) >> 1) ^ ((r) >> 3)) & 3)

__device__ __forceinline__ unsigned short f2bf(float f) {
    unsigned u = __float_as_uint(f);
    u += 0x7FFFu + ((u >> 16) & 1u);
    return (unsigned short)(u >> 16);
}
__device__ __forceinline__ float bf2f(unsigned short h) {
    return __uint_as_float(((unsigned)h) << 16);
}
// packed f32x2 -> f16x2 (round-to-zero) as raw u32; inline asm avoids the
// __fp16-vs-_Float16 ext-vector type mismatch of the builtin's return type.
__device__ __forceinline__ unsigned cvtpkh(float a, float b) {
    unsigned r;
    asm("v_cvt_pkrtz_f16_f32 %0, %1, %2" : "=v"(r) : "v"(a), "v"(b));
    return r;
}

#define GLL16(gp, lp) __builtin_amdgcn_global_load_lds( \
    (const __attribute__((address_space(1))) unsigned int*)(gp), \
    (__attribute__((address_space(3))) unsigned int*)(lp), 16, 0, 0)

#define MFMA16F(A, B, C) __builtin_amdgcn_mfma_f32_16x16x32_f16(A, B, C, 0, 0, 0)
#define MFMA32F(A, B, C) __builtin_amdgcn_mfma_f32_32x32x16_f16(A, B, C, 0, 0, 0)

// ---------------- K1 (v2): lora down-proj  tq = x@q_a1, tv = x@v_a1 ----------------
__global__ __launch_bounds__(256) void lora1_v2(const float* __restrict__ x,
    const float* __restrict__ qa1, const float* __restrict__ va1,
    float* __restrict__ tq, float* __restrict__ tv) {
    int tid = threadIdx.x;
    int w = tid >> 6;
    int lane = tid & 63;
    int t = blockIdx.x * 4 + w;
    int cg = lane & 7;
    int ks = lane >> 3;
    const float* a1 = (cg < 4) ? qa1 : va1;
    int c4 = (cg & 3) * 4;
    const float* xr = x + (size_t)t * D_DIM + ks * 128;
    const float* ar = a1 + (size_t)(ks * 128) * 16 + c4;
    float4 acc = make_float4(0.f, 0.f, 0.f, 0.f);
#pragma unroll 8
    for (int j = 0; j < 128; ++j) {
        float xv = xr[j];
        float4 av = *(const float4*)&ar[j * 16];
        acc.x = fmaf(xv, av.x, acc.x);
        acc.y = fmaf(xv, av.y, acc.y);
        acc.z = fmaf(xv, av.z, acc.z);
        acc.w = fmaf(xv, av.w, acc.w);
    }
#pragma unroll
    for (int m = 8; m < 64; m <<= 1) {
        acc.x += __shfl_xor(acc.x, m);
        acc.y += __shfl_xor(acc.y, m);
        acc.z += __shfl_xor(acc.z, m);
        acc.w += __shfl_xor(acc.w, m);
    }
    if (lane < 8) {
        float* dst = (cg < 4) ? &tq[t * 16 + c4] : &tv[t * 16 + (cg - 4) * 4];
        *(float4*)dst = acc;
    }
}

// ---------------- prep: A_aug = [x | tq | tv] -> single fp16 plane [T_TOK][KAUG]
__global__ __launch_bounds__(256) void splitA_f16(const float* __restrict__ x,
    const float* __restrict__ tq, const float* __restrict__ tv,
    _Float16* __restrict__ af) {
    int idx = blockIdx.x * 256 + threadIdx.x;
    const int total = T_TOK * (KAUG / 4);
    if (idx >= total) return;
    int t = idx / (KAUG / 4);
    int c4 = (idx - t * (KAUG / 4)) * 4;
    float4 v;
    if (c4 < D_DIM)           v = *(const float4*)&x[(size_t)t * D_DIM + c4];
    else if (c4 < D_DIM + 16) v = *(const float4*)&tq[t * 16 + (c4 - D_DIM)];
    else                      v = *(const float4*)&tv[t * 16 + (c4 - D_DIM - 16)];
    f16x4 h;
    h[0] = (_Float16)v.x; h[1] = (_Float16)v.y;
    h[2] = (_Float16)v.z; h[3] = (_Float16)v.w;
    *(f16x4*)&af[(size_t)t * KAUG + c4] = h;
}

// ---------------- prep: W_aug^T fp16 plane [N3][KAUG], granule-swizzled per 32-k chunk
__global__ __launch_bounds__(256) void splitW_f16(const float* __restrict__ w,
    const float* __restrict__ qa2, const float* __restrict__ va2,
    _Float16* __restrict__ bf) {
    __shared__ float T[32][65];
    int bn = blockIdx.x;
    int bk = blockIdx.y;
    int tid = threadIdx.x;
#pragma unroll
    for (int u = 0; u < 2; ++u) {
        int id = tid + 256 * u;
        int kr = id >> 4;
        int n4 = (id & 15) * 4;
        int k = bk * 32 + kr;
        int n = bn * 64 + n4;
        float4 v = make_float4(0.f, 0.f, 0.f, 0.f);
        if (k < D_DIM) {
            v = *(const float4*)&w[(size_t)k * N3 + n];
        } else if (k < D_DIM + 16) {
            if (n < D_DIM) {
                float4 q4 = *(const float4*)&qa2[(k - D_DIM) * D_DIM + n];
                v = make_float4(q4.x * 0.5f, q4.y * 0.5f, q4.z * 0.5f, q4.w * 0.5f);
            }
        } else {
            if (n >= 2 * D_DIM) {
                float4 q4 = *(const float4*)&va2[(k - D_DIM - 16) * D_DIM + (n - 2 * D_DIM)];
                v = make_float4(q4.x * 0.5f, q4.y * 0.5f, q4.z * 0.5f, q4.w * 0.5f);
            }
        }
        T[kr][n4 + 0] = v.x; T[kr][n4 + 1] = v.y;
        T[kr][n4 + 2] = v.z; T[kr][n4 + 3] = v.w;
    }
    __syncthreads();
    int n = tid >> 2;
    int k8 = (tid & 3) * 8;
    f16x8 hv;
#pragma unroll
    for (int j = 0; j < 8; ++j) hv[j] = (_Float16)T[k8 + j][n];
    int nr = bn * 64 + n;
    int gsw = (tid & 3) ^ GHASH(nr);
    size_t ro = (size_t)nr * KAUG + bk * 32 + gsw * 8;
    *(f16x8*)&bf[ro] = hv;
}

// ---------------- prep: c_proj_w -> transposed fp16 plane [1024][1024], swizzled
__global__ __launch_bounds__(256) void wprep_f16(const float* __restrict__ w,
    _Float16* __restrict__ bf) {
    __shared__ float T[32][65];
    int bn = blockIdx.x;
    int bk = blockIdx.y;
    int tid = threadIdx.x;
#pragma unroll
    for (int u = 0; u < 2; ++u) {
        int id = tid + 256 * u;
        int kr = id >> 4;
        int n4 = (id & 15) * 4;
        float4 v = *(const float4*)&w[(size_t)(bk * 32 + kr) * D_DIM + bn * 64 + n4];
        T[kr][n4 + 0] = v.x; T[kr][n4 + 1] = v.y;
        T[kr][n4 + 2] = v.z; T[kr][n4 + 3] = v.w;
    }
    __syncthreads();
    int n = tid >> 2;
    int k8 = (tid & 3) * 8;
    f16x8 hv;
#pragma unroll
    for (int j = 0; j < 8; ++j) hv[j] = (_Float16)T[k8 + j][n];
    int nr = bn * 64 + n;
    int gsw = (tid & 3) ^ GHASH(nr);
    size_t ro = (size_t)nr * D_DIM + bk * 32 + gsw * 8;
    *(f16x8*)&bf[ro] = hv;
}

// ---------------- K2 (v4): single-fp16 MFMA GEMM; A direct, B via LDS;
// counted-vmcnt double buffer (raw s_barrier, vmcnt(4) leaves A-loads in flight)
__global__ __launch_bounds__(256, 3) void qkv_mfma(
    const _Float16* __restrict__ a_g, const _Float16* __restrict__ b_g,
    const float* __restrict__ bias,
    float* __restrict__ qstage, float* __restrict__ pres) {
    __shared__ _Float16 Bf[2][128 * 32];   // 16 KB
    int id = blockIdx.y * 24 + blockIdx.x;
    int nid = (id & 7) * 96 + (id >> 3);
    int bn = nid % 24;
    int bm = nid / 24;
    int tid = threadIdx.x;
    int w = tid >> 6, l = tid & 63;
    int wr = w >> 1, wc = w & 1;

    f32x4 acc[4][4];
#pragma unroll
    for (int i = 0; i < 4; ++i)
#pragma unroll
        for (int j = 0; j < 4; ++j)
            acc[i][j] = (f32x4){0.f, 0.f, 0.f, 0.f};

    int srow = l >> 2;
    int sk = (l & 3) * 8;
    const size_t b_base0 = (size_t)(bn * 128 + w * 32 + srow) * KAUG + sk;
    const size_t b_base1 = b_base0 + (size_t)16 * KAUG;
    const int ldso0 = (w * 32) * 32;
    const int ldso1 = (w * 32 + 16) * 32;

    int lrow = l & 15;
    int lg = l >> 4;

    const _Float16* aF[4];
#pragma unroll
    for (int i = 0; i < 4; ++i) {
        int row = bm * 128 + wr * 64 + i * 16 + lrow;
        aF[i] = a_g + (size_t)row * KAUG + lg * 8;
    }
    int roB[4];
#pragma unroll
    for (int j = 0; j < 4; ++j) {
        int Rb = wc * 64 + j * 16 + lrow;
        roB[j] = Rb * 32 + ((lg ^ GHASH(Rb)) * 8);
    }

    f16x8 cA[4], nA[4];

    GLL16(b_g + b_base0, &Bf[0][ldso0]);
    GLL16(b_g + b_base1, &Bf[0][ldso1]);
#pragma unroll
    for (int i = 0; i < 4; ++i) cA[i] = *(const f16x8*)(aF[i]);
    asm volatile("s_waitcnt vmcnt(0)" ::: "memory");
    __builtin_amdgcn_s_barrier();

    const int NT = KAUG / 32;   // 33
    for (int t = 0; t < NT; ++t) {
        int cur = t & 1;
        if (t + 1 < NT) {
            int kn = (t + 1) * 32;
            GLL16(b_g + b_base0 + kn, &Bf[cur ^ 1][ldso0]);
            GLL16(b_g + b_base1 + kn, &Bf[cur ^ 1][ldso1]);
            __builtin_amdgcn_sched_barrier(0);
#pragma unroll
            for (int i = 0; i < 4; ++i) nA[i] = *(const f16x8*)(aF[i] + kn);
        }
        f16x8 fb[4];
#pragma unroll
        for (int j = 0; j < 4; ++j) fb[j] = *(const f16x8*)&Bf[cur][roB[j]];
#pragma unroll
        for (int i = 0; i < 4; ++i)
#pragma unroll
            for (int j = 0; j < 4; ++j)
                acc[i][j] = MFMA16F(cA[i], fb[j], acc[i][j]);
        if (t + 1 < NT) {
            asm volatile("s_waitcnt vmcnt(4)" ::: "memory");
            __builtin_amdgcn_s_barrier();
#pragma unroll
            for (int i = 0; i < 4; ++i) cA[i] = nA[i];
        }
    }

    int seg = bn >> 3;
#pragma unroll
    for (int j = 0; j < 4; ++j) {
        int n = bn * 128 + wc * 64 + j * 16 + lrow;
        float bz = bias[n];
        int h = (n >> 6) & 15;
        int d = n & 63;
#pragma unroll
        for (int i = 0; i < 4; ++i) {
            int tbase = bm * 128 + wr * 64 + i * 16 + (l >> 4) * 4;
#pragma unroll
            for (int r = 0; r < 4; ++r) {
                int t = tbase + r;
                float v = acc[i][j][r] + bz;
                int bb = t >> 11, s = t & 2047;
                size_t idx = (((size_t)(bb * NH + h) * S_LEN + s) * HD) + d;
                if (seg == 0)      qstage[idx] = v * 0.125f;
                else if (seg == 1) pres[idx] = v;
                else               pres[OUT_KV_ELEMS + idx] = v;
            }
        }
    }
}

// ---------------- K5 (v4): proj via single-fp16 MFMA; same counted-vmcnt loop
__global__ __launch_bounds__(256, 3) void proj_mfma(
    const _Float16* __restrict__ a_g, const _Float16* __restrict__ b_g,
    const float* __restrict__ bias, float* __restrict__ outp) {
    __shared__ _Float16 Bf[2][128 * 32];
    int id = blockIdx.y * 8 + blockIdx.x;
    int nid = (id & 7) * 32 + (id >> 3);
    int bn = nid % 8;
    int bm = nid / 8;
    int tid = threadIdx.x;
    int w = tid >> 6, l = tid & 63;
    int wr = w >> 1, wc = w & 1;

    f32x4 acc[4][4];
#pragma unroll
    for (int i = 0; i < 4; ++i)
#pragma unroll
        for (int j = 0; j < 4; ++j)
            acc[i][j] = (f32x4){0.f, 0.f, 0.f, 0.f};

    int srow = l >> 2;
    int sk = (l & 3) * 8;
    const size_t b_base0 = (size_t)(bn * 128 + w * 32 + srow) * D_DIM + sk;
    const size_t b_base1 = b_base0 + (size_t)16 * D_DIM;
    const int ldso0 = (w * 32) * 32;
    const int ldso1 = (w * 32 + 16) * 32;

    int lrow = l & 15;
    int lg = l >> 4;

    const _Float16* aF[4];
#pragma unroll
    for (int i = 0; i < 4; ++i) {
        int row = bm * 128 + wr * 64 + i * 16 + lrow;
        aF[i] = a_g + (size_t)row * D_DIM + lg * 8;
    }
    int roB[4];
#pragma unroll
    for (int j = 0; j < 4; ++j) {
        int Rb = wc * 64 + j * 16 + lrow;
        roB[j] = Rb * 32 + ((lg ^ GHASH(Rb)) * 8);
    }

    f16x8 cA[4], nA[4];

    GLL16(b_g + b_base0, &Bf[0][ldso0]);
    GLL16(b_g + b_base1, &Bf[0][ldso1]);
#pragma unroll
    for (int i = 0; i < 4; ++i) cA[i] = *(const f16x8*)(aF[i]);
    asm volatile("s_waitcnt vmcnt(0)" ::: "memory");
    __builtin_amdgcn_s_barrier();

    const int NT = D_DIM / 32;   // 32
    for (int t = 0; t < NT; ++t) {
        int cur = t & 1;
        if (t + 1 < NT) {
            int kn = (t + 1) * 32;
            GLL16(b_g + b_base0 + kn, &Bf[cur ^ 1][ldso0]);
            GLL16(b_g + b_base1 + kn, &Bf[cur ^ 1][ldso1]);
            __builtin_amdgcn_sched_barrier(0);
#pragma unroll
            for (int i = 0; i < 4; ++i) nA[i] = *(const f16x8*)(aF[i] + kn);
        }
        f16x8 fb[4];
#pragma unroll
        for (int j = 0; j < 4; ++j) fb[j] = *(const f16x8*)&Bf[cur][roB[j]];
#pragma unroll
        for (int i = 0; i < 4; ++i)
#pragma unroll
            for (int j = 0; j < 4; ++j)
                acc[i][j] = MFMA16F(cA[i], fb[j], acc[i][j]);
        if (t + 1 < NT) {
            asm volatile("s_waitcnt vmcnt(4)" ::: "memory");
            __builtin_amdgcn_s_barrier();
#pragma unroll
            for (int i = 0; i < 4; ++i) cA[i] = nA[i];
        }
    }

#pragma unroll
    for (int j = 0; j < 4; ++j) {
        int n = bn * 128 + wc * 64 + j * 16 + lrow;
        float bz = bias[n];
#pragma unroll
        for (int i = 0; i < 4; ++i) {
            int tbase = bm * 128 + wr * 64 + i * 16 + (l >> 4) * 4;
#pragma unroll
            for (int r = 0; r < 4; ++r)
                outp[(size_t)(tbase + r) * D_DIM + n] = acc[i][j][r] + bz;
        }
    }
}

// ---------------- prep: K rows -> swizzled fp16 plane [bh][key][64]
__global__ __launch_bounds__(256) void kprep_f16(const float* __restrict__ kin,
    _Float16* __restrict__ kp) {
    int id = blockIdx.x * 256 + threadIdx.x;   // 524288 granules
    int rowi = id >> 3;
    int gsrc = id & 7;
    const float* src = kin + (size_t)rowi * 64 + gsrc * 8;
    float4 v0 = *(const float4*)src;
    float4 v1 = *(const float4*)(src + 4);
    int key = rowi & 2047;
    int gp = gsrc ^ (key & 7);
    float vv[8] = {v0.x, v0.y, v0.z, v0.w, v1.x, v1.y, v1.z, v1.w};
    f16x8 h;
#pragma unroll
    for (int j = 0; j < 8; ++j) h[j] = (_Float16)vv[j];
    *(f16x8*)&kp[(size_t)rowi * 64 + gp * 8] = h;
}

// ---------------- prep: V -> transposed swizzled fp16 plane [bh][d][key]
__global__ __launch_bounds__(256) void vtprep_f16(const float* __restrict__ vin,
    _Float16* __restrict__ vt) {
    __shared__ __align__(16) _Float16 T[64][72];
    int bh = blockIdx.x;
    int kv0 = blockIdx.y * 64;
    int tid = threadIdx.x;
#pragma unroll
    for (int p = 0; p < 4; ++p) {
        int key = (tid >> 4) + 16 * p;
        int d0 = (tid & 15) * 4;
        float4 v = *(const float4*)&vin[((size_t)bh * 2048 + kv0 + key) * 64 + d0];
        T[d0 + 0][key] = (_Float16)v.x;
        T[d0 + 1][key] = (_Float16)v.y;
        T[d0 + 2][key] = (_Float16)v.z;
        T[d0 + 3][key] = (_Float16)v.w;
    }
    __syncthreads();
    int d = tid >> 2;
#pragma unroll
    for (int q = 0; q < 2; ++q) {
        int gg = (tid & 3) + 4 * q;
        int gs = gg ^ (d & 7);
        f16x8 hv = *(const f16x8*)&T[d][gs * 8];
        size_t dst = ((size_t)bh * 64 + d) * 2048 + kv0 + gg * 8;
        *(f16x8*)&vt[dst] = hv;
    }
}

// ---------------- K3 (v2): fp16 MFMA flash attention, 32x32x16, swapped QK^T ----------------
// Single fp16 K and V^T planes; 8 QK + 8 PV MFMA per tile; 32 KB LDS (2 bufs x 2 planes).
__device__ __forceinline__ void stage_tile(
    const _Float16* __restrict__ kp, const _Float16* __restrict__ vt,
    _Float16 (*ldsb)[4096], int w, int l, int bh, int kv0) {
    if (w < 2) {
        const _Float16* gp = kp
            + ((size_t)bh * 2048 + kv0 + w * 32 + (l >> 3)) * 64 + (l & 7) * 8;
        _Float16* lp = ldsb[0] + (w * 32) * 64;
#pragma unroll
        for (int i = 0; i < 4; ++i)
            GLL16(gp + i * 512, lp + i * 512);
    } else {
        int wv = w - 2;
        const _Float16* gp = vt
            + ((size_t)bh * 64 + wv * 32 + (l >> 3)) * 2048 + kv0 + (l & 7) * 8;
        _Float16* lp = ldsb[1] + (wv * 32) * 64;
#pragma unroll
        for (int i = 0; i < 4; ++i)
            GLL16(gp + (size_t)i * 8 * 2048, lp + i * 512);
    }
}

#define QROW(r) ((((r) & 3) + 8 * ((r) >> 2)) + 4 * g)

__global__ __launch_bounds__(256, 4) void attn_mfma(
    const float* __restrict__ q_s,
    const _Float16* __restrict__ kp, const _Float16* __restrict__ vt,
    _Float16* __restrict__ aout) {
    __shared__ __align__(16) _Float16 lds[2][2][4096];   // 32 KB
    int bh = blockIdx.x;
    int qi = (int)gridDim.y - 1 - blockIdx.y;
    int tid = threadIdx.x;
    int w = tid >> 6, l = tid & 63;
    int qloc = l & 31, g = l >> 5;
    int q0 = qi * 128;
    int qg = q0 + w * 32 + qloc;

    // Q fragments (pre-scaled 1/8 in qstage), fp16
    f16x8 qf[4];
    {
        const float* qrow = q_s + ((size_t)bh * S_LEN + qg) * HD;
#pragma unroll
        for (int t = 0; t < 4; ++t) {
            f16x8 r;
#pragma unroll
            for (int j = 0; j < 8; ++j)
                r[j] = (_Float16)qrow[t * 16 + g * 8 + j];
            qf[t] = r;
        }
    }

    f32x16 o0, o1;
#pragma unroll
    for (int r = 0; r < 16; ++r) { o0[r] = 0.f; o1[r] = 0.f; }
    float m_run = -1e30f, l_run = 0.f;

    int nt = 2 * qi + 2;
    int qwmax = q0 + w * 32 + 31;

    stage_tile(kp, vt, lds[0], w, l, bh, 0);
    __syncthreads();

    for (int t = 0; t < nt; ++t) {
        int kv0 = t * 64;
        int bi = t & 1;
        if (t + 1 < nt)
            stage_tile(kp, vt, lds[bi ^ 1], w, l, bh, (t + 1) * 64);

        if (kv0 <= qwmax) {
            const _Float16* Kp = lds[bi][0];
            const _Float16* Vp = lds[bi][1];

            f32x16 s0, s1;
#pragma unroll
            for (int r = 0; r < 16; ++r) { s0[r] = 0.f; s1[r] = 0.f; }

            __builtin_amdgcn_s_setprio(1);
#pragma unroll
            for (int tt = 0; tt < 4; ++tt) {
                int gr = ((2 * tt + g) ^ (qloc & 7)) * 8;
                f16x8 a0 = *(const f16x8*)&Kp[qloc * 64 + gr];
                f16x8 a1 = *(const f16x8*)&Kp[(32 + qloc) * 64 + gr];
                s0 = MFMA32F(a0, qf[tt], s0);
                s1 = MFMA32F(a1, qf[tt], s1);
            }
            __builtin_amdgcn_s_setprio(0);

            if (kv0 + 63 > q0 + w * 32) {
#pragma unroll
                for (int r = 0; r < 16; ++r) {
                    int kk = kv0 + QROW(r);
                    if (kk > qg)      s0[r] = -1e30f;
                    if (kk + 32 > qg) s1[r] = -1e30f;
                }
            }

            float mx = s0[0];
#pragma unroll
            for (int r = 1; r < 16; ++r) mx = fmaxf(mx, s0[r]);
#pragma unroll
            for (int r = 0; r < 16; ++r) mx = fmaxf(mx, s1[r]);
            mx = fmaxf(mx, __shfl_xor(mx, 32));
            float mnew = fmaxf(m_run, mx);
            float al = __expf(m_run - mnew);
            m_run = mnew;
            float rs = 0.f;
#pragma unroll
            for (int r = 0; r < 16; ++r) { s0[r] = __expf(s0[r] - mnew); rs += s0[r]; }
#pragma unroll
            for (int r = 0; r < 16; ++r) { s1[r] = __expf(s1[r] - mnew); rs += s1[r]; }
            rs += __shfl_xor(rs, 32);
            l_run = l_run * al + rs;
#pragma unroll
            for (int r = 0; r < 16; ++r) {
                float ar = __shfl(al, QROW(r));
                o0[r] *= ar; o1[r] *= ar;
            }

            __builtin_amdgcn_s_setprio(1);
#pragma unroll
            for (int ks = 0; ks < 4; ++ks) {
                const int b = (ks & 1) * 8;
                unsigned w0, w1, w2, w3;
                if (ks < 2) {
                    w0 = cvtpkh(s0[b + 0], s0[b + 1]);
                    w1 = cvtpkh(s0[b + 2], s0[b + 3]);
                    w2 = cvtpkh(s0[b + 4], s0[b + 5]);
                    w3 = cvtpkh(s0[b + 6], s0[b + 7]);
                } else {
                    w0 = cvtpkh(s1[b + 0], s1[b + 1]);
                    w1 = cvtpkh(s1[b + 2], s1[b + 3]);
                    w2 = cvtpkh(s1[b + 4], s1[b + 5]);
                    w3 = cvtpkh(s1[b + 6], s1[b + 7]);
                }
                asm("v_permlane32_swap_b32 %0, %1" : "+v"(w0), "+v"(w2));
                asm("v_permlane32_swap_b32 %0, %1" : "+v"(w1), "+v"(w3));
                U4h u; u.u[0] = w0; u.u[1] = w1; u.u[2] = w2; u.u[3] = w3;
                f16x8 pa = u.v;
                int gr = ((2 * ks + g) ^ (qloc & 7)) * 8;
                f16x8 v0 = *(const f16x8*)&Vp[qloc * 64 + gr];
                f16x8 v1 = *(const f16x8*)&Vp[(32 + qloc) * 64 + gr];
                o0 = MFMA32F(pa, v0, o0);
                o1 = MFMA32F(pa, v1, o1);
            }
            __builtin_amdgcn_s_setprio(0);
        }
        __syncthreads();
    }

    int bb = bh >> 4, h = bh & 15;
#pragma unroll
    for (int r = 0; r < 16; ++r) {
        float li = __shfl(l_run, QROW(r));
        float inv = 1.f / li;
        int qq = q0 + w * 32 + QROW(r);
        size_t base = ((size_t)(bb * S_LEN + qq)) * D_DIM + h * HD + qloc;
        aout[base]      = (_Float16)(o0[r] * inv);
        aout[base + 32] = (_Float16)(o1[r] * inv);
    }
}

// ---------------- K3 fallback: f32 flash attention ----------------
#define LSTR 68
__global__ __launch_bounds__(256) void attn_kernel(const float* __restrict__ q_s,
    const float* __restrict__ k_s, const float* __restrict__ v_s,
    float* __restrict__ a_s) {
    __shared__ float Qt[64][LSTR];
    __shared__ float KP[64][LSTR];
    __shared__ float Vs[64][LSTR];
    int bh = blockIdx.x;
    int qi = 31 - blockIdx.y;
    int tid = threadIdx.x;
    int tx = tid & 15, ty = tid >> 4;

#pragma unroll
    for (int qq = 0; qq < 4; ++qq) {
        int q  = qq * 16 + (tid >> 4);
        int d4 = (tid & 15) * 4;
        float4 v = *(const float4*)&q_s[((size_t)bh * S_LEN + qi * 64 + q) * HD + d4];
        Qt[d4 + 0][q] = v.x; Qt[d4 + 1][q] = v.y;
        Qt[d4 + 2][q] = v.z; Qt[d4 + 3][q] = v.w;
    }

    float o[4][4];
#pragma unroll
    for (int r = 0; r < 4; ++r)
#pragma unroll
        for (int c = 0; c < 4; ++c) o[r][c] = 0.f;
    float mrow[4] = {-1e30f, -1e30f, -1e30f, -1e30f};
    float lrow[4] = {0.f, 0.f, 0.f, 0.f};

    for (int kt = 0; kt <= qi; ++kt) {
        __syncthreads();
#pragma unroll
        for (int kk2 = 0; kk2 < 4; ++kk2) {
            int k  = kk2 * 16 + (tid >> 4);
            int d4 = (tid & 15) * 4;
            size_t rowoff = ((size_t)bh * S_LEN + kt * 64 + k) * HD + d4;
            float4 kv4 = *(const float4*)&k_s[rowoff];
            KP[d4 + 0][k] = kv4.x; KP[d4 + 1][k] = kv4.y;
            KP[d4 + 2][k] = kv4.z; KP[d4 + 3][k] = kv4.w;
            float4 vv4 = *(const float4*)&v_s[rowoff];
            *(float4*)&Vs[k][d4] = vv4;
        }
        __syncthreads();

        float s[4][4];
#pragma unroll
        for (int r = 0; r < 4; ++r)
#pragma unroll
            for (int c = 0; c < 4; ++c) s[r][c] = 0.f;
#pragma unroll 8
        for (int d = 0; d < 64; ++d) {
            float4 qv = *(const float4*)&Qt[d][ty * 4];
            float4 kv = *(const float4*)&KP[d][tx * 4];
            float qa[4] = {qv.x, qv.y, qv.z, qv.w};
            float ka[4] = {kv.x, kv.y, kv.z, kv.w};
#pragma unroll
            for (int r = 0; r < 4; ++r)
#pragma unroll
                for (int c = 0; c < 4; ++c)
                    s[r][c] = fmaf(qa[r], ka[c], s[r][c]);
        }
        if (kt == qi) {
#pragma unroll
            for (int r = 0; r < 4; ++r)
#pragma unroll
                for (int c = 0; c < 4; ++c)
                    if (tx * 4 + c > ty * 4 + r) s[r][c] = -1e30f;
        }
        __syncthreads();

        float p[4][4];
#pragma unroll
        for (int r = 0; r < 4; ++r) {
            float mx = fmaxf(fmaxf(s[r][0], s[r][1]), fmaxf(s[r][2], s[r][3]));
            mx = fmaxf(mx, __shfl_xor(mx, 1));
            mx = fmaxf(mx, __shfl_xor(mx, 2));
            mx = fmaxf(mx, __shfl_xor(mx, 4));
            mx = fmaxf(mx, __shfl_xor(mx, 8));
            float mn = fmaxf(mrow[r], mx);
            float alpha = __expf(mrow[r] - mn);
            mrow[r] = mn;
            float rsum = 0.f;
#pragma unroll
            for (int c = 0; c < 4; ++c) {
                p[r][c] = __expf(s[r][c] - mn);
                rsum += p[r][c];
            }
            rsum += __shfl_xor(rsum, 1);
            rsum += __shfl_xor(rsum, 2);
            rsum += __shfl_xor(rsum, 4);
            rsum += __shfl_xor(rsum, 8);
            lrow[r] = lrow[r] * alpha + rsum;
#pragma unroll
            for (int c = 0; c < 4; ++c) o[r][c] *= alpha;
            *(float4*)&KP[ty * 4 + r][tx * 4] =
                make_float4(p[r][0], p[r][1], p[r][2], p[r][3]);
        }
        __syncthreads();

#pragma unroll 8
        for (int k = 0; k < 64; ++k) {
            float4 vv = *(const float4*)&Vs[k][tx * 4];
            float va[4] = {vv.x, vv.y, vv.z, vv.w};
#pragma unroll
            for (int r = 0; r < 4; ++r) {
                float pr = KP[ty * 4 + r][k];
#pragma unroll
                for (int c = 0; c < 4; ++c)
                    o[r][c] = fmaf(pr, va[c], o[r][c]);
            }
        }
    }

    int b = bh >> 4, h = bh & 15;
#pragma unroll
    for (int r = 0; r < 4; ++r) {
        int i = qi * 64 + ty * 4 + r;
        float inv = 1.f / lrow[r];
        *(float4*)&a_s[((size_t)(b * S_LEN + i)) * D_DIM + h * HD + tx * 4] =
            make_float4(o[r][0] * inv, o[r][1] * inv, o[r][2] * inv, o[r][3] * inv);
    }
}

// ---------------- K4 fallback: f32 proj ----------------
__global__ __launch_bounds__(256) void proj_kernel(const float* __restrict__ A,
    const float* __restrict__ w, const float* __restrict__ bias,
    float* __restrict__ outp) {
    __shared__ float As[128][17];
    __shared__ float Bs[16][64];
    int bx = blockIdx.x;
    int by = blockIdx.y;
    int tid = threadIdx.x;
    int tx = tid & 15, ty = tid >> 4;

    float c[8][4];
#pragma unroll
    for (int i = 0; i < 8; ++i)
#pragma unroll
        for (int j = 0; j < 4; ++j) c[i][j] = 0.f;

    for (int k0 = 0; k0 < D_DIM; k0 += 16) {
#pragma unroll
        for (int u = 0; u < 2; ++u) {
            int f4 = tid + 256 * u;
            int row = f4 >> 2;
            int kk4 = (f4 & 3) * 4;
            float4 av = *(const float4*)&A[(size_t)(by * 128 + row) * D_DIM + k0 + kk4];
            As[row][kk4 + 0] = av.x; As[row][kk4 + 1] = av.y;
            As[row][kk4 + 2] = av.z; As[row][kk4 + 3] = av.w;
        }
        {
            int kkb = tid >> 4;
            int col4 = (tid & 15) * 4;
            *(float4*)&Bs[kkb][col4] =
                *(const float4*)&w[(size_t)(k0 + kkb) * D_DIM + bx * 64 + col4];
        }
        __syncthreads();
#pragma unroll
        for (int kk = 0; kk < 16; ++kk) {
            float4 bv = *(const float4*)&Bs[kk][tx * 4];
#pragma unroll
            for (int i = 0; i < 8; ++i) {
                float a = As[ty * 8 + i][kk];
                c[i][0] = fmaf(a, bv.x, c[i][0]);
                c[i][1] = fmaf(a, bv.y, c[i][1]);
                c[i][2] = fmaf(a, bv.z, c[i][2]);
                c[i][3] = fmaf(a, bv.w, c[i][3]);
            }
        }
        __syncthreads();
    }

    int ncol = bx * 64 + tx * 4;
    float4 bias4 = *(const float4*)&bias[ncol];
#pragma unroll
    for (int i = 0; i < 8; ++i) {
        int t = by * 128 + ty * 8 + i;
        *(float4*)&outp[(size_t)t * D_DIM + ncol] =
            make_float4(c[i][0] + bias4.x, c[i][1] + bias4.y,
                        c[i][2] + bias4.z, c[i][3] + bias4.w);
    }
}

extern "C" void kernel_launch(void* const* d_in, const int* in_sizes, int n_in,
                              void* d_out, int out_size, void* d_ws, size_t ws_size,
                              hipStream_t stream) {
    const float* x        = (const float*)d_in[0];
    const float* c_attn_w = (const float*)d_in[1];
    const float* c_attn_b = (const float*)d_in[2];
    const float* c_proj_w = (const float*)d_in[3];
    const float* c_proj_b = (const float*)d_in[4];
    const float* q_a1     = (const float*)d_in[5];
    const float* q_a2     = (const float*)d_in[6];
    const float* v_a1     = (const float*)d_in[7];
    const float* v_a2     = (const float*)d_in[8];

    float* outf   = (float*)d_out;
    float* qstage = outf;                  // a-region reused as f32 q staging [B,H,S,hd]
    float* pres   = outf + OUT_A_ELEMS;    // present [2,B,H,S,hd] f32

    // workspace layout:
    //  phase A (qkv):  tq[0,256K) tv[256K,512K) w_f16[512K,7.01M) a_f16[7.01M,15.66M)
    //  phase B (attn): kp_f16[16.78M,25.17M) vt_f16[25.17M,33.55M)
    //                  aout_f16[0,8.39M)  wp_f16[8.39M,10.49M)  (dead qkv region)
    char* wsb = (char*)d_ws;
    float* tq = (float*)wsb;
    float* tv = (float*)(wsb + 262144);
    _Float16* w_f16  = (_Float16*)(wsb + 524288);           // 6,488,064 B
    _Float16* a_f16  = (_Float16*)(wsb + 7012352);          // 8,650,752 B
    _Float16* kp_f16 = (_Float16*)(wsb + 16777216);         // 8,388,608 B
    _Float16* vt_f16 = (_Float16*)(wsb + 25165824);         // 8,388,608 B
    _Float16* aout_f16 = (_Float16*)wsb;                    // 8,388,608 B
    _Float16* wp_f16   = (_Float16*)(wsb + 8388608);        // 2,097,152 B
    const size_t WS_FULL = 33554432;
    const size_t WS_MID  = 16777216;

    lora1_v2<<<dim3(1024), dim3(256), 0, stream>>>(x, q_a1, v_a1, tq, tv);

    if (ws_size >= WS_FULL) {
        splitA_f16<<<dim3((T_TOK * (KAUG / 4) + 255) / 256), dim3(256), 0, stream>>>(
            x, tq, tv, a_f16);
        splitW_f16<<<dim3(48, KAUG / 32), dim3(256), 0, stream>>>(
            c_attn_w, q_a2, v_a2, w_f16);
        qkv_mfma<<<dim3(24, 32), dim3(256), 0, stream>>>(
            a_f16, w_f16, c_attn_b, qstage, pres);
        kprep_f16<<<dim3(2048), dim3(256), 0, stream>>>(pres, kp_f16);
        vtprep_f16<<<dim3(32, 32), dim3(256), 0, stream>>>(
            pres + OUT_KV_ELEMS, vt_f16);
        attn_mfma<<<dim3(32, 16), dim3(256), 0, stream>>>(
            qstage, kp_f16, vt_f16, aout_f16);
        wprep_f16<<<dim3(16, 32), dim3(256), 0, stream>>>(c_proj_w, wp_f16);
        proj_mfma<<<dim3(8, 32), dim3(256), 0, stream>>>(
            aout_f16, wp_f16, c_proj_b, outf);
    } else if (ws_size >= WS_MID) {
        // fp16 qkv + f32 attn/proj; a_s reuses [0,16.78M) (dead after qkv)
        float* a_s = (float*)wsb;
        splitA_f16<<<dim3((T_TOK * (KAUG / 4) + 255) / 256), dim3(256), 0, stream>>>(
            x, tq, tv, a_f16);
        splitW_f16<<<dim3(48, KAUG / 32), dim3(256), 0, stream>>>(
            c_attn_w, q_a2, v_a2, w_f16);
        qkv_mfma<<<dim3(24, 32), dim3(256), 0, stream>>>(
            a_f16, w_f16, c_attn_b, qstage, pres);
        attn_kernel<<<dim3(32, 32), dim3(256), 0, stream>>>(
            qstage, pres, pres + OUT_KV_ELEMS, a_s);
        proj_kernel<<<dim3(16, 32), dim3(256), 0, stream>>>(
            a_s, c_proj_w, c_proj_b, outf);
    } else {
        float* a_s2 = tv + 65536;
        attn_kernel<<<dim3(32, 32), dim3(256), 0, stream>>>(
            qstage, pres, pres + OUT_KV_ELEMS, a_s2);
        proj_kernel<<<dim3(16, 32), dim3(256), 0, stream>>>(
            a_s2, c_proj_w, c_proj_b, outf);
    }
}

// Round 9
// 250.760 us; speedup vs baseline: 1.4781x; 1.0390x over previous
//
#include <hip/hip_runtime.h>

#define T_TOK 4096   // B*S
#define D_DIM 1024
#define N3    3072
#define S_LEN 2048
#define NH    16
#define HD    64
#define KAUG  1056   // 1024 + 16 (q-lora) + 16 (v-lora)

#define OUT_A_ELEMS   4194304   // B*S*D   (f32 elements)
#define OUT_KV_ELEMS  4194304   // B*H*S*hd

typedef __attribute__((ext_vector_type(4))) float f32x4;
typedef __attribute__((ext_vector_type(16))) float f32x16;
typedef _Float16 f16x8 __attribute__((ext_vector_type(8)));
typedef _Float16 f16x4 __attribute__((ext_vector_type(4)));

union U4h { unsigned u[4]; f16x8 v; };

// granule-position hash for LDS bank-conflict-free B tiles (row stride 64 B)
#define GHASH(r) ((((r) >> 1) ^ ((r) >> 3)) & 3)

// packed f32x2 -> f16x2 (round-to-zero) as raw u32
__device__ __forceinline__ unsigned cvtpkh(float a, float b) {
    unsigned r;
    asm("v_cvt_pkrtz_f16_f32 %0, %1, %2" : "=v"(r) : "v"(a), "v"(b));
    return r;
}

#define GLL16(gp, lp) __builtin_amdgcn_global_load_lds( \
    (const __attribute__((address_space(1))) unsigned int*)(gp), \
    (__attribute__((address_space(3))) unsigned int*)(lp), 16, 0, 0)

#define MFMA16F(A, B, C) __builtin_amdgcn_mfma_f32_16x16x32_f16(A, B, C, 0, 0, 0)
#define MFMA32F(A, B, C) __builtin_amdgcn_mfma_f32_32x32x16_f16(A, B, C, 0, 0, 0)

// ---------------- K1: lora down-proj  tq = x@q_a1, tv = x@v_a1 ----------------
__global__ __launch_bounds__(256) void lora1_v2(const float* __restrict__ x,
    const float* __restrict__ qa1, const float* __restrict__ va1,
    float* __restrict__ tq, float* __restrict__ tv) {
    int tid = threadIdx.x;
    int w = tid >> 6;
    int lane = tid & 63;
    int t = blockIdx.x * 4 + w;
    int cg = lane & 7;
    int ks = lane >> 3;
    const float* a1 = (cg < 4) ? qa1 : va1;
    int c4 = (cg & 3) * 4;
    const float* xr = x + (size_t)t * D_DIM + ks * 128;
    const float* ar = a1 + (size_t)(ks * 128) * 16 + c4;
    float4 acc = make_float4(0.f, 0.f, 0.f, 0.f);
#pragma unroll 8
    for (int j = 0; j < 128; ++j) {
        float xv = xr[j];
        float4 av = *(const float4*)&ar[j * 16];
        acc.x = fmaf(xv, av.x, acc.x);
        acc.y = fmaf(xv, av.y, acc.y);
        acc.z = fmaf(xv, av.z, acc.z);
        acc.w = fmaf(xv, av.w, acc.w);
    }
#pragma unroll
    for (int m = 8; m < 64; m <<= 1) {
        acc.x += __shfl_xor(acc.x, m);
        acc.y += __shfl_xor(acc.y, m);
        acc.z += __shfl_xor(acc.z, m);
        acc.w += __shfl_xor(acc.w, m);
    }
    if (lane < 8) {
        float* dst = (cg < 4) ? &tq[t * 16 + c4] : &tv[t * 16 + (cg - 4) * 4];
        *(float4*)dst = acc;
    }
}

// ---------------- prep: A_aug = [x | tq | tv] -> single fp16 plane [T_TOK][KAUG]
__global__ __launch_bounds__(256) void splitA_f16(const float* __restrict__ x,
    const float* __restrict__ tq, const float* __restrict__ tv,
    _Float16* __restrict__ af) {
    int idx = blockIdx.x * 256 + threadIdx.x;
    const int total = T_TOK * (KAUG / 4);
    if (idx >= total) return;
    int t = idx / (KAUG / 4);
    int c4 = (idx - t * (KAUG / 4)) * 4;
    float4 v;
    if (c4 < D_DIM)           v = *(const float4*)&x[(size_t)t * D_DIM + c4];
    else if (c4 < D_DIM + 16) v = *(const float4*)&tq[t * 16 + (c4 - D_DIM)];
    else                      v = *(const float4*)&tv[t * 16 + (c4 - D_DIM - 16)];
    f16x4 h;
    h[0] = (_Float16)v.x; h[1] = (_Float16)v.y;
    h[2] = (_Float16)v.z; h[3] = (_Float16)v.w;
    *(f16x4*)&af[(size_t)t * KAUG + c4] = h;
}

// ---------------- prep: W_aug^T fp16 plane [N3][KAUG], granule-swizzled per 32-k chunk
__global__ __launch_bounds__(256) void splitW_f16(const float* __restrict__ w,
    const float* __restrict__ qa2, const float* __restrict__ va2,
    _Float16* __restrict__ bf) {
    __shared__ float T[32][65];
    int bn = blockIdx.x;
    int bk = blockIdx.y;
    int tid = threadIdx.x;
#pragma unroll
    for (int u = 0; u < 2; ++u) {
        int id = tid + 256 * u;
        int kr = id >> 4;
        int n4 = (id & 15) * 4;
        int k = bk * 32 + kr;
        int n = bn * 64 + n4;
        float4 v = make_float4(0.f, 0.f, 0.f, 0.f);
        if (k < D_DIM) {
            v = *(const float4*)&w[(size_t)k * N3 + n];
        } else if (k < D_DIM + 16) {
            if (n < D_DIM) {
                float4 q4 = *(const float4*)&qa2[(k - D_DIM) * D_DIM + n];
                v = make_float4(q4.x * 0.5f, q4.y * 0.5f, q4.z * 0.5f, q4.w * 0.5f);
            }
        } else {
            if (n >= 2 * D_DIM) {
                float4 q4 = *(const float4*)&va2[(k - D_DIM - 16) * D_DIM + (n - 2 * D_DIM)];
                v = make_float4(q4.x * 0.5f, q4.y * 0.5f, q4.z * 0.5f, q4.w * 0.5f);
            }
        }
        T[kr][n4 + 0] = v.x; T[kr][n4 + 1] = v.y;
        T[kr][n4 + 2] = v.z; T[kr][n4 + 3] = v.w;
    }
    __syncthreads();
    int n = tid >> 2;
    int k8 = (tid & 3) * 8;
    f16x8 hv;
#pragma unroll
    for (int j = 0; j < 8; ++j) hv[j] = (_Float16)T[k8 + j][n];
    int nr = bn * 64 + n;
    int gsw = (tid & 3) ^ GHASH(nr);
    size_t ro = (size_t)nr * KAUG + bk * 32 + gsw * 8;
    *(f16x8*)&bf[ro] = hv;
}

// ---------------- prep: c_proj_w -> transposed fp16 plane [1024][1024], swizzled
__global__ __launch_bounds__(256) void wprep_f16(const float* __restrict__ w,
    _Float16* __restrict__ bf) {
    __shared__ float T[32][65];
    int bn = blockIdx.x;
    int bk = blockIdx.y;
    int tid = threadIdx.x;
#pragma unroll
    for (int u = 0; u < 2; ++u) {
        int id = tid + 256 * u;
        int kr = id >> 4;
        int n4 = (id & 15) * 4;
        float4 v = *(const float4*)&w[(size_t)(bk * 32 + kr) * D_DIM + bn * 64 + n4];
        T[kr][n4 + 0] = v.x; T[kr][n4 + 1] = v.y;
        T[kr][n4 + 2] = v.z; T[kr][n4 + 3] = v.w;
    }
    __syncthreads();
    int n = tid >> 2;
    int k8 = (tid & 3) * 8;
    f16x8 hv;
#pragma unroll
    for (int j = 0; j < 8; ++j) hv[j] = (_Float16)T[k8 + j][n];
    int nr = bn * 64 + n;
    int gsw = (tid & 3) ^ GHASH(nr);
    size_t ro = (size_t)nr * D_DIM + bk * 32 + gsw * 8;
    *(f16x8*)&bf[ro] = hv;
}

// ---------------- K2 (v5): fp16 MFMA GEMM, BK=64 (2 chunks/round), fused epilogue
// mode 0: write q as fp16 plane + pres + swizzled kp/vt planes (kprep/vtprep fused)
// mode 1: write f32 qstage + pres (fallback path)
__global__ __launch_bounds__(256, 3) void qkv_mfma(
    const _Float16* __restrict__ a_g, const _Float16* __restrict__ b_g,
    const float* __restrict__ bias, int mode,
    float* __restrict__ qstage, float* __restrict__ pres,
    _Float16* __restrict__ qf16, _Float16* __restrict__ kp,
    _Float16* __restrict__ vt) {
    __shared__ _Float16 Bf[2][2][128 * 32];   // 32 KB (2 bufs x 2 chunk-slots)
    int id = blockIdx.y * 24 + blockIdx.x;
    int nid = (id & 7) * 96 + (id >> 3);      // XCD-contiguous, bijective (768=8x96)
    int bn = nid % 24;
    int bm = nid / 24;
    int tid = threadIdx.x;
    int w = tid >> 6, l = tid & 63;
    int wr = w >> 1, wc = w & 1;

    f32x4 acc[4][4];
#pragma unroll
    for (int i = 0; i < 4; ++i)
#pragma unroll
        for (int j = 0; j < 4; ++j)
            acc[i][j] = (f32x4){0.f, 0.f, 0.f, 0.f};

    int srow = l >> 2;
    int sk = (l & 3) * 8;
    const size_t b_base0 = (size_t)(bn * 128 + w * 32 + srow) * KAUG + sk;
    const size_t b_base1 = b_base0 + (size_t)16 * KAUG;
    const int ldso0 = (w * 32) * 32;
    const int ldso1 = (w * 32 + 16) * 32;

    int lrow = l & 15;
    int lg = l >> 4;

    const _Float16* aF[4];
#pragma unroll
    for (int i = 0; i < 4; ++i) {
        int row = bm * 128 + wr * 64 + i * 16 + lrow;
        aF[i] = a_g + (size_t)row * KAUG + lg * 8;
    }
    int roB[4];
#pragma unroll
    for (int j = 0; j < 4; ++j) {
        int Rb = wc * 64 + j * 16 + lrow;
        roB[j] = Rb * 32 + ((lg ^ GHASH(Rb)) * 8);
    }

    f16x8 cA0[4], cA1[4], nA0[4], nA1[4];

    // prologue: chunks 0,1 -> buf0 slots 0,1; A chunks 0,1 -> regs
    GLL16(b_g + b_base0,      &Bf[0][0][ldso0]);
    GLL16(b_g + b_base1,      &Bf[0][0][ldso1]);
    GLL16(b_g + b_base0 + 32, &Bf[0][1][ldso0]);
    GLL16(b_g + b_base1 + 32, &Bf[0][1][ldso1]);
#pragma unroll
    for (int i = 0; i < 4; ++i) {
        cA0[i] = *(const f16x8*)(aF[i]);
        cA1[i] = *(const f16x8*)(aF[i] + 32);
    }
    asm volatile("s_waitcnt vmcnt(0)" ::: "memory");
    __builtin_amdgcn_s_barrier();

    // 17 rounds: rounds 0..15 = 2 chunks, round 16 = chunk 32 only
    for (int r = 0; r < 17; ++r) {
        int cur = r & 1;
        if (r < 16) {
            int kn = (r + 1) * 64;
            GLL16(b_g + b_base0 + kn, &Bf[cur ^ 1][0][ldso0]);
            GLL16(b_g + b_base1 + kn, &Bf[cur ^ 1][0][ldso1]);
            if (r < 15) {
                GLL16(b_g + b_base0 + kn + 32, &Bf[cur ^ 1][1][ldso0]);
                GLL16(b_g + b_base1 + kn + 32, &Bf[cur ^ 1][1][ldso1]);
            }
            __builtin_amdgcn_sched_barrier(0);   // GLLs issue before A prefetch
#pragma unroll
            for (int i = 0; i < 4; ++i) nA0[i] = *(const f16x8*)(aF[i] + kn);
            if (r < 15) {
#pragma unroll
                for (int i = 0; i < 4; ++i) nA1[i] = *(const f16x8*)(aF[i] + kn + 32);
            }
        }
        f16x8 fb[4];
#pragma unroll
        for (int j = 0; j < 4; ++j) fb[j] = *(const f16x8*)&Bf[cur][0][roB[j]];
#pragma unroll
        for (int i = 0; i < 4; ++i)
#pragma unroll
            for (int j = 0; j < 4; ++j)
                acc[i][j] = MFMA16F(cA0[i], fb[j], acc[i][j]);
        if (r < 16) {
#pragma unroll
            for (int j = 0; j < 4; ++j) fb[j] = *(const f16x8*)&Bf[cur][1][roB[j]];
#pragma unroll
            for (int i = 0; i < 4; ++i)
#pragma unroll
                for (int j = 0; j < 4; ++j)
                    acc[i][j] = MFMA16F(cA1[i], fb[j], acc[i][j]);
            // drain this round's GLLs (oldest); A prefetch stays in flight
            if (r < 15) asm volatile("s_waitcnt vmcnt(8)" ::: "memory");
            else        asm volatile("s_waitcnt vmcnt(4)" ::: "memory");
            __builtin_amdgcn_s_barrier();
#pragma unroll
            for (int i = 0; i < 4; ++i) cA0[i] = nA0[i];
            if (r < 15) {
#pragma unroll
                for (int i = 0; i < 4; ++i) cA1[i] = nA1[i];
            }
        }
    }

    // ---- fused epilogue ----
    int seg = bn >> 3;          // 0=q, 1=k, 2=v
    int bb = bm >> 4;           // batch (block-uniform)
#pragma unroll
    for (int j = 0; j < 4; ++j) {
        int n = bn * 128 + wc * 64 + j * 16 + lrow;
        float bz = bias[n];
        int h = (n >> 6) & 15;
        int d = n & 63;
        size_t rowbase = (size_t)(bb * NH + h) * S_LEN;
#pragma unroll
        for (int i = 0; i < 4; ++i) {
            int tb = bm * 128 + wr * 64 + i * 16 + (l >> 4) * 4;
            int s0 = tb & 2047;
            if (seg == 0) {
                if (mode == 0) {
#pragma unroll
                    for (int r = 0; r < 4; ++r)
                        qf16[(rowbase + s0 + r) * HD + d] =
                            (_Float16)((acc[i][j][r] + bz) * 0.125f);
                } else {
#pragma unroll
                    for (int r = 0; r < 4; ++r)
                        qstage[(rowbase + s0 + r) * HD + d] =
                            (acc[i][j][r] + bz) * 0.125f;
                }
            } else if (seg == 1) {
                int gsw = d >> 3;
#pragma unroll
                for (int r = 0; r < 4; ++r) {
                    float v = acc[i][j][r] + bz;
                    int s = s0 + r;
                    pres[(rowbase + s) * HD + d] = v;
                    if (mode == 0)
                        kp[(rowbase + s) * HD + ((gsw ^ (s & 7)) << 3) + (d & 7)] =
                            (_Float16)v;
                }
            } else {
                f16x4 pk;
#pragma unroll
                for (int r = 0; r < 4; ++r) {
                    float v = acc[i][j][r] + bz;
                    pres[OUT_KV_ELEMS + (rowbase + s0 + r) * HD + d] = v;
                    pk[r] = (_Float16)v;
                }
                if (mode == 0) {
                    int gp = ((s0 >> 3) & 7) ^ (d & 7);
                    *(f16x4*)&vt[((size_t)(bb * NH + h) * 64 + d) * 2048
                                 + (s0 & ~63) + (gp << 3) + (s0 & 7)] = pk;
                }
            }
        }
    }
}

// ---------------- K5 (v5): proj via fp16 MFMA, BK=64 (16 rounds exactly)
__global__ __launch_bounds__(256, 3) void proj_mfma(
    const _Float16* __restrict__ a_g, const _Float16* __restrict__ b_g,
    const float* __restrict__ bias, float* __restrict__ outp) {
    __shared__ _Float16 Bf[2][2][128 * 32];
    int id = blockIdx.y * 8 + blockIdx.x;
    int nid = (id & 7) * 32 + (id >> 3);
    int bn = nid % 8;
    int bm = nid / 8;
    int tid = threadIdx.x;
    int w = tid >> 6, l = tid & 63;
    int wr = w >> 1, wc = w & 1;

    f32x4 acc[4][4];
#pragma unroll
    for (int i = 0; i < 4; ++i)
#pragma unroll
        for (int j = 0; j < 4; ++j)
            acc[i][j] = (f32x4){0.f, 0.f, 0.f, 0.f};

    int srow = l >> 2;
    int sk = (l & 3) * 8;
    const size_t b_base0 = (size_t)(bn * 128 + w * 32 + srow) * D_DIM + sk;
    const size_t b_base1 = b_base0 + (size_t)16 * D_DIM;
    const int ldso0 = (w * 32) * 32;
    const int ldso1 = (w * 32 + 16) * 32;

    int lrow = l & 15;
    int lg = l >> 4;

    const _Float16* aF[4];
#pragma unroll
    for (int i = 0; i < 4; ++i) {
        int row = bm * 128 + wr * 64 + i * 16 + lrow;
        aF[i] = a_g + (size_t)row * D_DIM + lg * 8;
    }
    int roB[4];
#pragma unroll
    for (int j = 0; j < 4; ++j) {
        int Rb = wc * 64 + j * 16 + lrow;
        roB[j] = Rb * 32 + ((lg ^ GHASH(Rb)) * 8);
    }

    f16x8 cA0[4], cA1[4], nA0[4], nA1[4];

    GLL16(b_g + b_base0,      &Bf[0][0][ldso0]);
    GLL16(b_g + b_base1,      &Bf[0][0][ldso1]);
    GLL16(b_g + b_base0 + 32, &Bf[0][1][ldso0]);
    GLL16(b_g + b_base1 + 32, &Bf[0][1][ldso1]);
#pragma unroll
    for (int i = 0; i < 4; ++i) {
        cA0[i] = *(const f16x8*)(aF[i]);
        cA1[i] = *(const f16x8*)(aF[i] + 32);
    }
    asm volatile("s_waitcnt vmcnt(0)" ::: "memory");
    __builtin_amdgcn_s_barrier();

    for (int r = 0; r < 16; ++r) {
        int cur = r & 1;
        if (r < 15) {
            int kn = (r + 1) * 64;
            GLL16(b_g + b_base0 + kn,      &Bf[cur ^ 1][0][ldso0]);
            GLL16(b_g + b_base1 + kn,      &Bf[cur ^ 1][0][ldso1]);
            GLL16(b_g + b_base0 + kn + 32, &Bf[cur ^ 1][1][ldso0]);
            GLL16(b_g + b_base1 + kn + 32, &Bf[cur ^ 1][1][ldso1]);
            __builtin_amdgcn_sched_barrier(0);
#pragma unroll
            for (int i = 0; i < 4; ++i) {
                nA0[i] = *(const f16x8*)(aF[i] + kn);
                nA1[i] = *(const f16x8*)(aF[i] + kn + 32);
            }
        }
        f16x8 fb[4];
#pragma unroll
        for (int j = 0; j < 4; ++j) fb[j] = *(const f16x8*)&Bf[cur][0][roB[j]];
#pragma unroll
        for (int i = 0; i < 4; ++i)
#pragma unroll
            for (int j = 0; j < 4; ++j)
                acc[i][j] = MFMA16F(cA0[i], fb[j], acc[i][j]);
#pragma unroll
        for (int j = 0; j < 4; ++j) fb[j] = *(const f16x8*)&Bf[cur][1][roB[j]];
#pragma unroll
        for (int i = 0; i < 4; ++i)
#pragma unroll
            for (int j = 0; j < 4; ++j)
                acc[i][j] = MFMA16F(cA1[i], fb[j], acc[i][j]);
        if (r < 15) {
            asm volatile("s_waitcnt vmcnt(8)" ::: "memory");
            __builtin_amdgcn_s_barrier();
#pragma unroll
            for (int i = 0; i < 4; ++i) { cA0[i] = nA0[i]; cA1[i] = nA1[i]; }
        }
    }

#pragma unroll
    for (int j = 0; j < 4; ++j) {
        int n = bn * 128 + wc * 64 + j * 16 + lrow;
        float bz = bias[n];
#pragma unroll
        for (int i = 0; i < 4; ++i) {
            int tbase = bm * 128 + wr * 64 + i * 16 + (l >> 4) * 4;
#pragma unroll
            for (int r = 0; r < 4; ++r)
                outp[(size_t)(tbase + r) * D_DIM + n] = acc[i][j][r] + bz;
        }
    }
}

// ---------------- K3: fp16 MFMA flash attention, 32x32x16, swapped QK^T ----------------
__device__ __forceinline__ void stage_tile(
    const _Float16* __restrict__ kp, const _Float16* __restrict__ vt,
    _Float16 (*ldsb)[4096], int w, int l, int bh, int kv0) {
    if (w < 2) {
        const _Float16* gp = kp
            + ((size_t)bh * 2048 + kv0 + w * 32 + (l >> 3)) * 64 + (l & 7) * 8;
        _Float16* lp = ldsb[0] + (w * 32) * 64;
#pragma unroll
        for (int i = 0; i < 4; ++i)
            GLL16(gp + i * 512, lp + i * 512);
    } else {
        int wv = w - 2;
        const _Float16* gp = vt
            + ((size_t)bh * 64 + wv * 32 + (l >> 3)) * 2048 + kv0 + (l & 7) * 8;
        _Float16* lp = ldsb[1] + (wv * 32) * 64;
#pragma unroll
        for (int i = 0; i < 4; ++i)
            GLL16(gp + (size_t)i * 8 * 2048, lp + i * 512);
    }
}

#define QROW(r) ((((r) & 3) + 8 * ((r) >> 2)) + 4 * g)

__global__ __launch_bounds__(256, 4) void attn_mfma(
    const _Float16* __restrict__ q_h,
    const _Float16* __restrict__ kp, const _Float16* __restrict__ vt,
    _Float16* __restrict__ aout) {
    __shared__ __align__(16) _Float16 lds[2][2][4096];   // 32 KB
    int bh = blockIdx.x;
    int qi = (int)gridDim.y - 1 - blockIdx.y;
    int tid = threadIdx.x;
    int w = tid >> 6, l = tid & 63;
    int qloc = l & 31, g = l >> 5;
    int q0 = qi * 128;
    int qg = q0 + w * 32 + qloc;

    // Q fragments (pre-scaled 1/8, fp16 plane)
    f16x8 qf[4];
    {
        const _Float16* qrow = q_h + ((size_t)bh * S_LEN + qg) * HD;
#pragma unroll
        for (int t = 0; t < 4; ++t)
            qf[t] = *(const f16x8*)&qrow[t * 16 + g * 8];
    }

    f32x16 o0, o1;
#pragma unroll
    for (int r = 0; r < 16; ++r) { o0[r] = 0.f; o1[r] = 0.f; }
    float m_run = -1e30f, l_run = 0.f;

    int nt = 2 * qi + 2;
    int qwmax = q0 + w * 32 + 31;

    stage_tile(kp, vt, lds[0], w, l, bh, 0);
    __syncthreads();

    for (int t = 0; t < nt; ++t) {
        int kv0 = t * 64;
        int bi = t & 1;
        if (t + 1 < nt)
            stage_tile(kp, vt, lds[bi ^ 1], w, l, bh, (t + 1) * 64);

        if (kv0 <= qwmax) {
            const _Float16* Kp = lds[bi][0];
            const _Float16* Vp = lds[bi][1];

            f32x16 s0, s1;
#pragma unroll
            for (int r = 0; r < 16; ++r) { s0[r] = 0.f; s1[r] = 0.f; }

            __builtin_amdgcn_s_setprio(1);
#pragma unroll
            for (int tt = 0; tt < 4; ++tt) {
                int gr = ((2 * tt + g) ^ (qloc & 7)) * 8;
                f16x8 a0 = *(const f16x8*)&Kp[qloc * 64 + gr];
                f16x8 a1 = *(const f16x8*)&Kp[(32 + qloc) * 64 + gr];
                s0 = MFMA32F(a0, qf[tt], s0);
                s1 = MFMA32F(a1, qf[tt], s1);
            }
            __builtin_amdgcn_s_setprio(0);

            if (kv0 + 63 > q0 + w * 32) {
#pragma unroll
                for (int r = 0; r < 16; ++r) {
                    int kk = kv0 + QROW(r);
                    if (kk > qg)      s0[r] = -1e30f;
                    if (kk + 32 > qg) s1[r] = -1e30f;
                }
            }

            float mx = s0[0];
#pragma unroll
            for (int r = 1; r < 16; ++r) mx = fmaxf(mx, s0[r]);
#pragma unroll
            for (int r = 0; r < 16; ++r) mx = fmaxf(mx, s1[r]);
            mx = fmaxf(mx, __shfl_xor(mx, 32));
            float mnew = fmaxf(m_run, mx);
            float al = __expf(m_run - mnew);
            m_run = mnew;
            float rs = 0.f;
#pragma unroll
            for (int r = 0; r < 16; ++r) { s0[r] = __expf(s0[r] - mnew); rs += s0[r]; }
#pragma unroll
            for (int r = 0; r < 16; ++r) { s1[r] = __expf(s1[r] - mnew); rs += s1[r]; }
            rs += __shfl_xor(rs, 32);
            l_run = l_run * al + rs;
#pragma unroll
            for (int r = 0; r < 16; ++r) {
                float ar = __shfl(al, QROW(r));
                o0[r] *= ar; o1[r] *= ar;
            }

            __builtin_amdgcn_s_setprio(1);
#pragma unroll
            for (int ks = 0; ks < 4; ++ks) {
                const int b = (ks & 1) * 8;
                unsigned w0, w1, w2, w3;
                if (ks < 2) {
                    w0 = cvtpkh(s0[b + 0], s0[b + 1]);
                    w1 = cvtpkh(s0[b + 2], s0[b + 3]);
                    w2 = cvtpkh(s0[b + 4], s0[b + 5]);
                    w3 = cvtpkh(s0[b + 6], s0[b + 7]);
                } else {
                    w0 = cvtpkh(s1[b + 0], s1[b + 1]);
                    w1 = cvtpkh(s1[b + 2], s1[b + 3]);
                    w2 = cvtpkh(s1[b + 4], s1[b + 5]);
                    w3 = cvtpkh(s1[b + 6], s1[b + 7]);
                }
                asm("v_permlane32_swap_b32 %0, %1" : "+v"(w0), "+v"(w2));
                asm("v_permlane32_swap_b32 %0, %1" : "+v"(w1), "+v"(w3));
                U4h u; u.u[0] = w0; u.u[1] = w1; u.u[2] = w2; u.u[3] = w3;
                f16x8 pa = u.v;
                int gr = ((2 * ks + g) ^ (qloc & 7)) * 8;
                f16x8 v0 = *(const f16x8*)&Vp[qloc * 64 + gr];
                f16x8 v1 = *(const f16x8*)&Vp[(32 + qloc) * 64 + gr];
                o0 = MFMA32F(pa, v0, o0);
                o1 = MFMA32F(pa, v1, o1);
            }
            __builtin_amdgcn_s_setprio(0);
        }
        __syncthreads();
    }

    int bb = bh >> 4, h = bh & 15;
#pragma unroll
    for (int r = 0; r < 16; ++r) {
        float li = __shfl(l_run, QROW(r));
        float inv = 1.f / li;
        int qq = q0 + w * 32 + QROW(r);
        size_t base = ((size_t)(bb * S_LEN + qq)) * D_DIM + h * HD + qloc;
        aout[base]      = (_Float16)(o0[r] * inv);
        aout[base + 32] = (_Float16)(o1[r] * inv);
    }
}

// ---------------- K3 fallback: f32 flash attention ----------------
#define LSTR 68
__global__ __launch_bounds__(256) void attn_kernel(const float* __restrict__ q_s,
    const float* __restrict__ k_s, const float* __restrict__ v_s,
    float* __restrict__ a_s) {
    __shared__ float Qt[64][LSTR];
    __shared__ float KP[64][LSTR];
    __shared__ float Vs[64][LSTR];
    int bh = blockIdx.x;
    int qi = 31 - blockIdx.y;
    int tid = threadIdx.x;
    int tx = tid & 15, ty = tid >> 4;

#pragma unroll
    for (int qq = 0; qq < 4; ++qq) {
        int q  = qq * 16 + (tid >> 4);
        int d4 = (tid & 15) * 4;
        float4 v = *(const float4*)&q_s[((size_t)bh * S_LEN + qi * 64 + q) * HD + d4];
        Qt[d4 + 0][q] = v.x; Qt[d4 + 1][q] = v.y;
        Qt[d4 + 2][q] = v.z; Qt[d4 + 3][q] = v.w;
    }

    float o[4][4];
#pragma unroll
    for (int r = 0; r < 4; ++r)
#pragma unroll
        for (int c = 0; c < 4; ++c) o[r][c] = 0.f;
    float mrow[4] = {-1e30f, -1e30f, -1e30f, -1e30f};
    float lrow[4] = {0.f, 0.f, 0.f, 0.f};

    for (int kt = 0; kt <= qi; ++kt) {
        __syncthreads();
#pragma unroll
        for (int kk2 = 0; kk2 < 4; ++kk2) {
            int k  = kk2 * 16 + (tid >> 4);
            int d4 = (tid & 15) * 4;
            size_t rowoff = ((size_t)bh * S_LEN + kt * 64 + k) * HD + d4;
            float4 kv4 = *(const float4*)&k_s[rowoff];
            KP[d4 + 0][k] = kv4.x; KP[d4 + 1][k] = kv4.y;
            KP[d4 + 2][k] = kv4.z; KP[d4 + 3][k] = kv4.w;
            float4 vv4 = *(const float4*)&v_s[rowoff];
            *(float4*)&Vs[k][d4] = vv4;
        }
        __syncthreads();

        float s[4][4];
#pragma unroll
        for (int r = 0; r < 4; ++r)
#pragma unroll
            for (int c = 0; c < 4; ++c) s[r][c] = 0.f;
#pragma unroll 8
        for (int d = 0; d < 64; ++d) {
            float4 qv = *(const float4*)&Qt[d][ty * 4];
            float4 kv = *(const float4*)&KP[d][tx * 4];
            float qa[4] = {qv.x, qv.y, qv.z, qv.w};
            float ka[4] = {kv.x, kv.y, kv.z, kv.w};
#pragma unroll
            for (int r = 0; r < 4; ++r)
#pragma unroll
                for (int c = 0; c < 4; ++c)
                    s[r][c] = fmaf(qa[r], ka[c], s[r][c]);
        }
        if (kt == qi) {
#pragma unroll
            for (int r = 0; r < 4; ++r)
#pragma unroll
                for (int c = 0; c < 4; ++c)
                    if (tx * 4 + c > ty * 4 + r) s[r][c] = -1e30f;
        }
        __syncthreads();

        float p[4][4];
#pragma unroll
        for (int r = 0; r < 4; ++r) {
            float mx = fmaxf(fmaxf(s[r][0], s[r][1]), fmaxf(s[r][2], s[r][3]));
            mx = fmaxf(mx, __shfl_xor(mx, 1));
            mx = fmaxf(mx, __shfl_xor(mx, 2));
            mx = fmaxf(mx, __shfl_xor(mx, 4));
            mx = fmaxf(mx, __shfl_xor(mx, 8));
            float mn = fmaxf(mrow[r], mx);
            float alpha = __expf(mrow[r] - mn);
            mrow[r] = mn;
            float rsum = 0.f;
#pragma unroll
            for (int c = 0; c < 4; ++c) {
                p[r][c] = __expf(s[r][c] - mn);
                rsum += p[r][c];
            }
            rsum += __shfl_xor(rsum, 1);
            rsum += __shfl_xor(rsum, 2);
            rsum += __shfl_xor(rsum, 4);
            rsum += __shfl_xor(rsum, 8);
            lrow[r] = lrow[r] * alpha + rsum;
#pragma unroll
            for (int c = 0; c < 4; ++c) o[r][c] *= alpha;
            *(float4*)&KP[ty * 4 + r][tx * 4] =
                make_float4(p[r][0], p[r][1], p[r][2], p[r][3]);
        }
        __syncthreads();

#pragma unroll 8
        for (int k = 0; k < 64; ++k) {
            float4 vv = *(const float4*)&Vs[k][tx * 4];
            float va[4] = {vv.x, vv.y, vv.z, vv.w};
#pragma unroll
            for (int r = 0; r < 4; ++r) {
                float pr = KP[ty * 4 + r][k];
#pragma unroll
                for (int c = 0; c < 4; ++c)
                    o[r][c] = fmaf(pr, va[c], o[r][c]);
            }
        }
    }

    int b = bh >> 4, h = bh & 15;
#pragma unroll
    for (int r = 0; r < 4; ++r) {
        int i = qi * 64 + ty * 4 + r;
        float inv = 1.f / lrow[r];
        *(float4*)&a_s[((size_t)(b * S_LEN + i)) * D_DIM + h * HD + tx * 4] =
            make_float4(o[r][0] * inv, o[r][1] * inv, o[r][2] * inv, o[r][3] * inv);
    }
}

// ---------------- K4 fallback: f32 proj ----------------
__global__ __launch_bounds__(256) void proj_kernel(const float* __restrict__ A,
    const float* __restrict__ w, const float* __restrict__ bias,
    float* __restrict__ outp) {
    __shared__ float As[128][17];
    __shared__ float Bs[16][64];
    int bx = blockIdx.x;
    int by = blockIdx.y;
    int tid = threadIdx.x;
    int tx = tid & 15, ty = tid >> 4;

    float c[8][4];
#pragma unroll
    for (int i = 0; i < 8; ++i)
#pragma unroll
        for (int j = 0; j < 4; ++j) c[i][j] = 0.f;

    for (int k0 = 0; k0 < D_DIM; k0 += 16) {
#pragma unroll
        for (int u = 0; u < 2; ++u) {
            int f4 = tid + 256 * u;
            int row = f4 >> 2;
            int kk4 = (f4 & 3) * 4;
            float4 av = *(const float4*)&A[(size_t)(by * 128 + row) * D_DIM + k0 + kk4];
            As[row][kk4 + 0] = av.x; As[row][kk4 + 1] = av.y;
            As[row][kk4 + 2] = av.z; As[row][kk4 + 3] = av.w;
        }
        {
            int kkb = tid >> 4;
            int col4 = (tid & 15) * 4;
            *(float4*)&Bs[kkb][col4] =
                *(const float4*)&w[(size_t)(k0 + kkb) * D_DIM + bx * 64 + col4];
        }
        __syncthreads();
#pragma unroll
        for (int kk = 0; kk < 16; ++kk) {
            float4 bv = *(const float4*)&Bs[kk][tx * 4];
#pragma unroll
            for (int i = 0; i < 8; ++i) {
                float a = As[ty * 8 + i][kk];
                c[i][0] = fmaf(a, bv.x, c[i][0]);
                c[i][1] = fmaf(a, bv.y, c[i][1]);
                c[i][2] = fmaf(a, bv.z, c[i][2]);
                c[i][3] = fmaf(a, bv.w, c[i][3]);
            }
        }
        __syncthreads();
    }

    int ncol = bx * 64 + tx * 4;
    float4 bias4 = *(const float4*)&bias[ncol];
#pragma unroll
    for (int i = 0; i < 8; ++i) {
        int t = by * 128 + ty * 8 + i;
        *(float4*)&outp[(size_t)t * D_DIM + ncol] =
            make_float4(c[i][0] + bias4.x, c[i][1] + bias4.y,
                        c[i][2] + bias4.z, c[i][3] + bias4.w);
    }
}

extern "C" void kernel_launch(void* const* d_in, const int* in_sizes, int n_in,
                              void* d_out, int out_size, void* d_ws, size_t ws_size,
                              hipStream_t stream) {
    const float* x        = (const float*)d_in[0];
    const float* c_attn_w = (const float*)d_in[1];
    const float* c_attn_b = (const float*)d_in[2];
    const float* c_proj_w = (const float*)d_in[3];
    const float* c_proj_b = (const float*)d_in[4];
    const float* q_a1     = (const float*)d_in[5];
    const float* q_a2     = (const float*)d_in[6];
    const float* v_a1     = (const float*)d_in[7];
    const float* v_a2     = (const float*)d_in[8];

    float* outf   = (float*)d_out;
    float* qstage = outf;                  // f32 q staging (fallback path only)
    float* pres   = outf + OUT_A_ELEMS;    // present [2,B,H,S,hd] f32

    // workspace layout (FULL path):
    //  phase A (qkv):  tq[0,256K) tv[256K,512K) w_f16[512K,7.01M) a_f16[7.01M,15.66M)
    //  qkv outputs:    kp_f16[16.78M,25.17M) vt_f16[25.17M,33.55M) q_h16[33.55M,41.94M)
    //  phase B:        aout_f16[0,8.39M) wp_f16[8.39M,10.49M)   (dead qkv-input region)
    char* wsb = (char*)d_ws;
    float* tq = (float*)wsb;
    float* tv = (float*)(wsb + 262144);
    _Float16* w_f16  = (_Float16*)(wsb + 524288);           // 6,488,064 B
    _Float16* a_f16  = (_Float16*)(wsb + 7012352);          // 8,650,752 B
    _Float16* kp_f16 = (_Float16*)(wsb + 16777216);         // 8,388,608 B
    _Float16* vt_f16 = (_Float16*)(wsb + 25165824);         // 8,388,608 B
    _Float16* q_h16  = (_Float16*)(wsb + 33554432);         // 8,388,608 B
    _Float16* aout_f16 = (_Float16*)wsb;                    // 8,388,608 B
    _Float16* wp_f16   = (_Float16*)(wsb + 8388608);        // 2,097,152 B
    const size_t WS_FULL = 41943040;
    const size_t WS_MID  = 16777216;

    lora1_v2<<<dim3(1024), dim3(256), 0, stream>>>(x, q_a1, v_a1, tq, tv);

    if (ws_size >= WS_FULL) {
        splitA_f16<<<dim3((T_TOK * (KAUG / 4) + 255) / 256), dim3(256), 0, stream>>>(
            x, tq, tv, a_f16);
        splitW_f16<<<dim3(48, KAUG / 32), dim3(256), 0, stream>>>(
            c_attn_w, q_a2, v_a2, w_f16);
        qkv_mfma<<<dim3(24, 32), dim3(256), 0, stream>>>(
            a_f16, w_f16, c_attn_b, 0, nullptr, pres, q_h16, kp_f16, vt_f16);
        attn_mfma<<<dim3(32, 16), dim3(256), 0, stream>>>(
            q_h16, kp_f16, vt_f16, aout_f16);
        wprep_f16<<<dim3(16, 32), dim3(256), 0, stream>>>(c_proj_w, wp_f16);
        proj_mfma<<<dim3(8, 32), dim3(256), 0, stream>>>(
            aout_f16, wp_f16, c_proj_b, outf);
    } else if (ws_size >= WS_MID) {
        // fp16 qkv + f32 attn/proj; a_s reuses [0,16.78M) (dead after qkv)
        float* a_s = (float*)wsb;
        splitA_f16<<<dim3((T_TOK * (KAUG / 4) + 255) / 256), dim3(256), 0, stream>>>(
            x, tq, tv, a_f16);
        splitW_f16<<<dim3(48, KAUG / 32), dim3(256), 0, stream>>>(
            c_attn_w, q_a2, v_a2, w_f16);
        qkv_mfma<<<dim3(24, 32), dim3(256), 0, stream>>>(
            a_f16, w_f16, c_attn_b, 1, qstage, pres, nullptr, nullptr, nullptr);
        attn_kernel<<<dim3(32, 32), dim3(256), 0, stream>>>(
            qstage, pres, pres + OUT_KV_ELEMS, a_s);
        proj_kernel<<<dim3(16, 32), dim3(256), 0, stream>>>(
            a_s, c_proj_w, c_proj_b, outf);
    } else {
        float* a_s2 = tv + 65536;
        attn_kernel<<<dim3(32, 32), dim3(256), 0, stream>>>(
            qstage, pres, pres + OUT_KV_ELEMS, a_s2);
        proj_kernel<<<dim3(16, 32), dim3(256), 0, stream>>>(
            a_s2, c_proj_w, c_proj_b, outf);
    }
}